// Round 2
// baseline (528.968 us; speedup 1.0000x reference)
//
#include <hip/hip_runtime.h>

// ---------------------------------------------------------------------------
// TransformerEncoder: B=4, S=2048, D=1024, H=16, HD=64, FF=4096
// Round 7: correctness-recovery + 256x256 depth-3 pipelined GEMM core.
//   R6's 4-phase ledger was provably wrong (per-wave windows made "half-tile
//   phase reads" global nonsense -> WAR race + insufficient vmcnt).
//   New core ledger (trivially provable):
//     BK=32, 4 LDS bufs (A,B each 256x32 x4 = 128 KB), depth-3 pipeline.
//     step t: vmcnt(8)  [tile-t's 4 loads landed; t+1,t+2 in flight]
//             s_barrier [all waves: buf t&3 valid; reads of (t-1)&3 done]
//             STAGE tile t+3 -> buf (t+3)&3 == (t-1)&3   [WAR-safe: last
//               read was step t-1, sequenced before this barrier]
//             12x ds_read_b128 + 32x MFMA from buf t&3 (disjoint from any
//               in-flight buffer -> no intra-step hazards exist)
//     tail: vmcnt(8)/(4)/(0) for the last 3 tiles. Requires NK=K/32 >= 4.
//   Swizzle (both-sides, rule 21): LDS[row][chunk] = global[row][chunk^g],
//     g(row)=(row>>1)&3, chunk = 8-elem (16 B) unit. Verified algebraically:
//     stage writes chunk lc from global lc^g; read of global chunk q uses
//     LDS chunk q^g -> (q^g)^g = q. Breaks the 8-way read conflict of the
//     linear [256][32] layout (16 rows/quad -> 2 bank slots) down to 2-way.
//   New core used for ffn1 + qkv only (grids 512/384). proj + ffn2 (N=1024:
//   just 128 blocks at 256^2 -> half the CUs idle) keep the R5-verified
//   128^2 kernel verbatim. Attention / cast / prep unchanged.
// ---------------------------------------------------------------------------

typedef short bf16x8 __attribute__((ext_vector_type(8)));
typedef float f32x4 __attribute__((ext_vector_type(4)));

__device__ __forceinline__ unsigned short f2bf(float f) {
  unsigned int u = __builtin_bit_cast(unsigned int, f);
  u += 0x7fffu + ((u >> 16) & 1u);   // round-to-nearest-even
  return (unsigned short)(u >> 16);
}

__device__ __forceinline__ void gload16(const unsigned short* g, unsigned short* l) {
  __builtin_amdgcn_global_load_lds(
      (const __attribute__((address_space(1))) unsigned int*)(g),
      (__attribute__((address_space(3))) unsigned int*)(l),
      16, 0, 0);
}

// --------------------------- cast fp32 -> bf16 -----------------------------
__global__ __launch_bounds__(256) void cast_f32_bf16(
    const float* __restrict__ src, unsigned short* __restrict__ dst, int n4) {
  int i = blockIdx.x * 256 + threadIdx.x;
  if (i < n4) {
    float4 f = ((const float4*)src)[i];
    ushort4 o;
    o.x = f2bf(f.x); o.y = f2bf(f.y); o.z = f2bf(f.z); o.w = f2bf(f.w);
    ((ushort4*)dst)[i] = o;
  }
}

// ---------------- merged weight prep: 6 transposes in one kernel -----------
__global__ __launch_bounds__(256) void prep_weights(
    const float* __restrict__ qW, const float* __restrict__ kW,
    const float* __restrict__ vW, const float* __restrict__ oW,
    const float* __restrict__ w1, const float* __restrict__ w2,
    unsigned short* __restrict__ qWt, unsigned short* __restrict__ kWt,
    unsigned short* __restrict__ vWt, unsigned short* __restrict__ oWt,
    unsigned short* __restrict__ w1t, unsigned short* __restrict__ w2t) {
  const int t = blockIdx.x;
  const float* W; unsigned short* Wt; int N, K, nt, kt;
  if (t < 2048) {
    const int w = t >> 9, r = t & 511;
    nt = r & 15; kt = r >> 4; N = 1024; K = 1024;
    W  = w == 0 ? qW : w == 1 ? kW : w == 2 ? vW : oW;
    Wt = w == 0 ? qWt : w == 1 ? kWt : w == 2 ? vWt : oWt;
  } else if (t < 4096) {
    const int r = t - 2048;
    nt = r & 63; kt = r >> 6; N = 4096; K = 1024; W = w1; Wt = w1t;
  } else {
    const int r = t - 4096;
    nt = r & 15; kt = r >> 4; N = 1024; K = 4096; W = w2; Wt = w2t;
  }
  const int wave = threadIdx.x >> 6, lane = threadIdx.x & 63;
  const int n = nt * 64 + lane;
  const int k0 = kt * 32 + wave * 8;
  union { int4 v; unsigned short u[8]; } s;
#pragma unroll
  for (int j = 0; j < 8; ++j) s.u[j] = f2bf(W[(size_t)(k0 + j) * N + n]);
  *(int4*)(Wt + (size_t)n * K + k0) = s.v;
}

// ------------------- 256x256 depth-3 GEMM core (B^T) -----------------------
// C[256,256] tile = A[m0:+256,:K] @ Bt[n0:+256,:K]^T. 8 waves as 2M x 4N,
// wave tile 128x64 (8 m-frags x 4 n-frags of 16x16), BK=32 (1 kk slice).
// LDS: As/Bs = 4 bufs x [256][32] bf16 (64 KB each). See file-header ledger.
__device__ __forceinline__ void gemm256_core(
    const unsigned short* __restrict__ A, const unsigned short* __restrict__ Bt,
    unsigned short* __restrict__ As, unsigned short* __restrict__ Bs,
    const int m0, const int n0, const int K, f32x4 (&acc)[8][4]) {
  const int tid = (int)threadIdx.x;
  const int w = tid >> 6, l = tid & 63;
  const int quad = l >> 4, l16 = l & 15;
  const int wm = (w >> 2) * 128, wn = (w & 3) * 64;

  // staging: tile [256][32] = 16 chunks of 16 rows (1 KB); wave w stages
  // chunks 2w, 2w+1 of A and of B. lane l covers row lr=l>>2, col-chunk
  // lc=l&3 (linear LDS dest); source col pre-XOR'd with g(row)=(row>>1)&3
  // = (l>>3)&3 (chunk base is a multiple of 16 rows).
  const int lr = l >> 2, lc = l & 3;
  const int swz = (lc ^ ((l >> 3) & 3)) * 8;
  const unsigned short* gA[2]; const unsigned short* gB[2];
  unsigned short* dA[2]; unsigned short* dB[2];
#pragma unroll
  for (int j = 0; j < 2; ++j) {
    const int rr = (w * 2 + j) * 16 + lr;
    gA[j] = A + (size_t)(m0 + rr) * K + swz;
    gB[j] = Bt + (size_t)(n0 + rr) * K + swz;
    dA[j] = As + (w * 2 + j) * 512;
    dB[j] = Bs + (w * 2 + j) * 512;
  }

  // read col: global chunk `quad` at row 16a+l16 lives at LDS chunk
  // quad ^ ((l16>>1)&3).
  const int cread = (quad ^ ((l16 >> 1) & 3)) * 8;
  const int rA = (wm + l16) * 32;
  const int rB = (wn + l16) * 32;

  auto STAGE = [&](int db, int t) {
#pragma unroll
    for (int j = 0; j < 2; ++j) {
      gload16(gA[j] + t * 32, dA[j] + db * 8192);
      gload16(gB[j] + t * 32, dB[j] + db * 8192);
    }
  };
  auto COMPUTE = [&](int db) {
    bf16x8 af[8], bf[4];
    const unsigned short* pa = As + db * 8192 + rA + cread;
    const unsigned short* pb = Bs + db * 8192 + rB + cread;
#pragma unroll
    for (int ni = 0; ni < 4; ++ni) bf[ni] = *(const bf16x8*)(pb + ni * 16 * 32);
#pragma unroll
    for (int mi = 0; mi < 8; ++mi) af[mi] = *(const bf16x8*)(pa + mi * 16 * 32);
    __builtin_amdgcn_s_setprio(1);
#pragma unroll
    for (int mi = 0; mi < 8; ++mi)
#pragma unroll
      for (int ni = 0; ni < 4; ++ni)
        acc[mi][ni] = __builtin_amdgcn_mfma_f32_16x16x32_bf16(
            af[mi], bf[ni], acc[mi][ni], 0, 0, 0);
    __builtin_amdgcn_s_setprio(0);
  };

  const int NK = K >> 5;   // >= 4
  STAGE(0, 0); STAGE(1, 1); STAGE(2, 2);
#pragma unroll 1
  for (int t = 0; t < NK - 3; ++t) {
    asm volatile("s_waitcnt vmcnt(8)" ::: "memory");
    __builtin_amdgcn_s_barrier();
    STAGE((t + 3) & 3, t + 3);
    COMPUTE(t & 3);
  }
  asm volatile("s_waitcnt vmcnt(8)" ::: "memory");
  __builtin_amdgcn_s_barrier();
  COMPUTE((NK - 3) & 3);
  asm volatile("s_waitcnt vmcnt(4)" ::: "memory");
  __builtin_amdgcn_s_barrier();
  COMPUTE((NK - 2) & 3);
  asm volatile("s_waitcnt vmcnt(0)" ::: "memory");
  __builtin_amdgcn_s_barrier();
  COMPUTE((NK - 1) & 3);
}

// --------------------- 256^2 GEMM (B^T), generic epilogue ------------------
// EPI: 0 fp32 out, 1 bf16 out, 2 bf16+relu. Bijective XCD swizzle (grid%8==0).
template <int EPI>
__global__ __launch_bounds__(512, 1) void gemm256_bt(
    const unsigned short* __restrict__ A, const unsigned short* __restrict__ Bt,
    const float* __restrict__ bias, void* __restrict__ C, int N, int K) {
  __shared__ unsigned short As[4 * 8192];
  __shared__ unsigned short Bs[4 * 8192];
  const int tn = N >> 8;
  const int cpx = (int)gridDim.x >> 3;
  const int sw = ((int)blockIdx.x & 7) * cpx + ((int)blockIdx.x >> 3);
  const int nt = sw % tn, mt = sw / tn;
  const int m0 = mt * 256, n0 = nt * 256;

  f32x4 acc[8][4] = {};
  gemm256_core(A, Bt, As, Bs, m0, n0, K, acc);

  const int tid = (int)threadIdx.x;
  const int w = tid >> 6, l = tid & 63;
  const int quad = l >> 4, l16 = l & 15;
  const int wm = (w >> 2) * 128, wn = (w & 3) * 64;
#pragma unroll
  for (int ni = 0; ni < 4; ++ni) {
    const int col = n0 + wn + ni * 16 + l16;
    const float bv = bias[col];
#pragma unroll
    for (int mi = 0; mi < 8; ++mi) {
      const int row = m0 + wm + mi * 16 + quad * 4;
#pragma unroll
      for (int r = 0; r < 4; ++r) {
        float v = acc[mi][ni][r] + bv;
        if (EPI == 2) v = v > 0.f ? v : 0.f;
        if (EPI == 0)
          ((float*)C)[(size_t)(row + r) * N + col] = v;
        else
          ((unsigned short*)C)[(size_t)(row + r) * N + col] = f2bf(v);
      }
    }
  }
}

// --------------------------- fused QKV GEMM (256^2) ------------------------
#define QSCALE 0.180336884f   // 0.125 * log2(e)

__global__ __launch_bounds__(512, 1) void gemm256_qkv(
    const unsigned short* __restrict__ A, const unsigned short* __restrict__ Bt,
    const float* __restrict__ qb, const float* __restrict__ kb,
    const float* __restrict__ vb, unsigned short* __restrict__ Qo,
    unsigned short* __restrict__ Ko, unsigned short* __restrict__ Vto, int K) {
  __shared__ unsigned short As[4 * 8192];
  __shared__ unsigned short Bs[4 * 8192];
  const int tn = 12;                           // N = 3072
  const int cpx = (int)gridDim.x >> 3;
  const int sw = ((int)blockIdx.x & 7) * cpx + ((int)blockIdx.x >> 3);
  const int nt = sw % tn, mt = sw / tn;
  const int m0 = mt * 256, n0 = nt * 256;

  f32x4 acc[8][4] = {};
  gemm256_core(A, Bt, As, Bs, m0, n0, K, acc);

  const int tid = (int)threadIdx.x;
  const int w = tid >> 6, l = tid & 63;
  const int quad = l >> 4, l16 = l & 15;
  const int wm = (w >> 2) * 128, wn = (w & 3) * 64;

  const int seg = n0 >> 10;                    // 0=Q, 1=K, 2=V (block-uniform)
  const float* bias = seg == 0 ? qb : (seg == 1 ? kb : vb);
#pragma unroll
  for (int ni = 0; ni < 4; ++ni) {
    const int col = (n0 + wn + ni * 16 + l16) & 1023;
    const float bv = bias[col];
#pragma unroll
    for (int mi = 0; mi < 8; ++mi) {
      const int row = m0 + wm + mi * 16 + quad * 4;
      if (seg == 2) {
        const int b = row >> 11, s = row & 2047;
        const int hh = col >> 6, dh = col & 63;
        union { ushort4 v; unsigned short u[4]; } pk;
#pragma unroll
        for (int r = 0; r < 4; ++r) pk.u[r] = f2bf(acc[mi][ni][r] + bv);
        *(ushort4*)(Vto + ((size_t)((b * 16 + hh) * 64 + dh)) * 2048 + s) = pk.v;
      } else if (seg == 0) {
#pragma unroll
        for (int r = 0; r < 4; ++r)
          Qo[(size_t)(row + r) * 1024 + col] = f2bf((acc[mi][ni][r] + bv) * QSCALE);
      } else {
#pragma unroll
        for (int r = 0; r < 4; ++r)
          Ko[(size_t)(row + r) * 1024 + col] = f2bf(acc[mi][ni][r] + bv);
      }
    }
  }
}

// ------------------- R5-verified 128^2 GEMM (proj, ffn2) -------------------
template <int EPI>
__global__ __launch_bounds__(256) void gemm_bt(
    const unsigned short* __restrict__ A, const unsigned short* __restrict__ Bt,
    const float* __restrict__ bias, void* __restrict__ C,
    int M, int N, int K) {
  __shared__ unsigned short As[128 * 32];
  __shared__ unsigned short Bs[128 * 32];

  const int tid = threadIdx.x;
  const int wave = tid >> 6, lane = tid & 63;
  const int quad = lane >> 4, l16 = lane & 15;
  const int wm = (wave >> 1) * 64, wn = (wave & 1) * 64;

  const int NT = N >> 7, band = NT >> 3;
  const int xcd = blockIdx.x & 7, local = blockIdx.x >> 3;
  const int nt = xcd * band + local % band;
  const int mt = local / band;
  const int m0 = mt * 128, n0 = nt * 128;

  const int u1 = tid, u2 = 256 + tid;
  const int r1 = u1 >> 2, c1 = (u1 & 3) * 8;
  const int r2 = u2 >> 2, c2 = (u2 & 3) * 8;
  const unsigned short* ga1 = A + (size_t)(m0 + r1) * K + c1;
  const unsigned short* ga2 = A + (size_t)(m0 + r2) * K + c2;
  const unsigned short* gb1 = Bt + (size_t)(n0 + r1) * K + c1;
  const unsigned short* gb2 = Bt + (size_t)(n0 + r2) * K + c2;
  unsigned short* lA1 = As + wave * 512;
  unsigned short* lA2 = As + 2048 + wave * 512;
  unsigned short* lB1 = Bs + wave * 512;
  unsigned short* lB2 = Bs + 2048 + wave * 512;

  f32x4 acc[4][4] = {};

  for (int k0 = 0; k0 < K; k0 += 32) {
    __syncthreads();
    gload16(ga1 + k0, lA1);
    gload16(ga2 + k0, lA2);
    gload16(gb1 + k0, lB1);
    gload16(gb2 + k0, lB2);
    __syncthreads();

    bf16x8 af[4], bfr[4];
#pragma unroll
    for (int mi = 0; mi < 4; ++mi)
      af[mi] = *(const bf16x8*)(As + (wm + mi * 16 + l16) * 32 + quad * 8);
#pragma unroll
    for (int ni = 0; ni < 4; ++ni)
      bfr[ni] = *(const bf16x8*)(Bs + (wn + ni * 16 + l16) * 32 + quad * 8);
#pragma unroll
    for (int mi = 0; mi < 4; ++mi)
#pragma unroll
      for (int ni = 0; ni < 4; ++ni)
        acc[mi][ni] = __builtin_amdgcn_mfma_f32_16x16x32_bf16(
            af[mi], bfr[ni], acc[mi][ni], 0, 0, 0);
  }

#pragma unroll
  for (int ni = 0; ni < 4; ++ni) {
    const int col = n0 + wn + ni * 16 + l16;
    const float bv = bias[col];
#pragma unroll
    for (int mi = 0; mi < 4; ++mi) {
      const int row = m0 + wm + mi * 16 + quad * 4;
#pragma unroll
      for (int r = 0; r < 4; ++r) {
        float v = acc[mi][ni][r] + bv;
        if (EPI == 2) v = v > 0.f ? v : 0.f;
        if (EPI == 0)
          ((float*)C)[(size_t)(row + r) * N + col] = v;
        else
          ((unsigned short*)C)[(size_t)(row + r) * N + col] = f2bf(v);
      }
    }
  }
}

// --------------------------- flash attention -------------------------------
__global__ __launch_bounds__(256, 4) void attn_fused(
    const unsigned short* __restrict__ Q, const unsigned short* __restrict__ K,
    const unsigned short* __restrict__ Vt, const int* __restrict__ lengths,
    unsigned short* __restrict__ ctx) {
  constexpr int S = 2048, D = 1024;
  __shared__ unsigned short Ks[64 * 72];
  __shared__ unsigned short Vs[64 * 72];
  __shared__ unsigned short Ps[4 * 32 * 72];

  const int tid = threadIdx.x;
  const int wave = tid >> 6, lane = tid & 63;
  const int quad = lane >> 4, l16 = lane & 15;
  const int bid = blockIdx.x;
  const int qt = bid & 15;
  const int h = (bid >> 4) & 15;
  const int b = bid >> 8;
  const int q0 = qt * 128;
  const int len = lengths[b];
  const int ktEnd = (len + 63) >> 6;
  const float NEGINF = -__builtin_inff();

  const size_t xbase = (size_t)b * S * D + (size_t)h * 64;
  const size_t vtb = (size_t)(b * 16 + h) * 64;

  bf16x8 qf0[2], qf1[2];
#pragma unroll
  for (int mb = 0; mb < 2; ++mb) {
    const unsigned short* qrow =
        Q + xbase + (size_t)(q0 + wave * 32 + mb * 16 + l16) * D;
    qf0[mb] = *(const bf16x8*)(qrow + quad * 8);
    qf1[mb] = *(const bf16x8*)(qrow + 32 + quad * 8);
  }

  const int sr1 = tid >> 3, sc1 = (tid & 7) * 8;
  const int sr2 = (256 + tid) >> 3, sc2 = (tid & 7) * 8;
  const unsigned short* kg1 = K + xbase + (size_t)sr1 * D + sc1;
  const unsigned short* kg2 = K + xbase + (size_t)sr2 * D + sc2;
  const unsigned short* vg1 = Vt + (vtb + sr1) * S + sc1;
  const unsigned short* vg2 = Vt + (vtb + sr2) * S + sc2;

  f32x4 oacc[2][4] = {};
  float rs[2][4] = {};

  unsigned short* pw = Ps + wave * (32 * 72);

  for (int kt = 0; kt < ktEnd; ++kt) {
    const int k0 = kt * 64;
    __syncthreads();
    *(int4*)(Ks + sr1 * 72 + sc1) = *(const int4*)(kg1 + (size_t)k0 * D);
    *(int4*)(Ks + sr2 * 72 + sc2) = *(const int4*)(kg2 + (size_t)k0 * D);
    *(int4*)(Vs + sr1 * 72 + sc1) = *(const int4*)(vg1 + k0);
    *(int4*)(Vs + sr2 * 72 + sc2) = *(const int4*)(vg2 + k0);
    __syncthreads();

    f32x4 sf[2][4];
#pragma unroll
    for (int cb = 0; cb < 4; ++cb) {
      const bf16x8 kf0 = *(const bf16x8*)(Ks + (cb * 16 + l16) * 72 + quad * 8);
      const bf16x8 kf1 = *(const bf16x8*)(Ks + (cb * 16 + l16) * 72 + 32 + quad * 8);
#pragma unroll
      for (int mb = 0; mb < 2; ++mb) {
        f32x4 c = {0.f, 0.f, 0.f, 0.f};
        c = __builtin_amdgcn_mfma_f32_16x16x32_bf16(qf0[mb], kf0, c, 0, 0, 0);
        c = __builtin_amdgcn_mfma_f32_16x16x32_bf16(qf1[mb], kf1, c, 0, 0, 0);
        sf[mb][cb] = c;
      }
    }

    if (k0 + 64 > len) {
#pragma unroll
      for (int cb = 0; cb < 4; ++cb) {
        const bool msk = (k0 + cb * 16 + l16) >= len;
#pragma unroll
        for (int mb = 0; mb < 2; ++mb)
#pragma unroll
          for (int r = 0; r < 4; ++r) sf[mb][cb][r] = msk ? NEGINF : sf[mb][cb][r];
      }
    }

#pragma unroll
    for (int mb = 0; mb < 2; ++mb)
#pragma unroll
      for (int cb = 0; cb < 4; ++cb)
#pragma unroll
        for (int r = 0; r < 4; ++r) {
          const float p = __builtin_amdgcn_exp2f(sf[mb][cb][r]);
          sf[mb][cb][r] = p;
          rs[mb][r] += p;
        }

#pragma unroll
    for (int mb = 0; mb < 2; ++mb)
#pragma unroll
      for (int cb = 0; cb < 4; ++cb)
#pragma unroll
        for (int r = 0; r < 4; ++r)
          pw[(mb * 16 + quad * 4 + r) * 72 + cb * 16 + l16] = f2bf(sf[mb][cb][r]);

    bf16x8 pa0[2], pa1[2];
#pragma unroll
    for (int mb = 0; mb < 2; ++mb) {
      pa0[mb] = *(const bf16x8*)(pw + (mb * 16 + l16) * 72 + quad * 8);
      pa1[mb] = *(const bf16x8*)(pw + (mb * 16 + l16) * 72 + 32 + quad * 8);
    }
#pragma unroll
    for (int cb = 0; cb < 4; ++cb) {
      const bf16x8 vb0 = *(const bf16x8*)(Vs + (cb * 16 + l16) * 72 + quad * 8);
      const bf16x8 vb1 = *(const bf16x8*)(Vs + (cb * 16 + l16) * 72 + 32 + quad * 8);
#pragma unroll
      for (int mb = 0; mb < 2; ++mb) {
        oacc[mb][cb] = __builtin_amdgcn_mfma_f32_16x16x32_bf16(pa0[mb], vb0, oacc[mb][cb], 0, 0, 0);
        oacc[mb][cb] = __builtin_amdgcn_mfma_f32_16x16x32_bf16(pa1[mb], vb1, oacc[mb][cb], 0, 0, 0);
      }
    }
  }

#pragma unroll
  for (int off = 8; off > 0; off >>= 1)
#pragma unroll
    for (int mb = 0; mb < 2; ++mb)
#pragma unroll
      for (int r = 0; r < 4; ++r) rs[mb][r] += __shfl_xor(rs[mb][r], off, 16);

#pragma unroll
  for (int mb = 0; mb < 2; ++mb) {
    float inv[4];
#pragma unroll
    for (int r = 0; r < 4; ++r) inv[r] = 1.0f / rs[mb][r];
#pragma unroll
    for (int cb = 0; cb < 4; ++cb)
#pragma unroll
      for (int r = 0; r < 4; ++r) {
        const int row = q0 + wave * 32 + mb * 16 + quad * 4 + r;
        ctx[xbase + (size_t)row * D + cb * 16 + l16] = f2bf(oacc[mb][cb][r] * inv[r]);
      }
  }
}

// ------------------------------ launcher -----------------------------------
extern "C" void kernel_launch(void* const* d_in, const int* in_sizes, int n_in,
                              void* d_out, int out_size, void* d_ws,
                              size_t ws_size, hipStream_t stream) {
  const float* x  = (const float*)d_in[0];
  const int* lengths = (const int*)d_in[1];
  const float* qW = (const float*)d_in[2];
  const float* qb = (const float*)d_in[3];
  const float* kW = (const float*)d_in[4];
  const float* kb = (const float*)d_in[5];
  const float* vW = (const float*)d_in[6];
  const float* vb = (const float*)d_in[7];
  const float* oW = (const float*)d_in[8];
  const float* ob = (const float*)d_in[9];
  const float* w1 = (const float*)d_in[10];
  const float* b1 = (const float*)d_in[11];
  const float* w2 = (const float*)d_in[12];
  const float* b2 = (const float*)d_in[13];
  float* out = (float*)d_out;

  const int Bx = 4, S = 2048, D = 1024, FF = 4096;
  const int M = Bx * S;  // 8192

  unsigned short* p = (unsigned short*)d_ws;
  unsigned short* xb  = p; p += (size_t)M * D;
  unsigned short* qWt = p; p += (size_t)D * D;   // contiguous [3072,1024]
  unsigned short* kWt = p; p += (size_t)D * D;
  unsigned short* vWt = p; p += (size_t)D * D;
  unsigned short* oWt = p; p += (size_t)D * D;
  unsigned short* w1t = p; p += (size_t)D * FF;   // [FF, D]
  unsigned short* w2t = p; p += (size_t)FF * D;   // [D, FF]
  unsigned short* Qb  = p; p += (size_t)M * D;
  unsigned short* Kb  = p; p += (size_t)M * D;
  unsigned short* Vtb = p; p += (size_t)M * D;    // [B,H,64,S]
  unsigned short* Cb  = p; p += (size_t)M * D;
  unsigned short* Ab  = p; p += (size_t)M * D;
  unsigned short* Hb  = p; p += (size_t)M * FF;

  {
    int n4 = (int)((size_t)M * D / 4);
    cast_f32_bf16<<<dim3((n4 + 255) / 256), dim3(256), 0, stream>>>(x, xb, n4);
  }
  prep_weights<<<dim3(6144), dim3(256), 0, stream>>>(
      qW, kW, vW, oW, w1, w2, qWt, kWt, vWt, oWt, w1t, w2t);

  // qkv: 256^2 core, M/256 x 3072/256 = 32 x 12 = 384 blocks
  gemm256_qkv<<<dim3(384), dim3(512), 0, stream>>>(
      xb, qWt, qb, kb, vb, Qb, Kb, Vtb, D);

  attn_fused<<<dim3(Bx * 16 * (S / 128)), dim3(256), 0, stream>>>(
      Qb, Kb, Vtb, lengths, Cb);

  // proj: R5 128^2 kernel (N=1024 -> 512 blocks, 2/CU)
  gemm_bt<1><<<dim3((D / 128) * (M / 128)), dim3(256), 0, stream>>>(
      Cb, oWt, ob, Ab, M, D, D);
  // ffn1: 256^2 core, 32 x 16 = 512 blocks
  gemm256_bt<2><<<dim3(512), dim3(512), 0, stream>>>(Ab, w1t, b1, Hb, FF, D);
  // ffn2: R5 128^2 kernel (N=1024 -> 512 blocks)
  gemm_bt<0><<<dim3((D / 128) * (M / 128)), dim3(256), 0, stream>>>(
      Hb, w2t, b2, out, M, D, FF);
}

// Round 3
// 505.241 us; speedup vs baseline: 1.0470x; 1.0470x over previous
//
#include <hip/hip_runtime.h>

// ---------------------------------------------------------------------------
// TransformerEncoder: B=4, S=2048, D=1024, H=16, HD=64, FF=4096
// Round 8: propagate the R7-VERIFIED depth-3 counted-vmcnt + both-sides-
// swizzle pipeline to a 128^2 core (4 waves) for qkv/proj/ffn2 (shapes where
// 256^2 tiles under-fill or imbalance the grid). ffn1 keeps the 256^2 core.
// Attention gets T14 async-STAGE: next tile's K/V global loads issued under
// the current tile's compute.
//
// Depth-3 ledger (verified in R7): BK=32, 4 LDS bufs per operand.
//   step t: vmcnt(8)  [each lane: 12 outstanding loads -> oldest 4 (tile t)
//                      landed; tiles t+1,t+2 in flight]
//           s_barrier [all waves agree buf t&3 valid; reads of (t-1)&3 done]
//           STAGE tile t+3 -> buf (t+3)&3 == (t-1)&3  [WAR-safe]
//           ds_read + MFMA from buf t&3 [disjoint from in-flight bufs]
//   tail: vmcnt(8)/(4)/(0). Requires NK = K/32 >= 4.
// Swizzle (both-sides, rule 21): LDS[row][chunk] = global[row][chunk ^ g],
//   g(row) = (row>>1)&3, chunk = 8 elem (16 B). Stage: source col pre-XOR'd,
//   LDS dest linear. Read: chunk quad -> LDS chunk quad ^ ((l16>>1)&3).
// ---------------------------------------------------------------------------

typedef short bf16x8 __attribute__((ext_vector_type(8)));
typedef float f32x4 __attribute__((ext_vector_type(4)));

__device__ __forceinline__ unsigned short f2bf(float f) {
  unsigned int u = __builtin_bit_cast(unsigned int, f);
  u += 0x7fffu + ((u >> 16) & 1u);   // round-to-nearest-even
  return (unsigned short)(u >> 16);
}

__device__ __forceinline__ void gload16(const unsigned short* g, unsigned short* l) {
  __builtin_amdgcn_global_load_lds(
      (const __attribute__((address_space(1))) unsigned int*)(g),
      (__attribute__((address_space(3))) unsigned int*)(l),
      16, 0, 0);
}

// --------------------------- cast fp32 -> bf16 -----------------------------
__global__ __launch_bounds__(256) void cast_f32_bf16(
    const float* __restrict__ src, unsigned short* __restrict__ dst, int n4) {
  int i = blockIdx.x * 256 + threadIdx.x;
  if (i < n4) {
    float4 f = ((const float4*)src)[i];
    ushort4 o;
    o.x = f2bf(f.x); o.y = f2bf(f.y); o.z = f2bf(f.z); o.w = f2bf(f.w);
    ((ushort4*)dst)[i] = o;
  }
}

// ---------------- merged weight prep: 6 transposes in one kernel -----------
__global__ __launch_bounds__(256) void prep_weights(
    const float* __restrict__ qW, const float* __restrict__ kW,
    const float* __restrict__ vW, const float* __restrict__ oW,
    const float* __restrict__ w1, const float* __restrict__ w2,
    unsigned short* __restrict__ qWt, unsigned short* __restrict__ kWt,
    unsigned short* __restrict__ vWt, unsigned short* __restrict__ oWt,
    unsigned short* __restrict__ w1t, unsigned short* __restrict__ w2t) {
  const int t = blockIdx.x;
  const float* W; unsigned short* Wt; int N, K, nt, kt;
  if (t < 2048) {
    const int w = t >> 9, r = t & 511;
    nt = r & 15; kt = r >> 4; N = 1024; K = 1024;
    W  = w == 0 ? qW : w == 1 ? kW : w == 2 ? vW : oW;
    Wt = w == 0 ? qWt : w == 1 ? kWt : w == 2 ? vWt : oWt;
  } else if (t < 4096) {
    const int r = t - 2048;
    nt = r & 63; kt = r >> 6; N = 4096; K = 1024; W = w1; Wt = w1t;
  } else {
    const int r = t - 4096;
    nt = r & 15; kt = r >> 4; N = 1024; K = 4096; W = w2; Wt = w2t;
  }
  const int wave = threadIdx.x >> 6, lane = threadIdx.x & 63;
  const int n = nt * 64 + lane;
  const int k0 = kt * 32 + wave * 8;
  union { int4 v; unsigned short u[8]; } s;
#pragma unroll
  for (int j = 0; j < 8; ++j) s.u[j] = f2bf(W[(size_t)(k0 + j) * N + n]);
  *(int4*)(Wt + (size_t)n * K + k0) = s.v;
}

// ------------------- 256x256 depth-3 GEMM core (B^T) -----------------------
// 8 waves as 2M x 4N, wave tile 128x64 (8x4 frags). LDS 4 bufs x [256][32].
__device__ __forceinline__ void gemm256_core(
    const unsigned short* __restrict__ A, const unsigned short* __restrict__ Bt,
    unsigned short* __restrict__ As, unsigned short* __restrict__ Bs,
    const int m0, const int n0, const int K, f32x4 (&acc)[8][4]) {
  const int tid = (int)threadIdx.x;
  const int w = tid >> 6, l = tid & 63;
  const int quad = l >> 4, l16 = l & 15;
  const int wm = (w >> 2) * 128, wn = (w & 3) * 64;

  const int lr = l >> 2, lc = l & 3;
  const int swz = (lc ^ ((l >> 3) & 3)) * 8;
  const unsigned short* gA[2]; const unsigned short* gB[2];
  unsigned short* dA[2]; unsigned short* dB[2];
#pragma unroll
  for (int j = 0; j < 2; ++j) {
    const int rr = (w * 2 + j) * 16 + lr;
    gA[j] = A + (size_t)(m0 + rr) * K + swz;
    gB[j] = Bt + (size_t)(n0 + rr) * K + swz;
    dA[j] = As + (w * 2 + j) * 512;
    dB[j] = Bs + (w * 2 + j) * 512;
  }

  const int cread = (quad ^ ((l16 >> 1) & 3)) * 8;
  const int rA = (wm + l16) * 32;
  const int rB = (wn + l16) * 32;

  auto STAGE = [&](int db, int t) {
#pragma unroll
    for (int j = 0; j < 2; ++j) {
      gload16(gA[j] + t * 32, dA[j] + db * 8192);
      gload16(gB[j] + t * 32, dB[j] + db * 8192);
    }
  };
  auto COMPUTE = [&](int db) {
    bf16x8 af[8], bf[4];
    const unsigned short* pa = As + db * 8192 + rA + cread;
    const unsigned short* pb = Bs + db * 8192 + rB + cread;
#pragma unroll
    for (int ni = 0; ni < 4; ++ni) bf[ni] = *(const bf16x8*)(pb + ni * 16 * 32);
#pragma unroll
    for (int mi = 0; mi < 8; ++mi) af[mi] = *(const bf16x8*)(pa + mi * 16 * 32);
    __builtin_amdgcn_s_setprio(1);
#pragma unroll
    for (int mi = 0; mi < 8; ++mi)
#pragma unroll
      for (int ni = 0; ni < 4; ++ni)
        acc[mi][ni] = __builtin_amdgcn_mfma_f32_16x16x32_bf16(
            af[mi], bf[ni], acc[mi][ni], 0, 0, 0);
    __builtin_amdgcn_s_setprio(0);
  };

  const int NK = K >> 5;   // >= 4
  STAGE(0, 0); STAGE(1, 1); STAGE(2, 2);
#pragma unroll 1
  for (int t = 0; t < NK - 3; ++t) {
    asm volatile("s_waitcnt vmcnt(8)" ::: "memory");
    __builtin_amdgcn_s_barrier();
    STAGE((t + 3) & 3, t + 3);
    COMPUTE(t & 3);
  }
  asm volatile("s_waitcnt vmcnt(8)" ::: "memory");
  __builtin_amdgcn_s_barrier();
  COMPUTE((NK - 3) & 3);
  asm volatile("s_waitcnt vmcnt(4)" ::: "memory");
  __builtin_amdgcn_s_barrier();
  COMPUTE((NK - 2) & 3);
  asm volatile("s_waitcnt vmcnt(0)" ::: "memory");
  __builtin_amdgcn_s_barrier();
  COMPUTE((NK - 1) & 3);
}

// ------------------- 128x128 depth-3 GEMM core (B^T) -----------------------
// 4 waves as 2M x 2N, wave tile 64x64 (4x4 frags). LDS 4 bufs x [128][32]
// per operand (32 KB each, 64 KB total -> 2 blocks/CU). Same ledger/swizzle.
__device__ __forceinline__ void gemm128_core(
    const unsigned short* __restrict__ A, const unsigned short* __restrict__ Bt,
    unsigned short* __restrict__ As, unsigned short* __restrict__ Bs,
    const int m0, const int n0, const int K, f32x4 (&acc)[4][4]) {
  const int tid = (int)threadIdx.x;
  const int w = tid >> 6, l = tid & 63;
  const int quad = l >> 4, l16 = l & 15;
  const int wm = (w >> 1) * 64, wn = (w & 1) * 64;

  const int lr = l >> 2, lc = l & 3;
  const int swz = (lc ^ ((l >> 3) & 3)) * 8;
  const unsigned short* gA[2]; const unsigned short* gB[2];
  unsigned short* dA[2]; unsigned short* dB[2];
#pragma unroll
  for (int j = 0; j < 2; ++j) {
    const int rr = (w * 2 + j) * 16 + lr;    // waves 0..3 cover rows 0..127
    gA[j] = A + (size_t)(m0 + rr) * K + swz;
    gB[j] = Bt + (size_t)(n0 + rr) * K + swz;
    dA[j] = As + (w * 2 + j) * 512;
    dB[j] = Bs + (w * 2 + j) * 512;
  }

  const int cread = (quad ^ ((l16 >> 1) & 3)) * 8;
  const int rA = (wm + l16) * 32;
  const int rB = (wn + l16) * 32;

  auto STAGE = [&](int db, int t) {
#pragma unroll
    for (int j = 0; j < 2; ++j) {
      gload16(gA[j] + t * 32, dA[j] + db * 4096);
      gload16(gB[j] + t * 32, dB[j] + db * 4096);
    }
  };
  auto COMPUTE = [&](int db) {
    bf16x8 af[4], bf[4];
    const unsigned short* pa = As + db * 4096 + rA + cread;
    const unsigned short* pb = Bs + db * 4096 + rB + cread;
#pragma unroll
    for (int ni = 0; ni < 4; ++ni) bf[ni] = *(const bf16x8*)(pb + ni * 16 * 32);
#pragma unroll
    for (int mi = 0; mi < 4; ++mi) af[mi] = *(const bf16x8*)(pa + mi * 16 * 32);
    __builtin_amdgcn_s_setprio(1);
#pragma unroll
    for (int mi = 0; mi < 4; ++mi)
#pragma unroll
      for (int ni = 0; ni < 4; ++ni)
        acc[mi][ni] = __builtin_amdgcn_mfma_f32_16x16x32_bf16(
            af[mi], bf[ni], acc[mi][ni], 0, 0, 0);
    __builtin_amdgcn_s_setprio(0);
  };

  const int NK = K >> 5;   // >= 4
  STAGE(0, 0); STAGE(1, 1); STAGE(2, 2);
#pragma unroll 1
  for (int t = 0; t < NK - 3; ++t) {
    asm volatile("s_waitcnt vmcnt(8)" ::: "memory");
    __builtin_amdgcn_s_barrier();
    STAGE((t + 3) & 3, t + 3);
    COMPUTE(t & 3);
  }
  asm volatile("s_waitcnt vmcnt(8)" ::: "memory");
  __builtin_amdgcn_s_barrier();
  COMPUTE((NK - 3) & 3);
  asm volatile("s_waitcnt vmcnt(4)" ::: "memory");
  __builtin_amdgcn_s_barrier();
  COMPUTE((NK - 2) & 3);
  asm volatile("s_waitcnt vmcnt(0)" ::: "memory");
  __builtin_amdgcn_s_barrier();
  COMPUTE((NK - 1) & 3);
}

// --------------------- 256^2 GEMM (B^T), generic epilogue ------------------
template <int EPI>
__global__ __launch_bounds__(512, 1) void gemm256_bt(
    const unsigned short* __restrict__ A, const unsigned short* __restrict__ Bt,
    const float* __restrict__ bias, void* __restrict__ C, int N, int K) {
  __shared__ unsigned short As[4 * 8192];
  __shared__ unsigned short Bs[4 * 8192];
  const int tn = N >> 8;
  const int cpx = (int)gridDim.x >> 3;
  const int sw = ((int)blockIdx.x & 7) * cpx + ((int)blockIdx.x >> 3);
  const int nt = sw % tn, mt = sw / tn;
  const int m0 = mt * 256, n0 = nt * 256;

  f32x4 acc[8][4] = {};
  gemm256_core(A, Bt, As, Bs, m0, n0, K, acc);

  const int tid = (int)threadIdx.x;
  const int w = tid >> 6, l = tid & 63;
  const int quad = l >> 4, l16 = l & 15;
  const int wm = (w >> 2) * 128, wn = (w & 3) * 64;
#pragma unroll
  for (int ni = 0; ni < 4; ++ni) {
    const int col = n0 + wn + ni * 16 + l16;
    const float bv = bias[col];
#pragma unroll
    for (int mi = 0; mi < 8; ++mi) {
      const int row = m0 + wm + mi * 16 + quad * 4;
#pragma unroll
      for (int r = 0; r < 4; ++r) {
        float v = acc[mi][ni][r] + bv;
        if (EPI == 2) v = v > 0.f ? v : 0.f;
        if (EPI == 0)
          ((float*)C)[(size_t)(row + r) * N + col] = v;
        else
          ((unsigned short*)C)[(size_t)(row + r) * N + col] = f2bf(v);
      }
    }
  }
}

// --------------------- 128^2 GEMM (B^T), generic epilogue ------------------
// XCD swizzle (R5-verified mapping): xcd owns an n-band of NT/8 tiles.
template <int EPI>
__global__ __launch_bounds__(256, 2) void gemm128_bt(
    const unsigned short* __restrict__ A, const unsigned short* __restrict__ Bt,
    const float* __restrict__ bias, void* __restrict__ C, int N, int K) {
  __shared__ unsigned short As[4 * 4096];
  __shared__ unsigned short Bs[4 * 4096];
  const int NT = N >> 7, band = NT >> 3;
  const int xcd = blockIdx.x & 7, local = blockIdx.x >> 3;
  const int nt = xcd * band + local % band;
  const int mt = local / band;
  const int m0 = mt * 128, n0 = nt * 128;

  f32x4 acc[4][4] = {};
  gemm128_core(A, Bt, As, Bs, m0, n0, K, acc);

  const int tid = (int)threadIdx.x;
  const int w = tid >> 6, l = tid & 63;
  const int quad = l >> 4, l16 = l & 15;
  const int wm = (w >> 1) * 64, wn = (w & 1) * 64;
#pragma unroll
  for (int ni = 0; ni < 4; ++ni) {
    const int col = n0 + wn + ni * 16 + l16;
    const float bv = bias[col];
#pragma unroll
    for (int mi = 0; mi < 4; ++mi) {
      const int row = m0 + wm + mi * 16 + quad * 4;
#pragma unroll
      for (int r = 0; r < 4; ++r) {
        float v = acc[mi][ni][r] + bv;
        if (EPI == 2) v = v > 0.f ? v : 0.f;
        if (EPI == 0)
          ((float*)C)[(size_t)(row + r) * N + col] = v;
        else
          ((unsigned short*)C)[(size_t)(row + r) * N + col] = f2bf(v);
      }
    }
  }
}

// --------------------------- fused QKV GEMM (128^2) ------------------------
#define QSCALE 0.180336884f   // 0.125 * log2(e)

__global__ __launch_bounds__(256, 2) void gemm128_qkv(
    const unsigned short* __restrict__ A, const unsigned short* __restrict__ Bt,
    const float* __restrict__ qb, const float* __restrict__ kb,
    const float* __restrict__ vb, unsigned short* __restrict__ Qo,
    unsigned short* __restrict__ Ko, unsigned short* __restrict__ Vto, int K) {
  __shared__ unsigned short As[4 * 4096];
  __shared__ unsigned short Bs[4 * 4096];
  const int NT = 24, band = 3;                 // N = 3072
  const int xcd = blockIdx.x & 7, local = blockIdx.x >> 3;
  const int nt = xcd * band + local % band;
  const int mt = local / band;
  const int m0 = mt * 128, n0 = nt * 128;

  f32x4 acc[4][4] = {};
  gemm128_core(A, Bt, As, Bs, m0, n0, K, acc);

  const int tid = (int)threadIdx.x;
  const int w = tid >> 6, l = tid & 63;
  const int quad = l >> 4, l16 = l & 15;
  const int wm = (w >> 1) * 64, wn = (w & 1) * 64;

  const int seg = n0 >> 10;                    // 0=Q, 1=K, 2=V (block-uniform)
  const float* bias = seg == 0 ? qb : (seg == 1 ? kb : vb);
#pragma unroll
  for (int ni = 0; ni < 4; ++ni) {
    const int col = (n0 + wn + ni * 16 + l16) & 1023;
    const float bv = bias[col];
#pragma unroll
    for (int mi = 0; mi < 4; ++mi) {
      const int row = m0 + wm + mi * 16 + quad * 4;
      if (seg == 2) {
        const int b = row >> 11, s = row & 2047;
        const int hh = col >> 6, dh = col & 63;
        union { ushort4 v; unsigned short u[4]; } pk;
#pragma unroll
        for (int r = 0; r < 4; ++r) pk.u[r] = f2bf(acc[mi][ni][r] + bv);
        *(ushort4*)(Vto + ((size_t)((b * 16 + hh) * 64 + dh)) * 2048 + s) = pk.v;
      } else if (seg == 0) {
#pragma unroll
        for (int r = 0; r < 4; ++r)
          Qo[(size_t)(row + r) * 1024 + col] = f2bf((acc[mi][ni][r] + bv) * QSCALE);
      } else {
#pragma unroll
        for (int r = 0; r < 4; ++r)
          Ko[(size_t)(row + r) * 1024 + col] = f2bf(acc[mi][ni][r] + bv);
      }
    }
  }
}

// --------------------------- flash attention -------------------------------
// T14 async-STAGE: next tile's K/V global loads are issued right after the
// second barrier, so HBM latency hides under QK+softmax+PV compute; the
// loaded regs are written to LDS at the next iteration's staging slot.
__global__ __launch_bounds__(256, 4) void attn_fused(
    const unsigned short* __restrict__ Q, const unsigned short* __restrict__ K,
    const unsigned short* __restrict__ Vt, const int* __restrict__ lengths,
    unsigned short* __restrict__ ctx) {
  constexpr int S = 2048, D = 1024;
  __shared__ unsigned short Ks[64 * 72];
  __shared__ unsigned short Vs[64 * 72];
  __shared__ unsigned short Ps[4 * 32 * 72];

  const int tid = threadIdx.x;
  const int wave = tid >> 6, lane = tid & 63;
  const int quad = lane >> 4, l16 = lane & 15;
  const int bid = blockIdx.x;
  const int qt = bid & 15;
  const int h = (bid >> 4) & 15;
  const int b = bid >> 8;
  const int q0 = qt * 128;
  const int len = lengths[b];
  const int ktEnd = (len + 63) >> 6;
  const float NEGINF = -__builtin_inff();

  const size_t xbase = (size_t)b * S * D + (size_t)h * 64;
  const size_t vtb = (size_t)(b * 16 + h) * 64;

  bf16x8 qf0[2], qf1[2];
#pragma unroll
  for (int mb = 0; mb < 2; ++mb) {
    const unsigned short* qrow =
        Q + xbase + (size_t)(q0 + wave * 32 + mb * 16 + l16) * D;
    qf0[mb] = *(const bf16x8*)(qrow + quad * 8);
    qf1[mb] = *(const bf16x8*)(qrow + 32 + quad * 8);
  }

  const int sr1 = tid >> 3, sc1 = (tid & 7) * 8;
  const int sr2 = (256 + tid) >> 3, sc2 = (tid & 7) * 8;
  const unsigned short* kg1 = K + xbase + (size_t)sr1 * D + sc1;
  const unsigned short* kg2 = K + xbase + (size_t)sr2 * D + sc2;
  const unsigned short* vg1 = Vt + (vtb + sr1) * S + sc1;
  const unsigned short* vg2 = Vt + (vtb + sr2) * S + sc2;

  f32x4 oacc[2][4] = {};
  float rs[2][4] = {};

  unsigned short* pw = Ps + wave * (32 * 72);

  int4 kr1, kr2, vr1, vr2;
  {
    kr1 = *(const int4*)(kg1);
    kr2 = *(const int4*)(kg2);
    vr1 = *(const int4*)(vg1);
    vr2 = *(const int4*)(vg2);
  }

  for (int kt = 0; kt < ktEnd; ++kt) {
    const int k0 = kt * 64;
    __syncthreads();
    *(int4*)(Ks + sr1 * 72 + sc1) = kr1;
    *(int4*)(Ks + sr2 * 72 + sc2) = kr2;
    *(int4*)(Vs + sr1 * 72 + sc1) = vr1;
    *(int4*)(Vs + sr2 * 72 + sc2) = vr2;
    __syncthreads();

    if (kt + 1 < ktEnd) {            // async prefetch of next tile
      const int kn = (kt + 1) * 64;
      kr1 = *(const int4*)(kg1 + (size_t)kn * D);
      kr2 = *(const int4*)(kg2 + (size_t)kn * D);
      vr1 = *(const int4*)(vg1 + kn);
      vr2 = *(const int4*)(vg2 + kn);
    }

    f32x4 sf[2][4];
#pragma unroll
    for (int cb = 0; cb < 4; ++cb) {
      const bf16x8 kf0 = *(const bf16x8*)(Ks + (cb * 16 + l16) * 72 + quad * 8);
      const bf16x8 kf1 = *(const bf16x8*)(Ks + (cb * 16 + l16) * 72 + 32 + quad * 8);
#pragma unroll
      for (int mb = 0; mb < 2; ++mb) {
        f32x4 c = {0.f, 0.f, 0.f, 0.f};
        c = __builtin_amdgcn_mfma_f32_16x16x32_bf16(qf0[mb], kf0, c, 0, 0, 0);
        c = __builtin_amdgcn_mfma_f32_16x16x32_bf16(qf1[mb], kf1, c, 0, 0, 0);
        sf[mb][cb] = c;
      }
    }

    if (k0 + 64 > len) {
#pragma unroll
      for (int cb = 0; cb < 4; ++cb) {
        const bool msk = (k0 + cb * 16 + l16) >= len;
#pragma unroll
        for (int mb = 0; mb < 2; ++mb)
#pragma unroll
          for (int r = 0; r < 4; ++r) sf[mb][cb][r] = msk ? NEGINF : sf[mb][cb][r];
      }
    }

#pragma unroll
    for (int mb = 0; mb < 2; ++mb)
#pragma unroll
      for (int cb = 0; cb < 4; ++cb)
#pragma unroll
        for (int r = 0; r < 4; ++r) {
          const float p = __builtin_amdgcn_exp2f(sf[mb][cb][r]);
          sf[mb][cb][r] = p;
          rs[mb][r] += p;
        }

#pragma unroll
    for (int mb = 0; mb < 2; ++mb)
#pragma unroll
      for (int cb = 0; cb < 4; ++cb)
#pragma unroll
        for (int r = 0; r < 4; ++r)
          pw[(mb * 16 + quad * 4 + r) * 72 + cb * 16 + l16] = f2bf(sf[mb][cb][r]);

    bf16x8 pa0[2], pa1[2];
#pragma unroll
    for (int mb = 0; mb < 2; ++mb) {
      pa0[mb] = *(const bf16x8*)(pw + (mb * 16 + l16) * 72 + quad * 8);
      pa1[mb] = *(const bf16x8*)(pw + (mb * 16 + l16) * 72 + 32 + quad * 8);
    }
#pragma unroll
    for (int cb = 0; cb < 4; ++cb) {
      const bf16x8 vb0 = *(const bf16x8*)(Vs + (cb * 16 + l16) * 72 + quad * 8);
      const bf16x8 vb1 = *(const bf16x8*)(Vs + (cb * 16 + l16) * 72 + 32 + quad * 8);
#pragma unroll
      for (int mb = 0; mb < 2; ++mb) {
        oacc[mb][cb] = __builtin_amdgcn_mfma_f32_16x16x32_bf16(pa0[mb], vb0, oacc[mb][cb], 0, 0, 0);
        oacc[mb][cb] = __builtin_amdgcn_mfma_f32_16x16x32_bf16(pa1[mb], vb1, oacc[mb][cb], 0, 0, 0);
      }
    }
  }

#pragma unroll
  for (int off = 8; off > 0; off >>= 1)
#pragma unroll
    for (int mb = 0; mb < 2; ++mb)
#pragma unroll
      for (int r = 0; r < 4; ++r) rs[mb][r] += __shfl_xor(rs[mb][r], off, 16);

#pragma unroll
  for (int mb = 0; mb < 2; ++mb) {
    float inv[4];
#pragma unroll
    for (int r = 0; r < 4; ++r) inv[r] = 1.0f / rs[mb][r];
#pragma unroll
    for (int cb = 0; cb < 4; ++cb)
#pragma unroll
      for (int r = 0; r < 4; ++r) {
        const int row = q0 + wave * 32 + mb * 16 + quad * 4 + r;
        ctx[xbase + (size_t)row * D + cb * 16 + l16] = f2bf(oacc[mb][cb][r] * inv[r]);
      }
  }
}

// ------------------------------ launcher -----------------------------------
extern "C" void kernel_launch(void* const* d_in, const int* in_sizes, int n_in,
                              void* d_out, int out_size, void* d_ws,
                              size_t ws_size, hipStream_t stream) {
  const float* x  = (const float*)d_in[0];
  const int* lengths = (const int*)d_in[1];
  const float* qW = (const float*)d_in[2];
  const float* qb = (const float*)d_in[3];
  const float* kW = (const float*)d_in[4];
  const float* kb = (const float*)d_in[5];
  const float* vW = (const float*)d_in[6];
  const float* vb = (const float*)d_in[7];
  const float* oW = (const float*)d_in[8];
  const float* ob = (const float*)d_in[9];
  const float* w1 = (const float*)d_in[10];
  const float* b1 = (const float*)d_in[11];
  const float* w2 = (const float*)d_in[12];
  const float* b2 = (const float*)d_in[13];
  float* out = (float*)d_out;

  const int Bx = 4, S = 2048, D = 1024, FF = 4096;
  const int M = Bx * S;  // 8192

  unsigned short* p = (unsigned short*)d_ws;
  unsigned short* xb  = p; p += (size_t)M * D;
  unsigned short* qWt = p; p += (size_t)D * D;   // contiguous [3072,1024]
  unsigned short* kWt = p; p += (size_t)D * D;
  unsigned short* vWt = p; p += (size_t)D * D;
  unsigned short* oWt = p; p += (size_t)D * D;
  unsigned short* w1t = p; p += (size_t)D * FF;   // [FF, D]
  unsigned short* w2t = p; p += (size_t)FF * D;   // [D, FF]
  unsigned short* Qb  = p; p += (size_t)M * D;
  unsigned short* Kb  = p; p += (size_t)M * D;
  unsigned short* Vtb = p; p += (size_t)M * D;    // [B,H,64,S]
  unsigned short* Cb  = p; p += (size_t)M * D;
  unsigned short* Ab  = p; p += (size_t)M * D;
  unsigned short* Hb  = p; p += (size_t)M * FF;

  {
    int n4 = (int)((size_t)M * D / 4);
    cast_f32_bf16<<<dim3((n4 + 255) / 256), dim3(256), 0, stream>>>(x, xb, n4);
  }
  prep_weights<<<dim3(6144), dim3(256), 0, stream>>>(
      qW, kW, vW, oW, w1, w2, qWt, kWt, vWt, oWt, w1t, w2t);

  // qkv: 128^2 depth-3 core, 24 x 64 = 1536 blocks (balanced, 2/CU resident)
  gemm128_qkv<<<dim3(1536), dim3(256), 0, stream>>>(
      xb, qWt, qb, kb, vb, Qb, Kb, Vtb, D);

  attn_fused<<<dim3(Bx * 16 * (S / 128)), dim3(256), 0, stream>>>(
      Qb, Kb, Vtb, lengths, Cb);

  // proj: 128^2 depth-3 core, 8 x 64 = 512 blocks
  gemm128_bt<1><<<dim3(512), dim3(256), 0, stream>>>(Cb, oWt, ob, Ab, D, D);
  // ffn1: 256^2 depth-3 core, 32 x 16 = 512 blocks
  gemm256_bt<2><<<dim3(512), dim3(512), 0, stream>>>(Ab, w1t, b1, Hb, FF, D);
  // ffn2: 128^2 depth-3 core, 8 x 64 = 512 blocks (K=4096: 128 K-steps)
  gemm128_bt<0><<<dim3(512), dim3(256), 0, stream>>>(Hb, w2t, b2, out, D, FF);
}

// Round 4
// 490.558 us; speedup vs baseline: 1.0783x; 1.0299x over previous
//
#include <hip/hip_runtime.h>

// ---------------------------------------------------------------------------
// TransformerEncoder: B=4, S=2048, D=1024, H=16, HD=64, FF=4096
// Round 9: true 8-phase counted-vmcnt 256^2 core (T3+T4, per-wave-proven
// ledger) for ffn1 + qkv. proj/ffn2 keep the R8-verified depth-3 128^2 core;
// attention (T14 async-stage) / cast / prep unchanged.
//
// 8-phase ledger (PER-WAVE derivation — the R6 failure was global reasoning):
//   BK=64, LDS = 2 dbuf x [256][64] per operand (128 KB). Load-round =
//   64 rows x 64 cols = 8 KB = 1 gload16/thread; A rounds a0..a3, B b0..b3
//   (round X covers rows [64X, 64X+64)). Wave w (wm=(w>>2)*128, wn=(w&3)*64)
//   reads: A round 2*(w>>2)+mh at its mh-phase; B round (w&3) at P1/P2.
//   Tile t computes buf c=t&1, phases P1(mh0,nh0) P2(mh0,nh1) P3(mh1,nh1)
//   P4(mh1,nh0); stages tile t+1 into buf c^1:
//     P1: b0,b1   P2: b2,b3   P3: a0,a2   P4: a1,a3
//   Global needs: t+1.P1 <= {b0..b3,a0,a2} (oldest 6 of 8); t+1.P3 <= {a1,a3}.
//   Waits: P4-end vmcnt(2)  [8 outstanding -> oldest 6 land = t+1.P1 need]
//          P2-end vmcnt(4)  [2 odd-A(t) + 4 B(t+1) -> oldest 2 = t.P3 need]
//   WAR: every stage into buf c^1 targets regions whose last reads ended
//   >= 2 barriers earlier (B regions: read at t-1.P1/P2; A-even: t-1.P1/P2
//   ... A regions: last ds_read t-1.P3, barrier-closed). In-flight odd-A
//   writes during t+1.P1/P2 target rows {64-128,192-256} of buf c^1 while
//   P1/P2 read rows {0-64,128-192} (mh0) — disjoint.
//   Publishing: every wave issues its own lane-slice of every round in the
//   same program order, so per-wave vmcnt + barrier publishes globally.
//   Tail (t=NK-1): no stages; P2-end vmcnt(0); P4-end no wait.
// Swizzle (both-sides, rule 21): LDS[row][chunk]=global[row][chunk^(row&7)],
//   chunk=16B. Stage: row = 8w+(l>>3) -> source chunk (l&7)^(l>>3), LDS
//   linear. Read: chunk (kk*4+quad)^(l16&7). 16 lanes -> 8 chunk-slots x2
//   rows (1024B apart, same bank) = 2-way = free.
// ---------------------------------------------------------------------------

typedef short bf16x8 __attribute__((ext_vector_type(8)));
typedef float f32x4 __attribute__((ext_vector_type(4)));

__device__ __forceinline__ unsigned short f2bf(float f) {
  unsigned int u = __builtin_bit_cast(unsigned int, f);
  u += 0x7fffu + ((u >> 16) & 1u);   // round-to-nearest-even
  return (unsigned short)(u >> 16);
}

__device__ __forceinline__ void gload16(const unsigned short* g, unsigned short* l) {
  __builtin_amdgcn_global_load_lds(
      (const __attribute__((address_space(1))) unsigned int*)(g),
      (__attribute__((address_space(3))) unsigned int*)(l),
      16, 0, 0);
}

// --------------------------- cast fp32 -> bf16 -----------------------------
__global__ __launch_bounds__(256) void cast_f32_bf16(
    const float* __restrict__ src, unsigned short* __restrict__ dst, int n4) {
  int i = blockIdx.x * 256 + threadIdx.x;
  if (i < n4) {
    float4 f = ((const float4*)src)[i];
    ushort4 o;
    o.x = f2bf(f.x); o.y = f2bf(f.y); o.z = f2bf(f.z); o.w = f2bf(f.w);
    ((ushort4*)dst)[i] = o;
  }
}

// ---------------- merged weight prep: 6 transposes in one kernel -----------
__global__ __launch_bounds__(256) void prep_weights(
    const float* __restrict__ qW, const float* __restrict__ kW,
    const float* __restrict__ vW, const float* __restrict__ oW,
    const float* __restrict__ w1, const float* __restrict__ w2,
    unsigned short* __restrict__ qWt, unsigned short* __restrict__ kWt,
    unsigned short* __restrict__ vWt, unsigned short* __restrict__ oWt,
    unsigned short* __restrict__ w1t, unsigned short* __restrict__ w2t) {
  const int t = blockIdx.x;
  const float* W; unsigned short* Wt; int N, K, nt, kt;
  if (t < 2048) {
    const int w = t >> 9, r = t & 511;
    nt = r & 15; kt = r >> 4; N = 1024; K = 1024;
    W  = w == 0 ? qW : w == 1 ? kW : w == 2 ? vW : oW;
    Wt = w == 0 ? qWt : w == 1 ? kWt : w == 2 ? vWt : oWt;
  } else if (t < 4096) {
    const int r = t - 2048;
    nt = r & 63; kt = r >> 6; N = 4096; K = 1024; W = w1; Wt = w1t;
  } else {
    const int r = t - 4096;
    nt = r & 15; kt = r >> 4; N = 1024; K = 4096; W = w2; Wt = w2t;
  }
  const int wave = threadIdx.x >> 6, lane = threadIdx.x & 63;
  const int n = nt * 64 + lane;
  const int k0 = kt * 32 + wave * 8;
  union { int4 v; unsigned short u[8]; } s;
#pragma unroll
  for (int j = 0; j < 8; ++j) s.u[j] = f2bf(W[(size_t)(k0 + j) * N + n]);
  *(int4*)(Wt + (size_t)n * K + k0) = s.v;
}

// ---------------- 256x256 8-phase counted-vmcnt core (B^T) -----------------
// 8 waves 2Mx4N, wave tile 128x64 (8x4 frags), BK=64 (2 kk). See file header.
__device__ __forceinline__ void gemm256_8ph(
    const unsigned short* __restrict__ A, const unsigned short* __restrict__ Bt,
    unsigned short* __restrict__ As, unsigned short* __restrict__ Bs,
    const int m0, const int n0, const int K, f32x4 (&acc)[8][4]) {
  const int tid = (int)threadIdx.x;
  const int w = tid >> 6, l = tid & 63;
  const int quad = l >> 4, l16 = l & 15;
  const int wm = (w >> 2) * 128, wn = (w & 3) * 64;

  // staging (per round: 64 rows x 64 cols; wave w covers rows 8w..8w+8)
  const int srow = w * 8 + (l >> 3);
  const int schunk = ((l & 7) ^ (l >> 3)) * 8;
  const unsigned short* gA = A + (size_t)(m0 + srow) * K + schunk;
  const unsigned short* gB = Bt + (size_t)(n0 + srow) * K + schunk;
  const int ldsW = w * 512;   // wave-uniform LDS offset within a round

  // ds_read swizzled chunk offsets (elements)
  const int xr = l16 & 7;
  const int c0 = ((0 + quad) ^ xr) * 8;   // kk=0: chunks 0..3
  const int c1 = ((4 + quad) ^ xr) * 8;   // kk=1: chunks 4..7

  bf16x8 af[4][2], bf0[2][2], bf1[2][2];

  auto STA = [&](int buf, int a, int t) {
    gload16(gA + (size_t)(a * 64) * K + t * 64,
            As + buf * 16384 + a * 4096 + ldsW);
  };
  auto STB = [&](int buf, int a, int t) {
    gload16(gB + (size_t)(a * 64) * K + t * 64,
            Bs + buf * 16384 + a * 4096 + ldsW);
  };
  auto LDA = [&](int buf, int mh) {
    const unsigned short* p = As + buf * 16384 + (wm + mh * 64 + l16) * 64;
#pragma unroll
    for (int mi = 0; mi < 4; ++mi) {
      af[mi][0] = *(const bf16x8*)(p + mi * 16 * 64 + c0);
      af[mi][1] = *(const bf16x8*)(p + mi * 16 * 64 + c1);
    }
  };
  auto LDB = [&](int buf, int nh, bf16x8 (&bf)[2][2]) {
    const unsigned short* p = Bs + buf * 16384 + (wn + nh * 32 + l16) * 64;
#pragma unroll
    for (int ni = 0; ni < 2; ++ni) {
      bf[ni][0] = *(const bf16x8*)(p + ni * 16 * 64 + c0);
      bf[ni][1] = *(const bf16x8*)(p + ni * 16 * 64 + c1);
    }
  };
  auto MM = [&](int mh, int nh, bf16x8 (&bf)[2][2]) {
    __builtin_amdgcn_s_setprio(1);
#pragma unroll
    for (int mi = 0; mi < 4; ++mi)
#pragma unroll
      for (int ni = 0; ni < 2; ++ni) {
        f32x4& a = acc[mh * 4 + mi][nh * 2 + ni];
        a = __builtin_amdgcn_mfma_f32_16x16x32_bf16(af[mi][0], bf[ni][0], a, 0, 0, 0);
        a = __builtin_amdgcn_mfma_f32_16x16x32_bf16(af[mi][1], bf[ni][1], a, 0, 0, 0);
      }
    __builtin_amdgcn_s_setprio(0);
  };

  const int NK = K >> 6;   // >= 2
  // prologue: tile 0 rounds in order b0..b3, a0, a2, a1, a3
  STB(0, 0, 0); STB(0, 1, 0); STB(0, 2, 0); STB(0, 3, 0);
  STA(0, 0, 0); STA(0, 2, 0); STA(0, 1, 0); STA(0, 3, 0);
  asm volatile("s_waitcnt vmcnt(2)" ::: "memory");
  __builtin_amdgcn_s_barrier();

#pragma unroll 1
  for (int t = 0; t < NK; ++t) {
    const int c = t & 1, nb = c ^ 1;
    const bool st = (t + 1 < NK);
    // ---- P1 (mh0, nh0)
    LDA(c, 0); LDB(c, 0, bf0);
    if (st) { STB(nb, 0, t + 1); STB(nb, 1, t + 1); }
    __builtin_amdgcn_s_barrier();
    asm volatile("s_waitcnt lgkmcnt(0)" ::: "memory");
    __builtin_amdgcn_sched_barrier(0);
    MM(0, 0, bf0);
    __builtin_amdgcn_s_barrier();
    // ---- P2 (mh0, nh1)
    LDB(c, 1, bf1);
    if (st) { STB(nb, 2, t + 1); STB(nb, 3, t + 1); }
    __builtin_amdgcn_s_barrier();
    asm volatile("s_waitcnt lgkmcnt(0)" ::: "memory");
    __builtin_amdgcn_sched_barrier(0);
    MM(0, 1, bf1);
    if (st) asm volatile("s_waitcnt vmcnt(4)" ::: "memory");
    else    asm volatile("s_waitcnt vmcnt(0)" ::: "memory");
    __builtin_amdgcn_s_barrier();
    // ---- P3 (mh1, nh1)
    LDA(c, 1);
    if (st) { STA(nb, 0, t + 1); STA(nb, 2, t + 1); }
    __builtin_amdgcn_s_barrier();
    asm volatile("s_waitcnt lgkmcnt(0)" ::: "memory");
    __builtin_amdgcn_sched_barrier(0);
    MM(1, 1, bf1);
    __builtin_amdgcn_s_barrier();
    // ---- P4 (mh1, nh0) — no new ds_reads (af from P3, bf0 from P1)
    if (st) { STA(nb, 1, t + 1); STA(nb, 3, t + 1); }
    __builtin_amdgcn_s_barrier();
    MM(1, 0, bf0);
    if (st) asm volatile("s_waitcnt vmcnt(2)" ::: "memory");
    __builtin_amdgcn_s_barrier();
  }
}

// --------------------- 256^2 GEMM (B^T), generic epilogue ------------------
template <int EPI>
__global__ __launch_bounds__(512, 1) void gemm256_bt(
    const unsigned short* __restrict__ A, const unsigned short* __restrict__ Bt,
    const float* __restrict__ bias, void* __restrict__ C, int N, int K) {
  __shared__ unsigned short As[2 * 16384];
  __shared__ unsigned short Bs[2 * 16384];
  const int tn = N >> 8;
  const int cpx = (int)gridDim.x >> 3;
  const int sw = ((int)blockIdx.x & 7) * cpx + ((int)blockIdx.x >> 3);
  const int nt = sw % tn, mt = sw / tn;
  const int m0 = mt * 256, n0 = nt * 256;

  f32x4 acc[8][4] = {};
  gemm256_8ph(A, Bt, As, Bs, m0, n0, K, acc);

  const int tid = (int)threadIdx.x;
  const int w = tid >> 6, l = tid & 63;
  const int quad = l >> 4, l16 = l & 15;
  const int wm = (w >> 2) * 128, wn = (w & 3) * 64;
#pragma unroll
  for (int ni = 0; ni < 4; ++ni) {
    const int col = n0 + wn + ni * 16 + l16;
    const float bv = bias[col];
#pragma unroll
    for (int mi = 0; mi < 8; ++mi) {
      const int row = m0 + wm + mi * 16 + quad * 4;
#pragma unroll
      for (int r = 0; r < 4; ++r) {
        float v = acc[mi][ni][r] + bv;
        if (EPI == 2) v = v > 0.f ? v : 0.f;
        if (EPI == 0)
          ((float*)C)[(size_t)(row + r) * N + col] = v;
        else
          ((unsigned short*)C)[(size_t)(row + r) * N + col] = f2bf(v);
      }
    }
  }
}

// --------------------------- fused QKV GEMM (256^2) ------------------------
#define QSCALE 0.180336884f   // 0.125 * log2(e)

__global__ __launch_bounds__(512, 1) void gemm256_qkv(
    const unsigned short* __restrict__ A, const unsigned short* __restrict__ Bt,
    const float* __restrict__ qb, const float* __restrict__ kb,
    const float* __restrict__ vb, unsigned short* __restrict__ Qo,
    unsigned short* __restrict__ Ko, unsigned short* __restrict__ Vto, int K) {
  __shared__ unsigned short As[2 * 16384];
  __shared__ unsigned short Bs[2 * 16384];
  const int tn = 12;                           // N = 3072
  const int cpx = (int)gridDim.x >> 3;
  const int sw = ((int)blockIdx.x & 7) * cpx + ((int)blockIdx.x >> 3);
  const int nt = sw % tn, mt = sw / tn;
  const int m0 = mt * 256, n0 = nt * 256;

  f32x4 acc[8][4] = {};
  gemm256_8ph(A, Bt, As, Bs, m0, n0, K, acc);

  const int tid = (int)threadIdx.x;
  const int w = tid >> 6, l = tid & 63;
  const int quad = l >> 4, l16 = l & 15;
  const int wm = (w >> 2) * 128, wn = (w & 3) * 64;

  const int seg = n0 >> 10;                    // 0=Q, 1=K, 2=V (block-uniform)
  const float* bias = seg == 0 ? qb : (seg == 1 ? kb : vb);
#pragma unroll
  for (int ni = 0; ni < 4; ++ni) {
    const int col = (n0 + wn + ni * 16 + l16) & 1023;
    const float bv = bias[col];
#pragma unroll
    for (int mi = 0; mi < 8; ++mi) {
      const int row = m0 + wm + mi * 16 + quad * 4;
      if (seg == 2) {
        const int b = row >> 11, s = row & 2047;
        const int hh = col >> 6, dh = col & 63;
        union { ushort4 v; unsigned short u[4]; } pk;
#pragma unroll
        for (int r = 0; r < 4; ++r) pk.u[r] = f2bf(acc[mi][ni][r] + bv);
        *(ushort4*)(Vto + ((size_t)((b * 16 + hh) * 64 + dh)) * 2048 + s) = pk.v;
      } else if (seg == 0) {
#pragma unroll
        for (int r = 0; r < 4; ++r)
          Qo[(size_t)(row + r) * 1024 + col] = f2bf((acc[mi][ni][r] + bv) * QSCALE);
      } else {
#pragma unroll
        for (int r = 0; r < 4; ++r)
          Ko[(size_t)(row + r) * 1024 + col] = f2bf(acc[mi][ni][r] + bv);
      }
    }
  }
}

// ------------------- 128x128 depth-3 GEMM core (R8-verified) ---------------
__device__ __forceinline__ void gemm128_core(
    const unsigned short* __restrict__ A, const unsigned short* __restrict__ Bt,
    unsigned short* __restrict__ As, unsigned short* __restrict__ Bs,
    const int m0, const int n0, const int K, f32x4 (&acc)[4][4]) {
  const int tid = (int)threadIdx.x;
  const int w = tid >> 6, l = tid & 63;
  const int quad = l >> 4, l16 = l & 15;
  const int wm = (w >> 1) * 64, wn = (w & 1) * 64;

  const int lr = l >> 2, lc = l & 3;
  const int swz = (lc ^ ((l >> 3) & 3)) * 8;
  const unsigned short* gA[2]; const unsigned short* gB[2];
  unsigned short* dA[2]; unsigned short* dB[2];
#pragma unroll
  for (int j = 0; j < 2; ++j) {
    const int rr = (w * 2 + j) * 16 + lr;
    gA[j] = A + (size_t)(m0 + rr) * K + swz;
    gB[j] = Bt + (size_t)(n0 + rr) * K + swz;
    dA[j] = As + (w * 2 + j) * 512;
    dB[j] = Bs + (w * 2 + j) * 512;
  }

  const int cread = (quad ^ ((l16 >> 1) & 3)) * 8;
  const int rA = (wm + l16) * 32;
  const int rB = (wn + l16) * 32;

  auto STAGE = [&](int db, int t) {
#pragma unroll
    for (int j = 0; j < 2; ++j) {
      gload16(gA[j] + t * 32, dA[j] + db * 4096);
      gload16(gB[j] + t * 32, dB[j] + db * 4096);
    }
  };
  auto COMPUTE = [&](int db) {
    bf16x8 af[4], bf[4];
    const unsigned short* pa = As + db * 4096 + rA + cread;
    const unsigned short* pb = Bs + db * 4096 + rB + cread;
#pragma unroll
    for (int ni = 0; ni < 4; ++ni) bf[ni] = *(const bf16x8*)(pb + ni * 16 * 32);
#pragma unroll
    for (int mi = 0; mi < 4; ++mi) af[mi] = *(const bf16x8*)(pa + mi * 16 * 32);
    __builtin_amdgcn_s_setprio(1);
#pragma unroll
    for (int mi = 0; mi < 4; ++mi)
#pragma unroll
      for (int ni = 0; ni < 4; ++ni)
        acc[mi][ni] = __builtin_amdgcn_mfma_f32_16x16x32_bf16(
            af[mi], bf[ni], acc[mi][ni], 0, 0, 0);
    __builtin_amdgcn_s_setprio(0);
  };

  const int NK = K >> 5;   // >= 4
  STAGE(0, 0); STAGE(1, 1); STAGE(2, 2);
#pragma unroll 1
  for (int t = 0; t < NK - 3; ++t) {
    asm volatile("s_waitcnt vmcnt(8)" ::: "memory");
    __builtin_amdgcn_s_barrier();
    STAGE((t + 3) & 3, t + 3);
    COMPUTE(t & 3);
  }
  asm volatile("s_waitcnt vmcnt(8)" ::: "memory");
  __builtin_amdgcn_s_barrier();
  COMPUTE((NK - 3) & 3);
  asm volatile("s_waitcnt vmcnt(4)" ::: "memory");
  __builtin_amdgcn_s_barrier();
  COMPUTE((NK - 2) & 3);
  asm volatile("s_waitcnt vmcnt(0)" ::: "memory");
  __builtin_amdgcn_s_barrier();
  COMPUTE((NK - 1) & 3);
}

// --------------------- 128^2 GEMM (B^T), generic epilogue ------------------
template <int EPI>
__global__ __launch_bounds__(256, 2) void gemm128_bt(
    const unsigned short* __restrict__ A, const unsigned short* __restrict__ Bt,
    const float* __restrict__ bias, void* __restrict__ C, int N, int K) {
  __shared__ unsigned short As[4 * 4096];
  __shared__ unsigned short Bs[4 * 4096];
  const int NT = N >> 7, band = NT >> 3;
  const int xcd = blockIdx.x & 7, local = blockIdx.x >> 3;
  const int nt = xcd * band + local % band;
  const int mt = local / band;
  const int m0 = mt * 128, n0 = nt * 128;

  f32x4 acc[4][4] = {};
  gemm128_core(A, Bt, As, Bs, m0, n0, K, acc);

  const int tid = (int)threadIdx.x;
  const int w = tid >> 6, l = tid & 63;
  const int quad = l >> 4, l16 = l & 15;
  const int wm = (w >> 1) * 64, wn = (w & 1) * 64;
#pragma unroll
  for (int ni = 0; ni < 4; ++ni) {
    const int col = n0 + wn + ni * 16 + l16;
    const float bv = bias[col];
#pragma unroll
    for (int mi = 0; mi < 4; ++mi) {
      const int row = m0 + wm + mi * 16 + quad * 4;
#pragma unroll
      for (int r = 0; r < 4; ++r) {
        float v = acc[mi][ni][r] + bv;
        if (EPI == 2) v = v > 0.f ? v : 0.f;
        if (EPI == 0)
          ((float*)C)[(size_t)(row + r) * N + col] = v;
        else
          ((unsigned short*)C)[(size_t)(row + r) * N + col] = f2bf(v);
      }
    }
  }
}

// --------------------------- flash attention -------------------------------
__global__ __launch_bounds__(256, 4) void attn_fused(
    const unsigned short* __restrict__ Q, const unsigned short* __restrict__ K,
    const unsigned short* __restrict__ Vt, const int* __restrict__ lengths,
    unsigned short* __restrict__ ctx) {
  constexpr int S = 2048, D = 1024;
  __shared__ unsigned short Ks[64 * 72];
  __shared__ unsigned short Vs[64 * 72];
  __shared__ unsigned short Ps[4 * 32 * 72];

  const int tid = threadIdx.x;
  const int wave = tid >> 6, lane = tid & 63;
  const int quad = lane >> 4, l16 = lane & 15;
  const int bid = blockIdx.x;
  const int qt = bid & 15;
  const int h = (bid >> 4) & 15;
  const int b = bid >> 8;
  const int q0 = qt * 128;
  const int len = lengths[b];
  const int ktEnd = (len + 63) >> 6;
  const float NEGINF = -__builtin_inff();

  const size_t xbase = (size_t)b * S * D + (size_t)h * 64;
  const size_t vtb = (size_t)(b * 16 + h) * 64;

  bf16x8 qf0[2], qf1[2];
#pragma unroll
  for (int mb = 0; mb < 2; ++mb) {
    const unsigned short* qrow =
        Q + xbase + (size_t)(q0 + wave * 32 + mb * 16 + l16) * D;
    qf0[mb] = *(const bf16x8*)(qrow + quad * 8);
    qf1[mb] = *(const bf16x8*)(qrow + 32 + quad * 8);
  }

  const int sr1 = tid >> 3, sc1 = (tid & 7) * 8;
  const int sr2 = (256 + tid) >> 3, sc2 = (tid & 7) * 8;
  const unsigned short* kg1 = K + xbase + (size_t)sr1 * D + sc1;
  const unsigned short* kg2 = K + xbase + (size_t)sr2 * D + sc2;
  const unsigned short* vg1 = Vt + (vtb + sr1) * S + sc1;
  const unsigned short* vg2 = Vt + (vtb + sr2) * S + sc2;

  f32x4 oacc[2][4] = {};
  float rs[2][4] = {};

  unsigned short* pw = Ps + wave * (32 * 72);

  int4 kr1, kr2, vr1, vr2;
  {
    kr1 = *(const int4*)(kg1);
    kr2 = *(const int4*)(kg2);
    vr1 = *(const int4*)(vg1);
    vr2 = *(const int4*)(vg2);
  }

  for (int kt = 0; kt < ktEnd; ++kt) {
    const int k0 = kt * 64;
    __syncthreads();
    *(int4*)(Ks + sr1 * 72 + sc1) = kr1;
    *(int4*)(Ks + sr2 * 72 + sc2) = kr2;
    *(int4*)(Vs + sr1 * 72 + sc1) = vr1;
    *(int4*)(Vs + sr2 * 72 + sc2) = vr2;
    __syncthreads();

    if (kt + 1 < ktEnd) {            // async prefetch of next tile
      const int kn = (kt + 1) * 64;
      kr1 = *(const int4*)(kg1 + (size_t)kn * D);
      kr2 = *(const int4*)(kg2 + (size_t)kn * D);
      vr1 = *(const int4*)(vg1 + kn);
      vr2 = *(const int4*)(vg2 + kn);
    }

    f32x4 sf[2][4];
#pragma unroll
    for (int cb = 0; cb < 4; ++cb) {
      const bf16x8 kf0 = *(const bf16x8*)(Ks + (cb * 16 + l16) * 72 + quad * 8);
      const bf16x8 kf1 = *(const bf16x8*)(Ks + (cb * 16 + l16) * 72 + 32 + quad * 8);
#pragma unroll
      for (int mb = 0; mb < 2; ++mb) {
        f32x4 c = {0.f, 0.f, 0.f, 0.f};
        c = __builtin_amdgcn_mfma_f32_16x16x32_bf16(qf0[mb], kf0, c, 0, 0, 0);
        c = __builtin_amdgcn_mfma_f32_16x16x32_bf16(qf1[mb], kf1, c, 0, 0, 0);
        sf[mb][cb] = c;
      }
    }

    if (k0 + 64 > len) {
#pragma unroll
      for (int cb = 0; cb < 4; ++cb) {
        const bool msk = (k0 + cb * 16 + l16) >= len;
#pragma unroll
        for (int mb = 0; mb < 2; ++mb)
#pragma unroll
          for (int r = 0; r < 4; ++r) sf[mb][cb][r] = msk ? NEGINF : sf[mb][cb][r];
      }
    }

#pragma unroll
    for (int mb = 0; mb < 2; ++mb)
#pragma unroll
      for (int cb = 0; cb < 4; ++cb)
#pragma unroll
        for (int r = 0; r < 4; ++r) {
          const float p = __builtin_amdgcn_exp2f(sf[mb][cb][r]);
          sf[mb][cb][r] = p;
          rs[mb][r] += p;
        }

#pragma unroll
    for (int mb = 0; mb < 2; ++mb)
#pragma unroll
      for (int cb = 0; cb < 4; ++cb)
#pragma unroll
        for (int r = 0; r < 4; ++r)
          pw[(mb * 16 + quad * 4 + r) * 72 + cb * 16 + l16] = f2bf(sf[mb][cb][r]);

    bf16x8 pa0[2], pa1[2];
#pragma unroll
    for (int mb = 0; mb < 2; ++mb) {
      pa0[mb] = *(const bf16x8*)(pw + (mb * 16 + l16) * 72 + quad * 8);
      pa1[mb] = *(const bf16x8*)(pw + (mb * 16 + l16) * 72 + 32 + quad * 8);
    }
#pragma unroll
    for (int cb = 0; cb < 4; ++cb) {
      const bf16x8 vb0 = *(const bf16x8*)(Vs + (cb * 16 + l16) * 72 + quad * 8);
      const bf16x8 vb1 = *(const bf16x8*)(Vs + (cb * 16 + l16) * 72 + 32 + quad * 8);
#pragma unroll
      for (int mb = 0; mb < 2; ++mb) {
        oacc[mb][cb] = __builtin_amdgcn_mfma_f32_16x16x32_bf16(pa0[mb], vb0, oacc[mb][cb], 0, 0, 0);
        oacc[mb][cb] = __builtin_amdgcn_mfma_f32_16x16x32_bf16(pa1[mb], vb1, oacc[mb][cb], 0, 0, 0);
      }
    }
  }

#pragma unroll
  for (int off = 8; off > 0; off >>= 1)
#pragma unroll
    for (int mb = 0; mb < 2; ++mb)
#pragma unroll
      for (int r = 0; r < 4; ++r) rs[mb][r] += __shfl_xor(rs[mb][r], off, 16);

#pragma unroll
  for (int mb = 0; mb < 2; ++mb) {
    float inv[4];
#pragma unroll
    for (int r = 0; r < 4; ++r) inv[r] = 1.0f / rs[mb][r];
#pragma unroll
    for (int cb = 0; cb < 4; ++cb)
#pragma unroll
      for (int r = 0; r < 4; ++r) {
        const int row = q0 + wave * 32 + mb * 16 + quad * 4 + r;
        ctx[xbase + (size_t)row * D + cb * 16 + l16] = f2bf(oacc[mb][cb][r] * inv[r]);
      }
  }
}

// ------------------------------ launcher -----------------------------------
extern "C" void kernel_launch(void* const* d_in, const int* in_sizes, int n_in,
                              void* d_out, int out_size, void* d_ws,
                              size_t ws_size, hipStream_t stream) {
  const float* x  = (const float*)d_in[0];
  const int* lengths = (const int*)d_in[1];
  const float* qW = (const float*)d_in[2];
  const float* qb = (const float*)d_in[3];
  const float* kW = (const float*)d_in[4];
  const float* kb = (const float*)d_in[5];
  const float* vW = (const float*)d_in[6];
  const float* vb = (const float*)d_in[7];
  const float* oW = (const float*)d_in[8];
  const float* ob = (const float*)d_in[9];
  const float* w1 = (const float*)d_in[10];
  const float* b1 = (const float*)d_in[11];
  const float* w2 = (const float*)d_in[12];
  const float* b2 = (const float*)d_in[13];
  float* out = (float*)d_out;

  const int Bx = 4, S = 2048, D = 1024, FF = 4096;
  const int M = Bx * S;  // 8192

  unsigned short* p = (unsigned short*)d_ws;
  unsigned short* xb  = p; p += (size_t)M * D;
  unsigned short* qWt = p; p += (size_t)D * D;   // contiguous [3072,1024]
  unsigned short* kWt = p; p += (size_t)D * D;
  unsigned short* vWt = p; p += (size_t)D * D;
  unsigned short* oWt = p; p += (size_t)D * D;
  unsigned short* w1t = p; p += (size_t)D * FF;   // [FF, D]
  unsigned short* w2t = p; p += (size_t)FF * D;   // [D, FF]
  unsigned short* Qb  = p; p += (size_t)M * D;
  unsigned short* Kb  = p; p += (size_t)M * D;
  unsigned short* Vtb = p; p += (size_t)M * D;    // [B,H,64,S]
  unsigned short* Cb  = p; p += (size_t)M * D;
  unsigned short* Ab  = p; p += (size_t)M * D;
  unsigned short* Hb  = p; p += (size_t)M * FF;

  {
    int n4 = (int)((size_t)M * D / 4);
    cast_f32_bf16<<<dim3((n4 + 255) / 256), dim3(256), 0, stream>>>(x, xb, n4);
  }
  prep_weights<<<dim3(6144), dim3(256), 0, stream>>>(
      qW, kW, vW, oW, w1, w2, qWt, kWt, vWt, oWt, w1t, w2t);

  // qkv: 256^2 8-phase core, 32 x 12 = 384 blocks
  gemm256_qkv<<<dim3(384), dim3(512), 0, stream>>>(
      xb, qWt, qb, kb, vb, Qb, Kb, Vtb, D);

  attn_fused<<<dim3(Bx * 16 * (S / 128)), dim3(256), 0, stream>>>(
      Qb, Kb, Vtb, lengths, Cb);

  // proj: 128^2 depth-3 core, 8 x 64 = 512 blocks
  gemm128_bt<1><<<dim3(512), dim3(256), 0, stream>>>(Cb, oWt, ob, Ab, D, D);
  // ffn1: 256^2 8-phase core, 32 x 16 = 512 blocks
  gemm256_bt<2><<<dim3(512), dim3(512), 0, stream>>>(Ab, w1t, b1, Hb, FF, D);
  // ffn2: 128^2 depth-3 core, 8 x 64 = 512 blocks (K=4096: 128 K-steps)
  gemm128_bt<0><<<dim3(512), dim3(256), 0, stream>>>(Hb, w2t, b2, out, D, FF);
}

// Round 5
// 477.311 us; speedup vs baseline: 1.1082x; 1.0278x over previous
//
#include <hip/hip_runtime.h>

// ---------------------------------------------------------------------------
// TransformerEncoder: B=4, S=2048, D=1024, H=16, HD=64, FF=4096
// Round 10: occupancy fix for the 128^2 pipelined core. R9 counters showed
// ffn2 latency-bound at 2 blocks/CU (MfmaUtil 27%, VALU 15%, HBM 37%,
// occupancy 20.7%): the 4-buf depth-3 core costs 64 KB LDS. New core:
// 3-buf depth-2 (48 KB -> 3 blocks/CU, 3 waves/SIMD, +50% TLP).
//   Depth-2 ledger (same proof skeleton as the R7/R8-verified depth-3):
//     prologue: STAGE(0,0) STAGE(1,1)            [8 loads outstanding]
//     step t (0..NK-3):
//       vmcnt(4)   [oldest 4 = tile t landed; tile t+1's 4 in flight]
//       s_barrier  [all waves: buf t%3 valid; reads of (t-1)%3 done in
//                   step t-1, before this barrier -> WAR-safe]
//       STAGE tile t+2 -> buf (t+2)%3 == (t-1)%3
//       COMPUTE buf t%3   [disjoint from in-flight bufs]
//     tail: vmcnt(4); barrier; COMPUTE(NK-2); vmcnt(0); barrier;
//           COMPUTE(NK-1).  Requires NK >= 2.
//   Swizzle unchanged (both-sides, verified): LDS[row][chunk] =
//   global[row][chunk ^ ((row>>1)&3)], chunk = 16 B.
// Users: qkv (back to 1536-block 128^2 geometry — R9's 384x512 shape lost
// 25% to launch-round round-up), proj, ffn2. ffn1 keeps the R9 8-phase
// 256^2 core (512 balanced blocks). Attention / cast / prep unchanged.
// ---------------------------------------------------------------------------

typedef short bf16x8 __attribute__((ext_vector_type(8)));
typedef float f32x4 __attribute__((ext_vector_type(4)));

__device__ __forceinline__ unsigned short f2bf(float f) {
  unsigned int u = __builtin_bit_cast(unsigned int, f);
  u += 0x7fffu + ((u >> 16) & 1u);   // round-to-nearest-even
  return (unsigned short)(u >> 16);
}

__device__ __forceinline__ void gload16(const unsigned short* g, unsigned short* l) {
  __builtin_amdgcn_global_load_lds(
      (const __attribute__((address_space(1))) unsigned int*)(g),
      (__attribute__((address_space(3))) unsigned int*)(l),
      16, 0, 0);
}

// --------------------------- cast fp32 -> bf16 -----------------------------
__global__ __launch_bounds__(256) void cast_f32_bf16(
    const float* __restrict__ src, unsigned short* __restrict__ dst, int n4) {
  int i = blockIdx.x * 256 + threadIdx.x;
  if (i < n4) {
    float4 f = ((const float4*)src)[i];
    ushort4 o;
    o.x = f2bf(f.x); o.y = f2bf(f.y); o.z = f2bf(f.z); o.w = f2bf(f.w);
    ((ushort4*)dst)[i] = o;
  }
}

// ---------------- merged weight prep: 6 transposes in one kernel -----------
__global__ __launch_bounds__(256) void prep_weights(
    const float* __restrict__ qW, const float* __restrict__ kW,
    const float* __restrict__ vW, const float* __restrict__ oW,
    const float* __restrict__ w1, const float* __restrict__ w2,
    unsigned short* __restrict__ qWt, unsigned short* __restrict__ kWt,
    unsigned short* __restrict__ vWt, unsigned short* __restrict__ oWt,
    unsigned short* __restrict__ w1t, unsigned short* __restrict__ w2t) {
  const int t = blockIdx.x;
  const float* W; unsigned short* Wt; int N, K, nt, kt;
  if (t < 2048) {
    const int w = t >> 9, r = t & 511;
    nt = r & 15; kt = r >> 4; N = 1024; K = 1024;
    W  = w == 0 ? qW : w == 1 ? kW : w == 2 ? vW : oW;
    Wt = w == 0 ? qWt : w == 1 ? kWt : w == 2 ? vWt : oWt;
  } else if (t < 4096) {
    const int r = t - 2048;
    nt = r & 63; kt = r >> 6; N = 4096; K = 1024; W = w1; Wt = w1t;
  } else {
    const int r = t - 4096;
    nt = r & 15; kt = r >> 4; N = 1024; K = 4096; W = w2; Wt = w2t;
  }
  const int wave = threadIdx.x >> 6, lane = threadIdx.x & 63;
  const int n = nt * 64 + lane;
  const int k0 = kt * 32 + wave * 8;
  union { int4 v; unsigned short u[8]; } s;
#pragma unroll
  for (int j = 0; j < 8; ++j) s.u[j] = f2bf(W[(size_t)(k0 + j) * N + n]);
  *(int4*)(Wt + (size_t)n * K + k0) = s.v;
}

// ---------------- 256x256 8-phase counted-vmcnt core (B^T) -----------------
// 8 waves 2Mx4N, wave tile 128x64 (8x4 frags), BK=64 (2 kk). R9-verified.
__device__ __forceinline__ void gemm256_8ph(
    const unsigned short* __restrict__ A, const unsigned short* __restrict__ Bt,
    unsigned short* __restrict__ As, unsigned short* __restrict__ Bs,
    const int m0, const int n0, const int K, f32x4 (&acc)[8][4]) {
  const int tid = (int)threadIdx.x;
  const int w = tid >> 6, l = tid & 63;
  const int quad = l >> 4, l16 = l & 15;
  const int wm = (w >> 2) * 128, wn = (w & 3) * 64;

  const int srow = w * 8 + (l >> 3);
  const int schunk = ((l & 7) ^ (l >> 3)) * 8;
  const unsigned short* gA = A + (size_t)(m0 + srow) * K + schunk;
  const unsigned short* gB = Bt + (size_t)(n0 + srow) * K + schunk;
  const int ldsW = w * 512;

  const int xr = l16 & 7;
  const int c0 = ((0 + quad) ^ xr) * 8;
  const int c1 = ((4 + quad) ^ xr) * 8;

  bf16x8 af[4][2], bf0[2][2], bf1[2][2];

  auto STA = [&](int buf, int a, int t) {
    gload16(gA + (size_t)(a * 64) * K + t * 64,
            As + buf * 16384 + a * 4096 + ldsW);
  };
  auto STB = [&](int buf, int a, int t) {
    gload16(gB + (size_t)(a * 64) * K + t * 64,
            Bs + buf * 16384 + a * 4096 + ldsW);
  };
  auto LDA = [&](int buf, int mh) {
    const unsigned short* p = As + buf * 16384 + (wm + mh * 64 + l16) * 64;
#pragma unroll
    for (int mi = 0; mi < 4; ++mi) {
      af[mi][0] = *(const bf16x8*)(p + mi * 16 * 64 + c0);
      af[mi][1] = *(const bf16x8*)(p + mi * 16 * 64 + c1);
    }
  };
  auto LDB = [&](int buf, int nh, bf16x8 (&bf)[2][2]) {
    const unsigned short* p = Bs + buf * 16384 + (wn + nh * 32 + l16) * 64;
#pragma unroll
    for (int ni = 0; ni < 2; ++ni) {
      bf[ni][0] = *(const bf16x8*)(p + ni * 16 * 64 + c0);
      bf[ni][1] = *(const bf16x8*)(p + ni * 16 * 64 + c1);
    }
  };
  auto MM = [&](int mh, int nh, bf16x8 (&bf)[2][2]) {
    __builtin_amdgcn_s_setprio(1);
#pragma unroll
    for (int mi = 0; mi < 4; ++mi)
#pragma unroll
      for (int ni = 0; ni < 2; ++ni) {
        f32x4& a = acc[mh * 4 + mi][nh * 2 + ni];
        a = __builtin_amdgcn_mfma_f32_16x16x32_bf16(af[mi][0], bf[ni][0], a, 0, 0, 0);
        a = __builtin_amdgcn_mfma_f32_16x16x32_bf16(af[mi][1], bf[ni][1], a, 0, 0, 0);
      }
    __builtin_amdgcn_s_setprio(0);
  };

  const int NK = K >> 6;   // >= 2
  STB(0, 0, 0); STB(0, 1, 0); STB(0, 2, 0); STB(0, 3, 0);
  STA(0, 0, 0); STA(0, 2, 0); STA(0, 1, 0); STA(0, 3, 0);
  asm volatile("s_waitcnt vmcnt(2)" ::: "memory");
  __builtin_amdgcn_s_barrier();

#pragma unroll 1
  for (int t = 0; t < NK; ++t) {
    const int c = t & 1, nb = c ^ 1;
    const bool st = (t + 1 < NK);
    // ---- P1 (mh0, nh0)
    LDA(c, 0); LDB(c, 0, bf0);
    if (st) { STB(nb, 0, t + 1); STB(nb, 1, t + 1); }
    __builtin_amdgcn_s_barrier();
    asm volatile("s_waitcnt lgkmcnt(0)" ::: "memory");
    __builtin_amdgcn_sched_barrier(0);
    MM(0, 0, bf0);
    __builtin_amdgcn_s_barrier();
    // ---- P2 (mh0, nh1)
    LDB(c, 1, bf1);
    if (st) { STB(nb, 2, t + 1); STB(nb, 3, t + 1); }
    __builtin_amdgcn_s_barrier();
    asm volatile("s_waitcnt lgkmcnt(0)" ::: "memory");
    __builtin_amdgcn_sched_barrier(0);
    MM(0, 1, bf1);
    if (st) asm volatile("s_waitcnt vmcnt(4)" ::: "memory");
    else    asm volatile("s_waitcnt vmcnt(0)" ::: "memory");
    __builtin_amdgcn_s_barrier();
    // ---- P3 (mh1, nh1)
    LDA(c, 1);
    if (st) { STA(nb, 0, t + 1); STA(nb, 2, t + 1); }
    __builtin_amdgcn_s_barrier();
    asm volatile("s_waitcnt lgkmcnt(0)" ::: "memory");
    __builtin_amdgcn_sched_barrier(0);
    MM(1, 1, bf1);
    __builtin_amdgcn_s_barrier();
    // ---- P4 (mh1, nh0)
    if (st) { STA(nb, 1, t + 1); STA(nb, 3, t + 1); }
    __builtin_amdgcn_s_barrier();
    MM(1, 0, bf0);
    if (st) asm volatile("s_waitcnt vmcnt(2)" ::: "memory");
    __builtin_amdgcn_s_barrier();
  }
}

// --------------------- 256^2 GEMM (B^T), generic epilogue ------------------
template <int EPI>
__global__ __launch_bounds__(512, 1) void gemm256_bt(
    const unsigned short* __restrict__ A, const unsigned short* __restrict__ Bt,
    const float* __restrict__ bias, void* __restrict__ C, int N, int K) {
  __shared__ unsigned short As[2 * 16384];
  __shared__ unsigned short Bs[2 * 16384];
  const int tn = N >> 8;
  const int cpx = (int)gridDim.x >> 3;
  const int sw = ((int)blockIdx.x & 7) * cpx + ((int)blockIdx.x >> 3);
  const int nt = sw % tn, mt = sw / tn;
  const int m0 = mt * 256, n0 = nt * 256;

  f32x4 acc[8][4] = {};
  gemm256_8ph(A, Bt, As, Bs, m0, n0, K, acc);

  const int tid = (int)threadIdx.x;
  const int w = tid >> 6, l = tid & 63;
  const int quad = l >> 4, l16 = l & 15;
  const int wm = (w >> 2) * 128, wn = (w & 3) * 64;
#pragma unroll
  for (int ni = 0; ni < 4; ++ni) {
    const int col = n0 + wn + ni * 16 + l16;
    const float bv = bias[col];
#pragma unroll
    for (int mi = 0; mi < 8; ++mi) {
      const int row = m0 + wm + mi * 16 + quad * 4;
#pragma unroll
      for (int r = 0; r < 4; ++r) {
        float v = acc[mi][ni][r] + bv;
        if (EPI == 2) v = v > 0.f ? v : 0.f;
        if (EPI == 0)
          ((float*)C)[(size_t)(row + r) * N + col] = v;
        else
          ((unsigned short*)C)[(size_t)(row + r) * N + col] = f2bf(v);
      }
    }
  }
}

// ------------- 128x128 depth-2 3-buf GEMM core (48 KB, 3 blk/CU) -----------
// 4 waves 2Mx2N, wave tile 64x64 (4x4 frags), BK=32. See file-header ledger.
__device__ __forceinline__ void gemm128_core(
    const unsigned short* __restrict__ A, const unsigned short* __restrict__ Bt,
    unsigned short* __restrict__ As, unsigned short* __restrict__ Bs,
    const int m0, const int n0, const int K, f32x4 (&acc)[4][4]) {
  const int tid = (int)threadIdx.x;
  const int w = tid >> 6, l = tid & 63;
  const int quad = l >> 4, l16 = l & 15;
  const int wm = (w >> 1) * 64, wn = (w & 1) * 64;

  const int lr = l >> 2, lc = l & 3;
  const int swz = (lc ^ ((l >> 3) & 3)) * 8;
  const unsigned short* gA[2]; const unsigned short* gB[2];
  unsigned short* dA[2]; unsigned short* dB[2];
#pragma unroll
  for (int j = 0; j < 2; ++j) {
    const int rr = (w * 2 + j) * 16 + lr;
    gA[j] = A + (size_t)(m0 + rr) * K + swz;
    gB[j] = Bt + (size_t)(n0 + rr) * K + swz;
    dA[j] = As + (w * 2 + j) * 512;
    dB[j] = Bs + (w * 2 + j) * 512;
  }

  const int cread = (quad ^ ((l16 >> 1) & 3)) * 8;
  const int rA = (wm + l16) * 32;
  const int rB = (wn + l16) * 32;

  auto STAGE = [&](int db, int t) {
#pragma unroll
    for (int j = 0; j < 2; ++j) {
      gload16(gA[j] + t * 32, dA[j] + db * 4096);
      gload16(gB[j] + t * 32, dB[j] + db * 4096);
    }
  };
  auto COMPUTE = [&](int db) {
    bf16x8 af[4], bf[4];
    const unsigned short* pa = As + db * 4096 + rA + cread;
    const unsigned short* pb = Bs + db * 4096 + rB + cread;
#pragma unroll
    for (int ni = 0; ni < 4; ++ni) bf[ni] = *(const bf16x8*)(pb + ni * 16 * 32);
#pragma unroll
    for (int mi = 0; mi < 4; ++mi) af[mi] = *(const bf16x8*)(pa + mi * 16 * 32);
    __builtin_amdgcn_s_setprio(1);
#pragma unroll
    for (int mi = 0; mi < 4; ++mi)
#pragma unroll
      for (int ni = 0; ni < 4; ++ni)
        acc[mi][ni] = __builtin_amdgcn_mfma_f32_16x16x32_bf16(
            af[mi], bf[ni], acc[mi][ni], 0, 0, 0);
    __builtin_amdgcn_s_setprio(0);
  };

  const int NK = K >> 5;   // >= 2
  STAGE(0, 0); STAGE(1, 1);
  int cc = 0, cs = 2;      // t % 3, (t+2) % 3
#pragma unroll 1
  for (int t = 0; t < NK - 2; ++t) {
    asm volatile("s_waitcnt vmcnt(4)" ::: "memory");
    __builtin_amdgcn_s_barrier();
    STAGE(cs, t + 2);
    COMPUTE(cc);
    cc = cc == 2 ? 0 : cc + 1;
    cs = cs == 2 ? 0 : cs + 1;
  }
  asm volatile("s_waitcnt vmcnt(4)" ::: "memory");
  __builtin_amdgcn_s_barrier();
  COMPUTE(cc);
  cc = cc == 2 ? 0 : cc + 1;
  asm volatile("s_waitcnt vmcnt(0)" ::: "memory");
  __builtin_amdgcn_s_barrier();
  COMPUTE(cc);
}

// --------------------- 128^2 GEMM (B^T), generic epilogue ------------------
template <int EPI>
__global__ __launch_bounds__(256, 3) void gemm128_bt(
    const unsigned short* __restrict__ A, const unsigned short* __restrict__ Bt,
    const float* __restrict__ bias, void* __restrict__ C, int N, int K) {
  __shared__ unsigned short As[3 * 4096];
  __shared__ unsigned short Bs[3 * 4096];
  const int NT = N >> 7, band = NT >> 3;
  const int xcd = blockIdx.x & 7, local = blockIdx.x >> 3;
  const int nt = xcd * band + local % band;
  const int mt = local / band;
  const int m0 = mt * 128, n0 = nt * 128;

  f32x4 acc[4][4] = {};
  gemm128_core(A, Bt, As, Bs, m0, n0, K, acc);

  const int tid = (int)threadIdx.x;
  const int w = tid >> 6, l = tid & 63;
  const int quad = l >> 4, l16 = l & 15;
  const int wm = (w >> 1) * 64, wn = (w & 1) * 64;
#pragma unroll
  for (int ni = 0; ni < 4; ++ni) {
    const int col = n0 + wn + ni * 16 + l16;
    const float bv = bias[col];
#pragma unroll
    for (int mi = 0; mi < 4; ++mi) {
      const int row = m0 + wm + mi * 16 + quad * 4;
#pragma unroll
      for (int r = 0; r < 4; ++r) {
        float v = acc[mi][ni][r] + bv;
        if (EPI == 2) v = v > 0.f ? v : 0.f;
        if (EPI == 0)
          ((float*)C)[(size_t)(row + r) * N + col] = v;
        else
          ((unsigned short*)C)[(size_t)(row + r) * N + col] = f2bf(v);
      }
    }
  }
}

// --------------------------- fused QKV GEMM (128^2) ------------------------
#define QSCALE 0.180336884f   // 0.125 * log2(e)

__global__ __launch_bounds__(256, 3) void gemm128_qkv(
    const unsigned short* __restrict__ A, const unsigned short* __restrict__ Bt,
    const float* __restrict__ qb, const float* __restrict__ kb,
    const float* __restrict__ vb, unsigned short* __restrict__ Qo,
    unsigned short* __restrict__ Ko, unsigned short* __restrict__ Vto, int K) {
  __shared__ unsigned short As[3 * 4096];
  __shared__ unsigned short Bs[3 * 4096];
  const int NT = 24, band = 3;                 // N = 3072
  const int xcd = blockIdx.x & 7, local = blockIdx.x >> 3;
  const int nt = xcd * band + local % band;
  const int mt = local / band;
  const int m0 = mt * 128, n0 = nt * 128;

  f32x4 acc[4][4] = {};
  gemm128_core(A, Bt, As, Bs, m0, n0, K, acc);

  const int tid = (int)threadIdx.x;
  const int w = tid >> 6, l = tid & 63;
  const int quad = l >> 4, l16 = l & 15;
  const int wm = (w >> 1) * 64, wn = (w & 1) * 64;

  const int seg = n0 >> 10;                    // 0=Q, 1=K, 2=V (block-uniform)
  const float* bias = seg == 0 ? qb : (seg == 1 ? kb : vb);
#pragma unroll
  for (int ni = 0; ni < 4; ++ni) {
    const int col = (n0 + wn + ni * 16 + l16) & 1023;
    const float bv = bias[col];
#pragma unroll
    for (int mi = 0; mi < 4; ++mi) {
      const int row = m0 + wm + mi * 16 + quad * 4;
      if (seg == 2) {
        const int b = row >> 11, s = row & 2047;
        const int hh = col >> 6, dh = col & 63;
        union { ushort4 v; unsigned short u[4]; } pk;
#pragma unroll
        for (int r = 0; r < 4; ++r) pk.u[r] = f2bf(acc[mi][ni][r] + bv);
        *(ushort4*)(Vto + ((size_t)((b * 16 + hh) * 64 + dh)) * 2048 + s) = pk.v;
      } else if (seg == 0) {
#pragma unroll
        for (int r = 0; r < 4; ++r)
          Qo[(size_t)(row + r) * 1024 + col] = f2bf((acc[mi][ni][r] + bv) * QSCALE);
      } else {
#pragma unroll
        for (int r = 0; r < 4; ++r)
          Ko[(size_t)(row + r) * 1024 + col] = f2bf(acc[mi][ni][r] + bv);
      }
    }
  }
}

// --------------------------- flash attention -------------------------------
__global__ __launch_bounds__(256, 4) void attn_fused(
    const unsigned short* __restrict__ Q, const unsigned short* __restrict__ K,
    const unsigned short* __restrict__ Vt, const int* __restrict__ lengths,
    unsigned short* __restrict__ ctx) {
  constexpr int S = 2048, D = 1024;
  __shared__ unsigned short Ks[64 * 72];
  __shared__ unsigned short Vs[64 * 72];
  __shared__ unsigned short Ps[4 * 32 * 72];

  const int tid = threadIdx.x;
  const int wave = tid >> 6, lane = tid & 63;
  const int quad = lane >> 4, l16 = lane & 15;
  const int bid = blockIdx.x;
  const int qt = bid & 15;
  const int h = (bid >> 4) & 15;
  const int b = bid >> 8;
  const int q0 = qt * 128;
  const int len = lengths[b];
  const int ktEnd = (len + 63) >> 6;
  const float NEGINF = -__builtin_inff();

  const size_t xbase = (size_t)b * S * D + (size_t)h * 64;
  const size_t vtb = (size_t)(b * 16 + h) * 64;

  bf16x8 qf0[2], qf1[2];
#pragma unroll
  for (int mb = 0; mb < 2; ++mb) {
    const unsigned short* qrow =
        Q + xbase + (size_t)(q0 + wave * 32 + mb * 16 + l16) * D;
    qf0[mb] = *(const bf16x8*)(qrow + quad * 8);
    qf1[mb] = *(const bf16x8*)(qrow + 32 + quad * 8);
  }

  const int sr1 = tid >> 3, sc1 = (tid & 7) * 8;
  const int sr2 = (256 + tid) >> 3, sc2 = (tid & 7) * 8;
  const unsigned short* kg1 = K + xbase + (size_t)sr1 * D + sc1;
  const unsigned short* kg2 = K + xbase + (size_t)sr2 * D + sc2;
  const unsigned short* vg1 = Vt + (vtb + sr1) * S + sc1;
  const unsigned short* vg2 = Vt + (vtb + sr2) * S + sc2;

  f32x4 oacc[2][4] = {};
  float rs[2][4] = {};

  unsigned short* pw = Ps + wave * (32 * 72);

  int4 kr1, kr2, vr1, vr2;
  {
    kr1 = *(const int4*)(kg1);
    kr2 = *(const int4*)(kg2);
    vr1 = *(const int4*)(vg1);
    vr2 = *(const int4*)(vg2);
  }

  for (int kt = 0; kt < ktEnd; ++kt) {
    const int k0 = kt * 64;
    __syncthreads();
    *(int4*)(Ks + sr1 * 72 + sc1) = kr1;
    *(int4*)(Ks + sr2 * 72 + sc2) = kr2;
    *(int4*)(Vs + sr1 * 72 + sc1) = vr1;
    *(int4*)(Vs + sr2 * 72 + sc2) = vr2;
    __syncthreads();

    if (kt + 1 < ktEnd) {            // async prefetch of next tile
      const int kn = (kt + 1) * 64;
      kr1 = *(const int4*)(kg1 + (size_t)kn * D);
      kr2 = *(const int4*)(kg2 + (size_t)kn * D);
      vr1 = *(const int4*)(vg1 + kn);
      vr2 = *(const int4*)(vg2 + kn);
    }

    f32x4 sf[2][4];
#pragma unroll
    for (int cb = 0; cb < 4; ++cb) {
      const bf16x8 kf0 = *(const bf16x8*)(Ks + (cb * 16 + l16) * 72 + quad * 8);
      const bf16x8 kf1 = *(const bf16x8*)(Ks + (cb * 16 + l16) * 72 + 32 + quad * 8);
#pragma unroll
      for (int mb = 0; mb < 2; ++mb) {
        f32x4 c = {0.f, 0.f, 0.f, 0.f};
        c = __builtin_amdgcn_mfma_f32_16x16x32_bf16(qf0[mb], kf0, c, 0, 0, 0);
        c = __builtin_amdgcn_mfma_f32_16x16x32_bf16(qf1[mb], kf1, c, 0, 0, 0);
        sf[mb][cb] = c;
      }
    }

    if (k0 + 64 > len) {
#pragma unroll
      for (int cb = 0; cb < 4; ++cb) {
        const bool msk = (k0 + cb * 16 + l16) >= len;
#pragma unroll
        for (int mb = 0; mb < 2; ++mb)
#pragma unroll
          for (int r = 0; r < 4; ++r) sf[mb][cb][r] = msk ? NEGINF : sf[mb][cb][r];
      }
    }

#pragma unroll
    for (int mb = 0; mb < 2; ++mb)
#pragma unroll
      for (int cb = 0; cb < 4; ++cb)
#pragma unroll
        for (int r = 0; r < 4; ++r) {
          const float p = __builtin_amdgcn_exp2f(sf[mb][cb][r]);
          sf[mb][cb][r] = p;
          rs[mb][r] += p;
        }

#pragma unroll
    for (int mb = 0; mb < 2; ++mb)
#pragma unroll
      for (int cb = 0; cb < 4; ++cb)
#pragma unroll
        for (int r = 0; r < 4; ++r)
          pw[(mb * 16 + quad * 4 + r) * 72 + cb * 16 + l16] = f2bf(sf[mb][cb][r]);

    bf16x8 pa0[2], pa1[2];
#pragma unroll
    for (int mb = 0; mb < 2; ++mb) {
      pa0[mb] = *(const bf16x8*)(pw + (mb * 16 + l16) * 72 + quad * 8);
      pa1[mb] = *(const bf16x8*)(pw + (mb * 16 + l16) * 72 + 32 + quad * 8);
    }
#pragma unroll
    for (int cb = 0; cb < 4; ++cb) {
      const bf16x8 vb0 = *(const bf16x8*)(Vs + (cb * 16 + l16) * 72 + quad * 8);
      const bf16x8 vb1 = *(const bf16x8*)(Vs + (cb * 16 + l16) * 72 + 32 + quad * 8);
#pragma unroll
      for (int mb = 0; mb < 2; ++mb) {
        oacc[mb][cb] = __builtin_amdgcn_mfma_f32_16x16x32_bf16(pa0[mb], vb0, oacc[mb][cb], 0, 0, 0);
        oacc[mb][cb] = __builtin_amdgcn_mfma_f32_16x16x32_bf16(pa1[mb], vb1, oacc[mb][cb], 0, 0, 0);
      }
    }
  }

#pragma unroll
  for (int off = 8; off > 0; off >>= 1)
#pragma unroll
    for (int mb = 0; mb < 2; ++mb)
#pragma unroll
      for (int r = 0; r < 4; ++r) rs[mb][r] += __shfl_xor(rs[mb][r], off, 16);

#pragma unroll
  for (int mb = 0; mb < 2; ++mb) {
    float inv[4];
#pragma unroll
    for (int r = 0; r < 4; ++r) inv[r] = 1.0f / rs[mb][r];
#pragma unroll
    for (int cb = 0; cb < 4; ++cb)
#pragma unroll
      for (int r = 0; r < 4; ++r) {
        const int row = q0 + wave * 32 + mb * 16 + quad * 4 + r;
        ctx[xbase + (size_t)row * D + cb * 16 + l16] = f2bf(oacc[mb][cb][r] * inv[r]);
      }
  }
}

// ------------------------------ launcher -----------------------------------
extern "C" void kernel_launch(void* const* d_in, const int* in_sizes, int n_in,
                              void* d_out, int out_size, void* d_ws,
                              size_t ws_size, hipStream_t stream) {
  const float* x  = (const float*)d_in[0];
  const int* lengths = (const int*)d_in[1];
  const float* qW = (const float*)d_in[2];
  const float* qb = (const float*)d_in[3];
  const float* kW = (const float*)d_in[4];
  const float* kb = (const float*)d_in[5];
  const float* vW = (const float*)d_in[6];
  const float* vb = (const float*)d_in[7];
  const float* oW = (const float*)d_in[8];
  const float* ob = (const float*)d_in[9];
  const float* w1 = (const float*)d_in[10];
  const float* b1 = (const float*)d_in[11];
  const float* w2 = (const float*)d_in[12];
  const float* b2 = (const float*)d_in[13];
  float* out = (float*)d_out;

  const int Bx = 4, S = 2048, D = 1024, FF = 4096;
  const int M = Bx * S;  // 8192

  unsigned short* p = (unsigned short*)d_ws;
  unsigned short* xb  = p; p += (size_t)M * D;
  unsigned short* qWt = p; p += (size_t)D * D;   // contiguous [3072,1024]
  unsigned short* kWt = p; p += (size_t)D * D;
  unsigned short* vWt = p; p += (size_t)D * D;
  unsigned short* oWt = p; p += (size_t)D * D;
  unsigned short* w1t = p; p += (size_t)D * FF;   // [FF, D]
  unsigned short* w2t = p; p += (size_t)FF * D;   // [D, FF]
  unsigned short* Qb  = p; p += (size_t)M * D;
  unsigned short* Kb  = p; p += (size_t)M * D;
  unsigned short* Vtb = p; p += (size_t)M * D;    // [B,H,64,S]
  unsigned short* Cb  = p; p += (size_t)M * D;
  unsigned short* Ab  = p; p += (size_t)M * D;
  unsigned short* Hb  = p; p += (size_t)M * FF;

  {
    int n4 = (int)((size_t)M * D / 4);
    cast_f32_bf16<<<dim3((n4 + 255) / 256), dim3(256), 0, stream>>>(x, xb, n4);
  }
  prep_weights<<<dim3(6144), dim3(256), 0, stream>>>(
      qW, kW, vW, oW, w1, w2, qWt, kWt, vWt, oWt, w1t, w2t);

  // qkv: 128^2 depth-2 core, 24 x 64 = 1536 blocks (balanced, 3/CU)
  gemm128_qkv<<<dim3(1536), dim3(256), 0, stream>>>(
      xb, qWt, qb, kb, vb, Qb, Kb, Vtb, D);

  attn_fused<<<dim3(Bx * 16 * (S / 128)), dim3(256), 0, stream>>>(
      Qb, Kb, Vtb, lengths, Cb);

  // proj: 128^2 depth-2 core, 8 x 64 = 512 blocks
  gemm128_bt<1><<<dim3(512), dim3(256), 0, stream>>>(Cb, oWt, ob, Ab, D, D);
  // ffn1: 256^2 8-phase core, 32 x 16 = 512 blocks
  gemm256_bt<2><<<dim3(512), dim3(512), 0, stream>>>(Ab, w1t, b1, Hb, FF, D);
  // ffn2: 128^2 depth-2 core, 8 x 64 = 512 blocks (K=4096: 128 K-steps)
  gemm128_bt<0><<<dim3(512), dim3(256), 0, stream>>>(Hb, w2t, b2, out, D, FF);
}

// Round 6
// 475.545 us; speedup vs baseline: 1.1123x; 1.0037x over previous
//
#include <hip/hip_runtime.h>

// ---------------------------------------------------------------------------
// TransformerEncoder: B=4, S=2048, D=1024, H=16, HD=64, FF=4096
// Round 11: register-double-buffered depth-3 128^2 core.
// R10 post-mortem: ffn2 unchanged (105 us) — occupancy was GRID-limited
// (512 blocks = 2/CU exactly), and per-step time ~410 cy/CU-step is
// dominated by the serial ds_read -> lgkmcnt(0) -> MFMA chain inside each
// step (only 2 waves/SIMD to cover it). Fix: cross-step register double
// buffering — step t ds_reads tile t+1's fragments into the alternate
// register bank while MFMAing tile t from the current bank. ds_read latency
// hides under a full K-step; the MFMA's lgkm wait covers reads issued one
// step earlier (compiler auto-emits counted lgkmcnt(8); no inline-asm lgkm
// -> rule-18 hazard avoided; banks are NAMED arrays, manually 2-unrolled
// loop -> rule-20 scratch hazard avoided).
//
// Depth-3 reg-dbuf ledger (delta from the R8-verified depth-3 proof):
//   prologue: STAGE(0,0) STAGE(1,1) STAGE(2,2); vmcnt(8) [tile0 landed];
//             barrier; DSREAD(0 -> bank A).
//   step t (computes tile t from bank CUR, loads tile t+1 into bank NXT):
//     entry invariant: tiles <= t landed & published; in-flight <= {t+1,t+2}
//     vmcnt(4) if t+2 staged else vmcnt(0)   [=> tile t+1 landed]
//     s_barrier                              [publish tile t+1; close reads
//                                             of buf (t-1)&3 from step t-2]
//     DSREAD((t+1)&3 -> NXT)                 [valid buf, 8x ds_read_b128]
//     STAGE((t+3)&3, t+3) if t+3 < NK        [WAR: last read step t-2,
//                                             >= 2 barriers ago]
//     MFMA(CUR)                              [auto lgkmcnt(8) waits only
//                                             for step t-1's ds_reads]
//   tail: step NK-2 uses vmcnt(0); then MFMA(bank of tile NK-1).
//   Requires NK even, >= 4 (users: 32, 32, 128).
// Swizzle unchanged (both-sides, verified): LDS[row][chunk] =
//   global[row][chunk ^ ((row>>1)&3)], chunk = 16 B.
// Users: qkv, proj, ffn2. ffn1 keeps the R9-verified 8-phase 256^2 core.
// Attention / cast / prep unchanged.
// ---------------------------------------------------------------------------

typedef short bf16x8 __attribute__((ext_vector_type(8)));
typedef float f32x4 __attribute__((ext_vector_type(4)));

__device__ __forceinline__ unsigned short f2bf(float f) {
  unsigned int u = __builtin_bit_cast(unsigned int, f);
  u += 0x7fffu + ((u >> 16) & 1u);   // round-to-nearest-even
  return (unsigned short)(u >> 16);
}

__device__ __forceinline__ void gload16(const unsigned short* g, unsigned short* l) {
  __builtin_amdgcn_global_load_lds(
      (const __attribute__((address_space(1))) unsigned int*)(g),
      (__attribute__((address_space(3))) unsigned int*)(l),
      16, 0, 0);
}

// --------------------------- cast fp32 -> bf16 -----------------------------
__global__ __launch_bounds__(256) void cast_f32_bf16(
    const float* __restrict__ src, unsigned short* __restrict__ dst, int n4) {
  int i = blockIdx.x * 256 + threadIdx.x;
  if (i < n4) {
    float4 f = ((const float4*)src)[i];
    ushort4 o;
    o.x = f2bf(f.x); o.y = f2bf(f.y); o.z = f2bf(f.z); o.w = f2bf(f.w);
    ((ushort4*)dst)[i] = o;
  }
}

// ---------------- merged weight prep: 6 transposes in one kernel -----------
__global__ __launch_bounds__(256) void prep_weights(
    const float* __restrict__ qW, const float* __restrict__ kW,
    const float* __restrict__ vW, const float* __restrict__ oW,
    const float* __restrict__ w1, const float* __restrict__ w2,
    unsigned short* __restrict__ qWt, unsigned short* __restrict__ kWt,
    unsigned short* __restrict__ vWt, unsigned short* __restrict__ oWt,
    unsigned short* __restrict__ w1t, unsigned short* __restrict__ w2t) {
  const int t = blockIdx.x;
  const float* W; unsigned short* Wt; int N, K, nt, kt;
  if (t < 2048) {
    const int w = t >> 9, r = t & 511;
    nt = r & 15; kt = r >> 4; N = 1024; K = 1024;
    W  = w == 0 ? qW : w == 1 ? kW : w == 2 ? vW : oW;
    Wt = w == 0 ? qWt : w == 1 ? kWt : w == 2 ? vWt : oWt;
  } else if (t < 4096) {
    const int r = t - 2048;
    nt = r & 63; kt = r >> 6; N = 4096; K = 1024; W = w1; Wt = w1t;
  } else {
    const int r = t - 4096;
    nt = r & 15; kt = r >> 4; N = 1024; K = 4096; W = w2; Wt = w2t;
  }
  const int wave = threadIdx.x >> 6, lane = threadIdx.x & 63;
  const int n = nt * 64 + lane;
  const int k0 = kt * 32 + wave * 8;
  union { int4 v; unsigned short u[8]; } s;
#pragma unroll
  for (int j = 0; j < 8; ++j) s.u[j] = f2bf(W[(size_t)(k0 + j) * N + n]);
  *(int4*)(Wt + (size_t)n * K + k0) = s.v;
}

// ---------------- 256x256 8-phase counted-vmcnt core (B^T) -----------------
// 8 waves 2Mx4N, wave tile 128x64 (8x4 frags), BK=64 (2 kk). R9-verified.
__device__ __forceinline__ void gemm256_8ph(
    const unsigned short* __restrict__ A, const unsigned short* __restrict__ Bt,
    unsigned short* __restrict__ As, unsigned short* __restrict__ Bs,
    const int m0, const int n0, const int K, f32x4 (&acc)[8][4]) {
  const int tid = (int)threadIdx.x;
  const int w = tid >> 6, l = tid & 63;
  const int quad = l >> 4, l16 = l & 15;
  const int wm = (w >> 2) * 128, wn = (w & 3) * 64;

  const int srow = w * 8 + (l >> 3);
  const int schunk = ((l & 7) ^ (l >> 3)) * 8;
  const unsigned short* gA = A + (size_t)(m0 + srow) * K + schunk;
  const unsigned short* gB = Bt + (size_t)(n0 + srow) * K + schunk;
  const int ldsW = w * 512;

  const int xr = l16 & 7;
  const int c0 = ((0 + quad) ^ xr) * 8;
  const int c1 = ((4 + quad) ^ xr) * 8;

  bf16x8 af[4][2], bf0[2][2], bf1[2][2];

  auto STA = [&](int buf, int a, int t) {
    gload16(gA + (size_t)(a * 64) * K + t * 64,
            As + buf * 16384 + a * 4096 + ldsW);
  };
  auto STB = [&](int buf, int a, int t) {
    gload16(gB + (size_t)(a * 64) * K + t * 64,
            Bs + buf * 16384 + a * 4096 + ldsW);
  };
  auto LDA = [&](int buf, int mh) {
    const unsigned short* p = As + buf * 16384 + (wm + mh * 64 + l16) * 64;
#pragma unroll
    for (int mi = 0; mi < 4; ++mi) {
      af[mi][0] = *(const bf16x8*)(p + mi * 16 * 64 + c0);
      af[mi][1] = *(const bf16x8*)(p + mi * 16 * 64 + c1);
    }
  };
  auto LDB = [&](int buf, int nh, bf16x8 (&bf)[2][2]) {
    const unsigned short* p = Bs + buf * 16384 + (wn + nh * 32 + l16) * 64;
#pragma unroll
    for (int ni = 0; ni < 2; ++ni) {
      bf[ni][0] = *(const bf16x8*)(p + ni * 16 * 64 + c0);
      bf[ni][1] = *(const bf16x8*)(p + ni * 16 * 64 + c1);
    }
  };
  auto MM = [&](int mh, int nh, bf16x8 (&bf)[2][2]) {
    __builtin_amdgcn_s_setprio(1);
#pragma unroll
    for (int mi = 0; mi < 4; ++mi)
#pragma unroll
      for (int ni = 0; ni < 2; ++ni) {
        f32x4& a = acc[mh * 4 + mi][nh * 2 + ni];
        a = __builtin_amdgcn_mfma_f32_16x16x32_bf16(af[mi][0], bf[ni][0], a, 0, 0, 0);
        a = __builtin_amdgcn_mfma_f32_16x16x32_bf16(af[mi][1], bf[ni][1], a, 0, 0, 0);
      }
    __builtin_amdgcn_s_setprio(0);
  };

  const int NK = K >> 6;   // >= 2
  STB(0, 0, 0); STB(0, 1, 0); STB(0, 2, 0); STB(0, 3, 0);
  STA(0, 0, 0); STA(0, 2, 0); STA(0, 1, 0); STA(0, 3, 0);
  asm volatile("s_waitcnt vmcnt(2)" ::: "memory");
  __builtin_amdgcn_s_barrier();

#pragma unroll 1
  for (int t = 0; t < NK; ++t) {
    const int c = t & 1, nb = c ^ 1;
    const bool st = (t + 1 < NK);
    // ---- P1 (mh0, nh0)
    LDA(c, 0); LDB(c, 0, bf0);
    if (st) { STB(nb, 0, t + 1); STB(nb, 1, t + 1); }
    __builtin_amdgcn_s_barrier();
    asm volatile("s_waitcnt lgkmcnt(0)" ::: "memory");
    __builtin_amdgcn_sched_barrier(0);
    MM(0, 0, bf0);
    __builtin_amdgcn_s_barrier();
    // ---- P2 (mh0, nh1)
    LDB(c, 1, bf1);
    if (st) { STB(nb, 2, t + 1); STB(nb, 3, t + 1); }
    __builtin_amdgcn_s_barrier();
    asm volatile("s_waitcnt lgkmcnt(0)" ::: "memory");
    __builtin_amdgcn_sched_barrier(0);
    MM(0, 1, bf1);
    if (st) asm volatile("s_waitcnt vmcnt(4)" ::: "memory");
    else    asm volatile("s_waitcnt vmcnt(0)" ::: "memory");
    __builtin_amdgcn_s_barrier();
    // ---- P3 (mh1, nh1)
    LDA(c, 1);
    if (st) { STA(nb, 0, t + 1); STA(nb, 2, t + 1); }
    __builtin_amdgcn_s_barrier();
    asm volatile("s_waitcnt lgkmcnt(0)" ::: "memory");
    __builtin_amdgcn_sched_barrier(0);
    MM(1, 1, bf1);
    __builtin_amdgcn_s_barrier();
    // ---- P4 (mh1, nh0)
    if (st) { STA(nb, 1, t + 1); STA(nb, 3, t + 1); }
    __builtin_amdgcn_s_barrier();
    MM(1, 0, bf0);
    if (st) asm volatile("s_waitcnt vmcnt(2)" ::: "memory");
    __builtin_amdgcn_s_barrier();
  }
}

// --------------------- 256^2 GEMM (B^T), generic epilogue ------------------
template <int EPI>
__global__ __launch_bounds__(512, 1) void gemm256_bt(
    const unsigned short* __restrict__ A, const unsigned short* __restrict__ Bt,
    const float* __restrict__ bias, void* __restrict__ C, int N, int K) {
  __shared__ unsigned short As[2 * 16384];
  __shared__ unsigned short Bs[2 * 16384];
  const int tn = N >> 8;
  const int cpx = (int)gridDim.x >> 3;
  const int sw = ((int)blockIdx.x & 7) * cpx + ((int)blockIdx.x >> 3);
  const int nt = sw % tn, mt = sw / tn;
  const int m0 = mt * 256, n0 = nt * 256;

  f32x4 acc[8][4] = {};
  gemm256_8ph(A, Bt, As, Bs, m0, n0, K, acc);

  const int tid = (int)threadIdx.x;
  const int w = tid >> 6, l = tid & 63;
  const int quad = l >> 4, l16 = l & 15;
  const int wm = (w >> 2) * 128, wn = (w & 3) * 64;
#pragma unroll
  for (int ni = 0; ni < 4; ++ni) {
    const int col = n0 + wn + ni * 16 + l16;
    const float bv = bias[col];
#pragma unroll
    for (int mi = 0; mi < 8; ++mi) {
      const int row = m0 + wm + mi * 16 + quad * 4;
#pragma unroll
      for (int r = 0; r < 4; ++r) {
        float v = acc[mi][ni][r] + bv;
        if (EPI == 2) v = v > 0.f ? v : 0.f;
        if (EPI == 0)
          ((float*)C)[(size_t)(row + r) * N + col] = v;
        else
          ((unsigned short*)C)[(size_t)(row + r) * N + col] = f2bf(v);
      }
    }
  }
}

// -------- 128x128 depth-3 reg-double-buffered GEMM core (B^T) --------------
// 4 waves 2Mx2N, wave tile 64x64 (4x4 frags), BK=32. See file-header ledger.
__device__ __forceinline__ void gemm128_core(
    const unsigned short* __restrict__ A, const unsigned short* __restrict__ Bt,
    unsigned short* __restrict__ As, unsigned short* __restrict__ Bs,
    const int m0, const int n0, const int K, f32x4 (&acc)[4][4]) {
  const int tid = (int)threadIdx.x;
  const int w = tid >> 6, l = tid & 63;
  const int quad = l >> 4, l16 = l & 15;
  const int wm = (w >> 1) * 64, wn = (w & 1) * 64;

  const int lr = l >> 2, lc = l & 3;
  const int swz = (lc ^ ((l >> 3) & 3)) * 8;
  const unsigned short* gA[2]; const unsigned short* gB[2];
  unsigned short* dA[2]; unsigned short* dB[2];
#pragma unroll
  for (int j = 0; j < 2; ++j) {
    const int rr = (w * 2 + j) * 16 + lr;
    gA[j] = A + (size_t)(m0 + rr) * K + swz;
    gB[j] = Bt + (size_t)(n0 + rr) * K + swz;
    dA[j] = As + (w * 2 + j) * 512;
    dB[j] = Bs + (w * 2 + j) * 512;
  }

  const int cread = (quad ^ ((l16 >> 1) & 3)) * 8;
  const int rA = (wm + l16) * 32;
  const int rB = (wn + l16) * 32;

  auto STAGE = [&](int db, int t) {
#pragma unroll
    for (int j = 0; j < 2; ++j) {
      gload16(gA[j] + t * 32, dA[j] + db * 4096);
      gload16(gB[j] + t * 32, dB[j] + db * 4096);
    }
  };
  auto DSR = [&](int db, bf16x8 (&af)[4], bf16x8 (&bf)[4]) {
    const unsigned short* pa = As + db * 4096 + rA + cread;
    const unsigned short* pb = Bs + db * 4096 + rB + cread;
#pragma unroll
    for (int ni = 0; ni < 4; ++ni) bf[ni] = *(const bf16x8*)(pb + ni * 16 * 32);
#pragma unroll
    for (int mi = 0; mi < 4; ++mi) af[mi] = *(const bf16x8*)(pa + mi * 16 * 32);
  };
  auto MM = [&](bf16x8 (&af)[4], bf16x8 (&bf)[4]) {
    __builtin_amdgcn_s_setprio(1);
#pragma unroll
    for (int mi = 0; mi < 4; ++mi)
#pragma unroll
      for (int ni = 0; ni < 4; ++ni)
        acc[mi][ni] = __builtin_amdgcn_mfma_f32_16x16x32_bf16(
            af[mi], bf[ni], acc[mi][ni], 0, 0, 0);
    __builtin_amdgcn_s_setprio(0);
  };

  bf16x8 afA[4], bfA[4], afB[4], bfB[4];

  const int NK = K >> 5;   // even, >= 4
  STAGE(0, 0); STAGE(1, 1); STAGE(2, 2);
  asm volatile("s_waitcnt vmcnt(8)" ::: "memory");
  __builtin_amdgcn_s_barrier();
  DSR(0, afA, bfA);

  // STEP(t): compute tile t from CUR bank, ds_read tile t+1 into NXT bank,
  // stage tile t+3.
#define STEP128(T, afC, bfC, afN, bfN)                                \
  {                                                                   \
    const int t_ = (T);                                               \
    if (t_ + 2 < NK) asm volatile("s_waitcnt vmcnt(4)" ::: "memory"); \
    else             asm volatile("s_waitcnt vmcnt(0)" ::: "memory"); \
    __builtin_amdgcn_s_barrier();                                     \
    DSR((t_ + 1) & 3, afN, bfN);                                      \
    if (t_ + 3 < NK) STAGE((t_ + 3) & 3, t_ + 3);                     \
    MM(afC, bfC);                                                     \
  }

#pragma unroll 1
  for (int t = 0; t < NK - 2; t += 2) {
    STEP128(t, afA, bfA, afB, bfB);
    STEP128(t + 1, afB, bfB, afA, bfA);
  }
  STEP128(NK - 2, afA, bfA, afB, bfB);
  MM(afB, bfB);
#undef STEP128
}

// --------------------- 128^2 GEMM (B^T), generic epilogue ------------------
template <int EPI>
__global__ __launch_bounds__(256, 2) void gemm128_bt(
    const unsigned short* __restrict__ A, const unsigned short* __restrict__ Bt,
    const float* __restrict__ bias, void* __restrict__ C, int N, int K) {
  __shared__ unsigned short As[4 * 4096];
  __shared__ unsigned short Bs[4 * 4096];
  const int NT = N >> 7, band = NT >> 3;
  const int xcd = blockIdx.x & 7, local = blockIdx.x >> 3;
  const int nt = xcd * band + local % band;
  const int mt = local / band;
  const int m0 = mt * 128, n0 = nt * 128;

  f32x4 acc[4][4] = {};
  gemm128_core(A, Bt, As, Bs, m0, n0, K, acc);

  const int tid = (int)threadIdx.x;
  const int w = tid >> 6, l = tid & 63;
  const int quad = l >> 4, l16 = l & 15;
  const int wm = (w >> 1) * 64, wn = (w & 1) * 64;
#pragma unroll
  for (int ni = 0; ni < 4; ++ni) {
    const int col = n0 + wn + ni * 16 + l16;
    const float bv = bias[col];
#pragma unroll
    for (int mi = 0; mi < 4; ++mi) {
      const int row = m0 + wm + mi * 16 + quad * 4;
#pragma unroll
      for (int r = 0; r < 4; ++r) {
        float v = acc[mi][ni][r] + bv;
        if (EPI == 2) v = v > 0.f ? v : 0.f;
        if (EPI == 0)
          ((float*)C)[(size_t)(row + r) * N + col] = v;
        else
          ((unsigned short*)C)[(size_t)(row + r) * N + col] = f2bf(v);
      }
    }
  }
}

// --------------------------- fused QKV GEMM (128^2) ------------------------
#define QSCALE 0.180336884f   // 0.125 * log2(e)

__global__ __launch_bounds__(256, 2) void gemm128_qkv(
    const unsigned short* __restrict__ A, const unsigned short* __restrict__ Bt,
    const float* __restrict__ qb, const float* __restrict__ kb,
    const float* __restrict__ vb, unsigned short* __restrict__ Qo,
    unsigned short* __restrict__ Ko, unsigned short* __restrict__ Vto, int K) {
  __shared__ unsigned short As[4 * 4096];
  __shared__ unsigned short Bs[4 * 4096];
  const int NT = 24, band = 3;                 // N = 3072
  const int xcd = blockIdx.x & 7, local = blockIdx.x >> 3;
  const int nt = xcd * band + local % band;
  const int mt = local / band;
  const int m0 = mt * 128, n0 = nt * 128;

  f32x4 acc[4][4] = {};
  gemm128_core(A, Bt, As, Bs, m0, n0, K, acc);

  const int tid = (int)threadIdx.x;
  const int w = tid >> 6, l = tid & 63;
  const int quad = l >> 4, l16 = l & 15;
  const int wm = (w >> 1) * 64, wn = (w & 1) * 64;

  const int seg = n0 >> 10;                    // 0=Q, 1=K, 2=V (block-uniform)
  const float* bias = seg == 0 ? qb : (seg == 1 ? kb : vb);
#pragma unroll
  for (int ni = 0; ni < 4; ++ni) {
    const int col = (n0 + wn + ni * 16 + l16) & 1023;
    const float bv = bias[col];
#pragma unroll
    for (int mi = 0; mi < 4; ++mi) {
      const int row = m0 + wm + mi * 16 + quad * 4;
      if (seg == 2) {
        const int b = row >> 11, s = row & 2047;
        const int hh = col >> 6, dh = col & 63;
        union { ushort4 v; unsigned short u[4]; } pk;
#pragma unroll
        for (int r = 0; r < 4; ++r) pk.u[r] = f2bf(acc[mi][ni][r] + bv);
        *(ushort4*)(Vto + ((size_t)((b * 16 + hh) * 64 + dh)) * 2048 + s) = pk.v;
      } else if (seg == 0) {
#pragma unroll
        for (int r = 0; r < 4; ++r)
          Qo[(size_t)(row + r) * 1024 + col] = f2bf((acc[mi][ni][r] + bv) * QSCALE);
      } else {
#pragma unroll
        for (int r = 0; r < 4; ++r)
          Ko[(size_t)(row + r) * 1024 + col] = f2bf(acc[mi][ni][r] + bv);
      }
    }
  }
}

// --------------------------- flash attention -------------------------------
__global__ __launch_bounds__(256, 4) void attn_fused(
    const unsigned short* __restrict__ Q, const unsigned short* __restrict__ K,
    const unsigned short* __restrict__ Vt, const int* __restrict__ lengths,
    unsigned short* __restrict__ ctx) {
  constexpr int S = 2048, D = 1024;
  __shared__ unsigned short Ks[64 * 72];
  __shared__ unsigned short Vs[64 * 72];
  __shared__ unsigned short Ps[4 * 32 * 72];

  const int tid = threadIdx.x;
  const int wave = tid >> 6, lane = tid & 63;
  const int quad = lane >> 4, l16 = lane & 15;
  const int bid = blockIdx.x;
  const int qt = bid & 15;
  const int h = (bid >> 4) & 15;
  const int b = bid >> 8;
  const int q0 = qt * 128;
  const int len = lengths[b];
  const int ktEnd = (len + 63) >> 6;
  const float NEGINF = -__builtin_inff();

  const size_t xbase = (size_t)b * S * D + (size_t)h * 64;
  const size_t vtb = (size_t)(b * 16 + h) * 64;

  bf16x8 qf0[2], qf1[2];
#pragma unroll
  for (int mb = 0; mb < 2; ++mb) {
    const unsigned short* qrow =
        Q + xbase + (size_t)(q0 + wave * 32 + mb * 16 + l16) * D;
    qf0[mb] = *(const bf16x8*)(qrow + quad * 8);
    qf1[mb] = *(const bf16x8*)(qrow + 32 + quad * 8);
  }

  const int sr1 = tid >> 3, sc1 = (tid & 7) * 8;
  const int sr2 = (256 + tid) >> 3, sc2 = (tid & 7) * 8;
  const unsigned short* kg1 = K + xbase + (size_t)sr1 * D + sc1;
  const unsigned short* kg2 = K + xbase + (size_t)sr2 * D + sc2;
  const unsigned short* vg1 = Vt + (vtb + sr1) * S + sc1;
  const unsigned short* vg2 = Vt + (vtb + sr2) * S + sc2;

  f32x4 oacc[2][4] = {};
  float rs[2][4] = {};

  unsigned short* pw = Ps + wave * (32 * 72);

  int4 kr1, kr2, vr1, vr2;
  {
    kr1 = *(const int4*)(kg1);
    kr2 = *(const int4*)(kg2);
    vr1 = *(const int4*)(vg1);
    vr2 = *(const int4*)(vg2);
  }

  for (int kt = 0; kt < ktEnd; ++kt) {
    const int k0 = kt * 64;
    __syncthreads();
    *(int4*)(Ks + sr1 * 72 + sc1) = kr1;
    *(int4*)(Ks + sr2 * 72 + sc2) = kr2;
    *(int4*)(Vs + sr1 * 72 + sc1) = vr1;
    *(int4*)(Vs + sr2 * 72 + sc2) = vr2;
    __syncthreads();

    if (kt + 1 < ktEnd) {            // async prefetch of next tile
      const int kn = (kt + 1) * 64;
      kr1 = *(const int4*)(kg1 + (size_t)kn * D);
      kr2 = *(const int4*)(kg2 + (size_t)kn * D);
      vr1 = *(const int4*)(vg1 + kn);
      vr2 = *(const int4*)(vg2 + kn);
    }

    f32x4 sf[2][4];
#pragma unroll
    for (int cb = 0; cb < 4; ++cb) {
      const bf16x8 kf0 = *(const bf16x8*)(Ks + (cb * 16 + l16) * 72 + quad * 8);
      const bf16x8 kf1 = *(const bf16x8*)(Ks + (cb * 16 + l16) * 72 + 32 + quad * 8);
#pragma unroll
      for (int mb = 0; mb < 2; ++mb) {
        f32x4 c = {0.f, 0.f, 0.f, 0.f};
        c = __builtin_amdgcn_mfma_f32_16x16x32_bf16(qf0[mb], kf0, c, 0, 0, 0);
        c = __builtin_amdgcn_mfma_f32_16x16x32_bf16(qf1[mb], kf1, c, 0, 0, 0);
        sf[mb][cb] = c;
      }
    }

    if (k0 + 64 > len) {
#pragma unroll
      for (int cb = 0; cb < 4; ++cb) {
        const bool msk = (k0 + cb * 16 + l16) >= len;
#pragma unroll
        for (int mb = 0; mb < 2; ++mb)
#pragma unroll
          for (int r = 0; r < 4; ++r) sf[mb][cb][r] = msk ? NEGINF : sf[mb][cb][r];
      }
    }

#pragma unroll
    for (int mb = 0; mb < 2; ++mb)
#pragma unroll
      for (int cb = 0; cb < 4; ++cb)
#pragma unroll
        for (int r = 0; r < 4; ++r) {
          const float p = __builtin_amdgcn_exp2f(sf[mb][cb][r]);
          sf[mb][cb][r] = p;
          rs[mb][r] += p;
        }

#pragma unroll
    for (int mb = 0; mb < 2; ++mb)
#pragma unroll
      for (int cb = 0; cb < 4; ++cb)
#pragma unroll
        for (int r = 0; r < 4; ++r)
          pw[(mb * 16 + quad * 4 + r) * 72 + cb * 16 + l16] = f2bf(sf[mb][cb][r]);

    bf16x8 pa0[2], pa1[2];
#pragma unroll
    for (int mb = 0; mb < 2; ++mb) {
      pa0[mb] = *(const bf16x8*)(pw + (mb * 16 + l16) * 72 + quad * 8);
      pa1[mb] = *(const bf16x8*)(pw + (mb * 16 + l16) * 72 + 32 + quad * 8);
    }
#pragma unroll
    for (int cb = 0; cb < 4; ++cb) {
      const bf16x8 vb0 = *(const bf16x8*)(Vs + (cb * 16 + l16) * 72 + quad * 8);
      const bf16x8 vb1 = *(const bf16x8*)(Vs + (cb * 16 + l16) * 72 + 32 + quad * 8);
#pragma unroll
      for (int mb = 0; mb < 2; ++mb) {
        oacc[mb][cb] = __builtin_amdgcn_mfma_f32_16x16x32_bf16(pa0[mb], vb0, oacc[mb][cb], 0, 0, 0);
        oacc[mb][cb] = __builtin_amdgcn_mfma_f32_16x16x32_bf16(pa1[mb], vb1, oacc[mb][cb], 0, 0, 0);
      }
    }
  }

#pragma unroll
  for (int off = 8; off > 0; off >>= 1)
#pragma unroll
    for (int mb = 0; mb < 2; ++mb)
#pragma unroll
      for (int r = 0; r < 4; ++r) rs[mb][r] += __shfl_xor(rs[mb][r], off, 16);

#pragma unroll
  for (int mb = 0; mb < 2; ++mb) {
    float inv[4];
#pragma unroll
    for (int r = 0; r < 4; ++r) inv[r] = 1.0f / rs[mb][r];
#pragma unroll
    for (int cb = 0; cb < 4; ++cb)
#pragma unroll
      for (int r = 0; r < 4; ++r) {
        const int row = q0 + wave * 32 + mb * 16 + quad * 4 + r;
        ctx[xbase + (size_t)row * D + cb * 16 + l16] = f2bf(oacc[mb][cb][r] * inv[r]);
      }
  }
}

// ------------------------------ launcher -----------------------------------
extern "C" void kernel_launch(void* const* d_in, const int* in_sizes, int n_in,
                              void* d_out, int out_size, void* d_ws,
                              size_t ws_size, hipStream_t stream) {
  const float* x  = (const float*)d_in[0];
  const int* lengths = (const int*)d_in[1];
  const float* qW = (const float*)d_in[2];
  const float* qb = (const float*)d_in[3];
  const float* kW = (const float*)d_in[4];
  const float* kb = (const float*)d_in[5];
  const float* vW = (const float*)d_in[6];
  const float* vb = (const float*)d_in[7];
  const float* oW = (const float*)d_in[8];
  const float* ob = (const float*)d_in[9];
  const float* w1 = (const float*)d_in[10];
  const float* b1 = (const float*)d_in[11];
  const float* w2 = (const float*)d_in[12];
  const float* b2 = (const float*)d_in[13];
  float* out = (float*)d_out;

  const int Bx = 4, S = 2048, D = 1024, FF = 4096;
  const int M = Bx * S;  // 8192

  unsigned short* p = (unsigned short*)d_ws;
  unsigned short* xb  = p; p += (size_t)M * D;
  unsigned short* qWt = p; p += (size_t)D * D;   // contiguous [3072,1024]
  unsigned short* kWt = p; p += (size_t)D * D;
  unsigned short* vWt = p; p += (size_t)D * D;
  unsigned short* oWt = p; p += (size_t)D * D;
  unsigned short* w1t = p; p += (size_t)D * FF;   // [FF, D]
  unsigned short* w2t = p; p += (size_t)FF * D;   // [D, FF]
  unsigned short* Qb  = p; p += (size_t)M * D;
  unsigned short* Kb  = p; p += (size_t)M * D;
  unsigned short* Vtb = p; p += (size_t)M * D;    // [B,H,64,S]
  unsigned short* Cb  = p; p += (size_t)M * D;
  unsigned short* Ab  = p; p += (size_t)M * D;
  unsigned short* Hb  = p; p += (size_t)M * FF;

  {
    int n4 = (int)((size_t)M * D / 4);
    cast_f32_bf16<<<dim3((n4 + 255) / 256), dim3(256), 0, stream>>>(x, xb, n4);
  }
  prep_weights<<<dim3(6144), dim3(256), 0, stream>>>(
      qW, kW, vW, oW, w1, w2, qWt, kWt, vWt, oWt, w1t, w2t);

  // qkv: 128^2 reg-dbuf core, 24 x 64 = 1536 blocks
  gemm128_qkv<<<dim3(1536), dim3(256), 0, stream>>>(
      xb, qWt, qb, kb, vb, Qb, Kb, Vtb, D);

  attn_fused<<<dim3(Bx * 16 * (S / 128)), dim3(256), 0, stream>>>(
      Qb, Kb, Vtb, lengths, Cb);

  // proj: 128^2 reg-dbuf core, 8 x 64 = 512 blocks
  gemm128_bt<1><<<dim3(512), dim3(256), 0, stream>>>(Cb, oWt, ob, Ab, D, D);
  // ffn1: 256^2 8-phase core, 32 x 16 = 512 blocks
  gemm256_bt<2><<<dim3(512), dim3(512), 0, stream>>>(Ab, w1t, b1, Hb, FF, D);
  // ffn2: 128^2 reg-dbuf core, 8 x 64 = 512 blocks (K=4096: 128 K-steps)
  gemm128_bt<0><<<dim3(512), dim3(256), 0, stream>>>(Hb, w2t, b2, out, D, FF);
}

// Round 7
// 450.189 us; speedup vs baseline: 1.1750x; 1.0563x over previous
//
#include <hip/hip_runtime.h>

// ---------------------------------------------------------------------------
// TransformerEncoder: B=4, S=2048, D=1024, H=16, HD=64, FF=4096
// Round 12: coalesced bf16 epilogues (per-wave LDS transpose).
// R11 counters: ffn1 WRITE_SIZE = 128 MB for a 64 MB output (2x write amp:
// per-lane 2B scalar stores -> 32-B segments). qkv's V scatter is 8B/lane at
// 4KB stride -> ~8x amp. Fix: after the K-loop, each wave stages its output
// slab in a private 64x72 LDS scratch (bias/relu/QSCALE folded, bf16), then
// stores bf16x8 with 8 lanes covering 128 contiguous bytes per row. V scratch
// is written transposed [dh][s] (acc's 4 rows pack into one ds_write_b64) so
// readout runs along s. K-loop ledgers (R8/R9-verified), grids, attention,
// cast, prep all unchanged. ffn2's fp32 epilogue already clean (64-B rows).
// ---------------------------------------------------------------------------

typedef short bf16x8 __attribute__((ext_vector_type(8)));
typedef float f32x4 __attribute__((ext_vector_type(4)));

__device__ __forceinline__ unsigned short f2bf(float f) {
  unsigned int u = __builtin_bit_cast(unsigned int, f);
  u += 0x7fffu + ((u >> 16) & 1u);   // round-to-nearest-even
  return (unsigned short)(u >> 16);
}

__device__ __forceinline__ void gload16(const unsigned short* g, unsigned short* l) {
  __builtin_amdgcn_global_load_lds(
      (const __attribute__((address_space(1))) unsigned int*)(g),
      (__attribute__((address_space(3))) unsigned int*)(l),
      16, 0, 0);
}

// --------------------------- cast fp32 -> bf16 -----------------------------
__global__ __launch_bounds__(256) void cast_f32_bf16(
    const float* __restrict__ src, unsigned short* __restrict__ dst, int n4) {
  int i = blockIdx.x * 256 + threadIdx.x;
  if (i < n4) {
    float4 f = ((const float4*)src)[i];
    ushort4 o;
    o.x = f2bf(f.x); o.y = f2bf(f.y); o.z = f2bf(f.z); o.w = f2bf(f.w);
    ((ushort4*)dst)[i] = o;
  }
}

// ---------------- merged weight prep: 6 transposes in one kernel -----------
__global__ __launch_bounds__(256) void prep_weights(
    const float* __restrict__ qW, const float* __restrict__ kW,
    const float* __restrict__ vW, const float* __restrict__ oW,
    const float* __restrict__ w1, const float* __restrict__ w2,
    unsigned short* __restrict__ qWt, unsigned short* __restrict__ kWt,
    unsigned short* __restrict__ vWt, unsigned short* __restrict__ oWt,
    unsigned short* __restrict__ w1t, unsigned short* __restrict__ w2t) {
  const int t = blockIdx.x;
  const float* W; unsigned short* Wt; int N, K, nt, kt;
  if (t < 2048) {
    const int w = t >> 9, r = t & 511;
    nt = r & 15; kt = r >> 4; N = 1024; K = 1024;
    W  = w == 0 ? qW : w == 1 ? kW : w == 2 ? vW : oW;
    Wt = w == 0 ? qWt : w == 1 ? kWt : w == 2 ? vWt : oWt;
  } else if (t < 4096) {
    const int r = t - 2048;
    nt = r & 63; kt = r >> 6; N = 4096; K = 1024; W = w1; Wt = w1t;
  } else {
    const int r = t - 4096;
    nt = r & 15; kt = r >> 4; N = 1024; K = 4096; W = w2; Wt = w2t;
  }
  const int wave = threadIdx.x >> 6, lane = threadIdx.x & 63;
  const int n = nt * 64 + lane;
  const int k0 = kt * 32 + wave * 8;
  union { int4 v; unsigned short u[8]; } s;
#pragma unroll
  for (int j = 0; j < 8; ++j) s.u[j] = f2bf(W[(size_t)(k0 + j) * N + n]);
  *(int4*)(Wt + (size_t)n * K + k0) = s.v;
}

// ---------------- 256x256 8-phase counted-vmcnt core (B^T) -----------------
// 8 waves 2Mx4N, wave tile 128x64 (8x4 frags), BK=64 (2 kk). R9-verified.
__device__ __forceinline__ void gemm256_8ph(
    const unsigned short* __restrict__ A, const unsigned short* __restrict__ Bt,
    unsigned short* __restrict__ As, unsigned short* __restrict__ Bs,
    const int m0, const int n0, const int K, f32x4 (&acc)[8][4]) {
  const int tid = (int)threadIdx.x;
  const int w = tid >> 6, l = tid & 63;
  const int quad = l >> 4, l16 = l & 15;
  const int wm = (w >> 2) * 128, wn = (w & 3) * 64;

  const int srow = w * 8 + (l >> 3);
  const int schunk = ((l & 7) ^ (l >> 3)) * 8;
  const unsigned short* gA = A + (size_t)(m0 + srow) * K + schunk;
  const unsigned short* gB = Bt + (size_t)(n0 + srow) * K + schunk;
  const int ldsW = w * 512;

  const int xr = l16 & 7;
  const int c0 = ((0 + quad) ^ xr) * 8;
  const int c1 = ((4 + quad) ^ xr) * 8;

  bf16x8 af[4][2], bf0[2][2], bf1[2][2];

  auto STA = [&](int buf, int a, int t) {
    gload16(gA + (size_t)(a * 64) * K + t * 64,
            As + buf * 16384 + a * 4096 + ldsW);
  };
  auto STB = [&](int buf, int a, int t) {
    gload16(gB + (size_t)(a * 64) * K + t * 64,
            Bs + buf * 16384 + a * 4096 + ldsW);
  };
  auto LDA = [&](int buf, int mh) {
    const unsigned short* p = As + buf * 16384 + (wm + mh * 64 + l16) * 64;
#pragma unroll
    for (int mi = 0; mi < 4; ++mi) {
      af[mi][0] = *(const bf16x8*)(p + mi * 16 * 64 + c0);
      af[mi][1] = *(const bf16x8*)(p + mi * 16 * 64 + c1);
    }
  };
  auto LDB = [&](int buf, int nh, bf16x8 (&bf)[2][2]) {
    const unsigned short* p = Bs + buf * 16384 + (wn + nh * 32 + l16) * 64;
#pragma unroll
    for (int ni = 0; ni < 2; ++ni) {
      bf[ni][0] = *(const bf16x8*)(p + ni * 16 * 64 + c0);
      bf[ni][1] = *(const bf16x8*)(p + ni * 16 * 64 + c1);
    }
  };
  auto MM = [&](int mh, int nh, bf16x8 (&bf)[2][2]) {
    __builtin_amdgcn_s_setprio(1);
#pragma unroll
    for (int mi = 0; mi < 4; ++mi)
#pragma unroll
      for (int ni = 0; ni < 2; ++ni) {
        f32x4& a = acc[mh * 4 + mi][nh * 2 + ni];
        a = __builtin_amdgcn_mfma_f32_16x16x32_bf16(af[mi][0], bf[ni][0], a, 0, 0, 0);
        a = __builtin_amdgcn_mfma_f32_16x16x32_bf16(af[mi][1], bf[ni][1], a, 0, 0, 0);
      }
    __builtin_amdgcn_s_setprio(0);
  };

  const int NK = K >> 6;   // >= 2
  STB(0, 0, 0); STB(0, 1, 0); STB(0, 2, 0); STB(0, 3, 0);
  STA(0, 0, 0); STA(0, 2, 0); STA(0, 1, 0); STA(0, 3, 0);
  asm volatile("s_waitcnt vmcnt(2)" ::: "memory");
  __builtin_amdgcn_s_barrier();

#pragma unroll 1
  for (int t = 0; t < NK; ++t) {
    const int c = t & 1, nb = c ^ 1;
    const bool st = (t + 1 < NK);
    // ---- P1 (mh0, nh0)
    LDA(c, 0); LDB(c, 0, bf0);
    if (st) { STB(nb, 0, t + 1); STB(nb, 1, t + 1); }
    __builtin_amdgcn_s_barrier();
    asm volatile("s_waitcnt lgkmcnt(0)" ::: "memory");
    __builtin_amdgcn_sched_barrier(0);
    MM(0, 0, bf0);
    __builtin_amdgcn_s_barrier();
    // ---- P2 (mh0, nh1)
    LDB(c, 1, bf1);
    if (st) { STB(nb, 2, t + 1); STB(nb, 3, t + 1); }
    __builtin_amdgcn_s_barrier();
    asm volatile("s_waitcnt lgkmcnt(0)" ::: "memory");
    __builtin_amdgcn_sched_barrier(0);
    MM(0, 1, bf1);
    if (st) asm volatile("s_waitcnt vmcnt(4)" ::: "memory");
    else    asm volatile("s_waitcnt vmcnt(0)" ::: "memory");
    __builtin_amdgcn_s_barrier();
    // ---- P3 (mh1, nh1)
    LDA(c, 1);
    if (st) { STA(nb, 0, t + 1); STA(nb, 2, t + 1); }
    __builtin_amdgcn_s_barrier();
    asm volatile("s_waitcnt lgkmcnt(0)" ::: "memory");
    __builtin_amdgcn_sched_barrier(0);
    MM(1, 1, bf1);
    __builtin_amdgcn_s_barrier();
    // ---- P4 (mh1, nh0)
    if (st) { STA(nb, 1, t + 1); STA(nb, 3, t + 1); }
    __builtin_amdgcn_s_barrier();
    MM(1, 0, bf0);
    if (st) asm volatile("s_waitcnt vmcnt(2)" ::: "memory");
    __builtin_amdgcn_s_barrier();
  }
}

// --------------------- 256^2 GEMM (B^T), generic epilogue ------------------
// EPI 1/2: coalesced bf16 epilogue via per-wave 64x72 LDS scratch, 2 halves.
template <int EPI>
__global__ __launch_bounds__(512, 1) void gemm256_bt(
    const unsigned short* __restrict__ A, const unsigned short* __restrict__ Bt,
    const float* __restrict__ bias, void* __restrict__ C, int N, int K) {
  __shared__ unsigned short As[2 * 16384];
  __shared__ unsigned short Bs[2 * 16384];
  const int tn = N >> 8;
  const int cpx = (int)gridDim.x >> 3;
  const int sw = ((int)blockIdx.x & 7) * cpx + ((int)blockIdx.x >> 3);
  const int nt = sw % tn, mt = sw / tn;
  const int m0 = mt * 256, n0 = nt * 256;

  f32x4 acc[8][4] = {};
  gemm256_8ph(A, Bt, As, Bs, m0, n0, K, acc);

  const int tid = (int)threadIdx.x;
  const int w = tid >> 6, l = tid & 63;
  const int quad = l >> 4, l16 = l & 15;
  const int wm = (w >> 2) * 128, wn = (w & 3) * 64;

  if (EPI == 0) {
#pragma unroll
    for (int ni = 0; ni < 4; ++ni) {
      const int col = n0 + wn + ni * 16 + l16;
      const float bv = bias[col];
#pragma unroll
      for (int mi = 0; mi < 8; ++mi) {
        const int row = m0 + wm + mi * 16 + quad * 4;
#pragma unroll
        for (int r = 0; r < 4; ++r)
          ((float*)C)[(size_t)(row + r) * N + col] = acc[mi][ni][r] + bv;
      }
    }
    return;
  }

  // coalesced bf16 path
  __syncthreads();
  unsigned short* sc = (w < 4) ? (As + w * 4608) : (Bs + (w - 4) * 4608);
  const int rr8 = l >> 3, c8 = (l & 7) * 8;
#pragma unroll
  for (int half = 0; half < 2; ++half) {
#pragma unroll
    for (int ni = 0; ni < 4; ++ni) {
      const int col = n0 + wn + ni * 16 + l16;
      const float bv = bias[col];
#pragma unroll
      for (int mi2 = 0; mi2 < 4; ++mi2) {
#pragma unroll
        for (int r = 0; r < 4; ++r) {
          float v = acc[half * 4 + mi2][ni][r] + bv;
          if (EPI == 2) v = v > 0.f ? v : 0.f;
          sc[(mi2 * 16 + quad * 4 + r) * 72 + ni * 16 + l16] = f2bf(v);
        }
      }
    }
    __syncthreads();
#pragma unroll
    for (int i = 0; i < 8; ++i) {
      bf16x8 vv = *(const bf16x8*)(sc + (i * 8 + rr8) * 72 + c8);
      const int row = m0 + wm + half * 64 + i * 8 + rr8;
      *(bf16x8*)((unsigned short*)C + (size_t)row * N + n0 + wn + c8) = vv;
    }
    __syncthreads();
  }
}

// -------- 128x128 depth-3 reg-double-buffered GEMM core (R11-verified) -----
__device__ __forceinline__ void gemm128_core(
    const unsigned short* __restrict__ A, const unsigned short* __restrict__ Bt,
    unsigned short* __restrict__ As, unsigned short* __restrict__ Bs,
    const int m0, const int n0, const int K, f32x4 (&acc)[4][4]) {
  const int tid = (int)threadIdx.x;
  const int w = tid >> 6, l = tid & 63;
  const int quad = l >> 4, l16 = l & 15;
  const int wm = (w >> 1) * 64, wn = (w & 1) * 64;

  const int lr = l >> 2, lc = l & 3;
  const int swz = (lc ^ ((l >> 3) & 3)) * 8;
  const unsigned short* gA[2]; const unsigned short* gB[2];
  unsigned short* dA[2]; unsigned short* dB[2];
#pragma unroll
  for (int j = 0; j < 2; ++j) {
    const int rr = (w * 2 + j) * 16 + lr;
    gA[j] = A + (size_t)(m0 + rr) * K + swz;
    gB[j] = Bt + (size_t)(n0 + rr) * K + swz;
    dA[j] = As + (w * 2 + j) * 512;
    dB[j] = Bs + (w * 2 + j) * 512;
  }

  const int cread = (quad ^ ((l16 >> 1) & 3)) * 8;
  const int rA = (wm + l16) * 32;
  const int rB = (wn + l16) * 32;

  auto STAGE = [&](int db, int t) {
#pragma unroll
    for (int j = 0; j < 2; ++j) {
      gload16(gA[j] + t * 32, dA[j] + db * 4096);
      gload16(gB[j] + t * 32, dB[j] + db * 4096);
    }
  };
  auto DSR = [&](int db, bf16x8 (&af)[4], bf16x8 (&bf)[4]) {
    const unsigned short* pa = As + db * 4096 + rA + cread;
    const unsigned short* pb = Bs + db * 4096 + rB + cread;
#pragma unroll
    for (int ni = 0; ni < 4; ++ni) bf[ni] = *(const bf16x8*)(pb + ni * 16 * 32);
#pragma unroll
    for (int mi = 0; mi < 4; ++mi) af[mi] = *(const bf16x8*)(pa + mi * 16 * 32);
  };
  auto MM = [&](bf16x8 (&af)[4], bf16x8 (&bf)[4]) {
    __builtin_amdgcn_s_setprio(1);
#pragma unroll
    for (int mi = 0; mi < 4; ++mi)
#pragma unroll
      for (int ni = 0; ni < 4; ++ni)
        acc[mi][ni] = __builtin_amdgcn_mfma_f32_16x16x32_bf16(
            af[mi], bf[ni], acc[mi][ni], 0, 0, 0);
    __builtin_amdgcn_s_setprio(0);
  };

  bf16x8 afA[4], bfA[4], afB[4], bfB[4];

  const int NK = K >> 5;   // even, >= 4
  STAGE(0, 0); STAGE(1, 1); STAGE(2, 2);
  asm volatile("s_waitcnt vmcnt(8)" ::: "memory");
  __builtin_amdgcn_s_barrier();
  DSR(0, afA, bfA);

#define STEP128(T, afC, bfC, afN, bfN)                                \
  {                                                                   \
    const int t_ = (T);                                               \
    if (t_ + 2 < NK) asm volatile("s_waitcnt vmcnt(4)" ::: "memory"); \
    else             asm volatile("s_waitcnt vmcnt(0)" ::: "memory"); \
    __builtin_amdgcn_s_barrier();                                     \
    DSR((t_ + 1) & 3, afN, bfN);                                      \
    if (t_ + 3 < NK) STAGE((t_ + 3) & 3, t_ + 3);                     \
    MM(afC, bfC);                                                     \
  }

#pragma unroll 1
  for (int t = 0; t < NK - 2; t += 2) {
    STEP128(t, afA, bfA, afB, bfB);
    STEP128(t + 1, afB, bfB, afA, bfA);
  }
  STEP128(NK - 2, afA, bfA, afB, bfB);
  MM(afB, bfB);
#undef STEP128
}

// --------------------- 128^2 GEMM (B^T), generic epilogue ------------------
// EPI 1: coalesced bf16 epilogue (per-wave 64x72 LDS scratch).
template <int EPI>
__global__ __launch_bounds__(256, 2) void gemm128_bt(
    const unsigned short* __restrict__ A, const unsigned short* __restrict__ Bt,
    const float* __restrict__ bias, void* __restrict__ C, int N, int K) {
  __shared__ unsigned short As[4 * 4096];
  __shared__ unsigned short Bs[4 * 4096];
  const int NT = N >> 7, band = NT >> 3;
  const int xcd = blockIdx.x & 7, local = blockIdx.x >> 3;
  const int nt = xcd * band + local % band;
  const int mt = local / band;
  const int m0 = mt * 128, n0 = nt * 128;

  f32x4 acc[4][4] = {};
  gemm128_core(A, Bt, As, Bs, m0, n0, K, acc);

  const int tid = (int)threadIdx.x;
  const int w = tid >> 6, l = tid & 63;
  const int quad = l >> 4, l16 = l & 15;
  const int wm = (w >> 1) * 64, wn = (w & 1) * 64;

  if (EPI == 0) {
#pragma unroll
    for (int ni = 0; ni < 4; ++ni) {
      const int col = n0 + wn + ni * 16 + l16;
      const float bv = bias[col];
#pragma unroll
      for (int mi = 0; mi < 4; ++mi) {
        const int row = m0 + wm + mi * 16 + quad * 4;
#pragma unroll
        for (int r = 0; r < 4; ++r)
          ((float*)C)[(size_t)(row + r) * N + col] = acc[mi][ni][r] + bv;
      }
    }
    return;
  }

  __syncthreads();   // close K-loop LDS use (reg-dbuf core reads after barrier)
  unsigned short* sc = (w < 2) ? (As + w * 4608) : (Bs + (w - 2) * 4608);
  const int rr8 = l >> 3, c8 = (l & 7) * 8;
#pragma unroll
  for (int ni = 0; ni < 4; ++ni) {
    const int col = n0 + wn + ni * 16 + l16;
    const float bv = bias[col];
#pragma unroll
    for (int mi = 0; mi < 4; ++mi) {
#pragma unroll
      for (int r = 0; r < 4; ++r) {
        float v = acc[mi][ni][r] + bv;
        if (EPI == 2) v = v > 0.f ? v : 0.f;
        sc[(mi * 16 + quad * 4 + r) * 72 + ni * 16 + l16] = f2bf(v);
      }
    }
  }
  __syncthreads();
#pragma unroll
  for (int i = 0; i < 8; ++i) {
    bf16x8 vv = *(const bf16x8*)(sc + (i * 8 + rr8) * 72 + c8);
    const int row = m0 + wm + i * 8 + rr8;
    *(bf16x8*)((unsigned short*)C + (size_t)row * N + n0 + wn + c8) = vv;
  }
}

// --------------------------- fused QKV GEMM (128^2) ------------------------
#define QSCALE 0.180336884f   // 0.125 * log2(e)

__global__ __launch_bounds__(256, 2) void gemm128_qkv(
    const unsigned short* __restrict__ A, const unsigned short* __restrict__ Bt,
    const float* __restrict__ qb, const float* __restrict__ kb,
    const float* __restrict__ vb, unsigned short* __restrict__ Qo,
    unsigned short* __restrict__ Ko, unsigned short* __restrict__ Vto, int K) {
  __shared__ unsigned short As[4 * 4096];
  __shared__ unsigned short Bs[4 * 4096];
  const int NT = 24, band = 3;                 // N = 3072
  const int xcd = blockIdx.x & 7, local = blockIdx.x >> 3;
  const int nt = xcd * band + local % band;
  const int mt = local / band;
  const int m0 = mt * 128, n0 = nt * 128;

  f32x4 acc[4][4] = {};
  gemm128_core(A, Bt, As, Bs, m0, n0, K, acc);

  const int tid = (int)threadIdx.x;
  const int w = tid >> 6, l = tid & 63;
  const int quad = l >> 4, l16 = l & 15;
  const int wm = (w >> 1) * 64, wn = (w & 1) * 64;

  const int seg = n0 >> 10;                    // 0=Q, 1=K, 2=V (block-uniform)
  const float* bias = seg == 0 ? qb : (seg == 1 ? kb : vb);
  const int colb = (n0 + wn) & 1023;           // wave-uniform col base

  __syncthreads();   // close K-loop LDS use
  unsigned short* sc = (w < 2) ? (As + w * 4608) : (Bs + (w - 2) * 4608);
  const int rr8 = l >> 3, c8 = (l & 7) * 8;

  if (seg == 2) {
    // V: scratch transposed [dh][s]; readout runs along s (contiguous in Vto)
    const int b = m0 >> 11;                    // tile never crosses b (128|2048)
    const int hh = colb >> 6;
    const int s0 = (m0 & 2047) + wm;
#pragma unroll
    for (int ni = 0; ni < 4; ++ni) {
      const float bv = bias[colb + ni * 16 + l16];
#pragma unroll
      for (int mi = 0; mi < 4; ++mi) {
        union { ushort4 v; unsigned short u[4]; } pk;
#pragma unroll
        for (int r = 0; r < 4; ++r) pk.u[r] = f2bf(acc[mi][ni][r] + bv);
        *(ushort4*)(sc + (ni * 16 + l16) * 72 + mi * 16 + quad * 4) = pk.v;
      }
    }
    __syncthreads();
    unsigned short* vbase = Vto + ((size_t)(b * 16 + hh) * 64) * 2048;
#pragma unroll
    for (int i = 0; i < 8; ++i) {
      bf16x8 vv = *(const bf16x8*)(sc + (i * 8 + rr8) * 72 + c8);
      const int dh = i * 8 + rr8;
      *(bf16x8*)(vbase + (size_t)dh * 2048 + s0 + c8) = vv;
    }
  } else {
    // Q/K: row-major scratch, coalesced 128-B row stores
    unsigned short* Out = seg == 0 ? Qo : Ko;
#pragma unroll
    for (int ni = 0; ni < 4; ++ni) {
      const float bv = bias[colb + ni * 16 + l16];
#pragma unroll
      for (int mi = 0; mi < 4; ++mi) {
#pragma unroll
        for (int r = 0; r < 4; ++r) {
          float v = acc[mi][ni][r] + bv;
          if (seg == 0) v *= QSCALE;
          sc[(mi * 16 + quad * 4 + r) * 72 + ni * 16 + l16] = f2bf(v);
        }
      }
    }
    __syncthreads();
#pragma unroll
    for (int i = 0; i < 8; ++i) {
      bf16x8 vv = *(const bf16x8*)(sc + (i * 8 + rr8) * 72 + c8);
      const int row = m0 + wm + i * 8 + rr8;
      *(bf16x8*)(Out + (size_t)row * 1024 + colb + c8) = vv;
    }
  }
}

// --------------------------- flash attention -------------------------------
__global__ __launch_bounds__(256, 4) void attn_fused(
    const unsigned short* __restrict__ Q, const unsigned short* __restrict__ K,
    const unsigned short* __restrict__ Vt, const int* __restrict__ lengths,
    unsigned short* __restrict__ ctx) {
  constexpr int S = 2048, D = 1024;
  __shared__ unsigned short Ks[64 * 72];
  __shared__ unsigned short Vs[64 * 72];
  __shared__ unsigned short Ps[4 * 32 * 72];

  const int tid = threadIdx.x;
  const int wave = tid >> 6, lane = tid & 63;
  const int quad = lane >> 4, l16 = lane & 15;
  const int bid = blockIdx.x;
  const int qt = bid & 15;
  const int h = (bid >> 4) & 15;
  const int b = bid >> 8;
  const int q0 = qt * 128;
  const int len = lengths[b];
  const int ktEnd = (len + 63) >> 6;
  const float NEGINF = -__builtin_inff();

  const size_t xbase = (size_t)b * S * D + (size_t)h * 64;
  const size_t vtb = (size_t)(b * 16 + h) * 64;

  bf16x8 qf0[2], qf1[2];
#pragma unroll
  for (int mb = 0; mb < 2; ++mb) {
    const unsigned short* qrow =
        Q + xbase + (size_t)(q0 + wave * 32 + mb * 16 + l16) * D;
    qf0[mb] = *(const bf16x8*)(qrow + quad * 8);
    qf1[mb] = *(const bf16x8*)(qrow + 32 + quad * 8);
  }

  const int sr1 = tid >> 3, sc1 = (tid & 7) * 8;
  const int sr2 = (256 + tid) >> 3, sc2 = (tid & 7) * 8;
  const unsigned short* kg1 = K + xbase + (size_t)sr1 * D + sc1;
  const unsigned short* kg2 = K + xbase + (size_t)sr2 * D + sc2;
  const unsigned short* vg1 = Vt + (vtb + sr1) * S + sc1;
  const unsigned short* vg2 = Vt + (vtb + sr2) * S + sc2;

  f32x4 oacc[2][4] = {};
  float rs[2][4] = {};

  unsigned short* pw = Ps + wave * (32 * 72);

  int4 kr1, kr2, vr1, vr2;
  {
    kr1 = *(const int4*)(kg1);
    kr2 = *(const int4*)(kg2);
    vr1 = *(const int4*)(vg1);
    vr2 = *(const int4*)(vg2);
  }

  for (int kt = 0; kt < ktEnd; ++kt) {
    const int k0 = kt * 64;
    __syncthreads();
    *(int4*)(Ks + sr1 * 72 + sc1) = kr1;
    *(int4*)(Ks + sr2 * 72 + sc2) = kr2;
    *(int4*)(Vs + sr1 * 72 + sc1) = vr1;
    *(int4*)(Vs + sr2 * 72 + sc2) = vr2;
    __syncthreads();

    if (kt + 1 < ktEnd) {            // async prefetch of next tile
      const int kn = (kt + 1) * 64;
      kr1 = *(const int4*)(kg1 + (size_t)kn * D);
      kr2 = *(const int4*)(kg2 + (size_t)kn * D);
      vr1 = *(const int4*)(vg1 + kn);
      vr2 = *(const int4*)(vg2 + kn);
    }

    f32x4 sf[2][4];
#pragma unroll
    for (int cb = 0; cb < 4; ++cb) {
      const bf16x8 kf0 = *(const bf16x8*)(Ks + (cb * 16 + l16) * 72 + quad * 8);
      const bf16x8 kf1 = *(const bf16x8*)(Ks + (cb * 16 + l16) * 72 + 32 + quad * 8);
#pragma unroll
      for (int mb = 0; mb < 2; ++mb) {
        f32x4 c = {0.f, 0.f, 0.f, 0.f};
        c = __builtin_amdgcn_mfma_f32_16x16x32_bf16(qf0[mb], kf0, c, 0, 0, 0);
        c = __builtin_amdgcn_mfma_f32_16x16x32_bf16(qf1[mb], kf1, c, 0, 0, 0);
        sf[mb][cb] = c;
      }
    }

    if (k0 + 64 > len) {
#pragma unroll
      for (int cb = 0; cb < 4; ++cb) {
        const bool msk = (k0 + cb * 16 + l16) >= len;
#pragma unroll
        for (int mb = 0; mb < 2; ++mb)
#pragma unroll
          for (int r = 0; r < 4; ++r) sf[mb][cb][r] = msk ? NEGINF : sf[mb][cb][r];
      }
    }

#pragma unroll
    for (int mb = 0; mb < 2; ++mb)
#pragma unroll
      for (int cb = 0; cb < 4; ++cb)
#pragma unroll
        for (int r = 0; r < 4; ++r) {
          const float p = __builtin_amdgcn_exp2f(sf[mb][cb][r]);
          sf[mb][cb][r] = p;
          rs[mb][r] += p;
        }

#pragma unroll
    for (int mb = 0; mb < 2; ++mb)
#pragma unroll
      for (int cb = 0; cb < 4; ++cb)
#pragma unroll
        for (int r = 0; r < 4; ++r)
          pw[(mb * 16 + quad * 4 + r) * 72 + cb * 16 + l16] = f2bf(sf[mb][cb][r]);

    bf16x8 pa0[2], pa1[2];
#pragma unroll
    for (int mb = 0; mb < 2; ++mb) {
      pa0[mb] = *(const bf16x8*)(pw + (mb * 16 + l16) * 72 + quad * 8);
      pa1[mb] = *(const bf16x8*)(pw + (mb * 16 + l16) * 72 + 32 + quad * 8);
    }
#pragma unroll
    for (int cb = 0; cb < 4; ++cb) {
      const bf16x8 vb0 = *(const bf16x8*)(Vs + (cb * 16 + l16) * 72 + quad * 8);
      const bf16x8 vb1 = *(const bf16x8*)(Vs + (cb * 16 + l16) * 72 + 32 + quad * 8);
#pragma unroll
      for (int mb = 0; mb < 2; ++mb) {
        oacc[mb][cb] = __builtin_amdgcn_mfma_f32_16x16x32_bf16(pa0[mb], vb0, oacc[mb][cb], 0, 0, 0);
        oacc[mb][cb] = __builtin_amdgcn_mfma_f32_16x16x32_bf16(pa1[mb], vb1, oacc[mb][cb], 0, 0, 0);
      }
    }
  }

#pragma unroll
  for (int off = 8; off > 0; off >>= 1)
#pragma unroll
    for (int mb = 0; mb < 2; ++mb)
#pragma unroll
      for (int r = 0; r < 4; ++r) rs[mb][r] += __shfl_xor(rs[mb][r], off, 16);

#pragma unroll
  for (int mb = 0; mb < 2; ++mb) {
    float inv[4];
#pragma unroll
    for (int r = 0; r < 4; ++r) inv[r] = 1.0f / rs[mb][r];
#pragma unroll
    for (int cb = 0; cb < 4; ++cb)
#pragma unroll
      for (int r = 0; r < 4; ++r) {
        const int row = q0 + wave * 32 + mb * 16 + quad * 4 + r;
        ctx[xbase + (size_t)row * D + cb * 16 + l16] = f2bf(oacc[mb][cb][r] * inv[r]);
      }
  }
}

// ------------------------------ launcher -----------------------------------
extern "C" void kernel_launch(void* const* d_in, const int* in_sizes, int n_in,
                              void* d_out, int out_size, void* d_ws,
                              size_t ws_size, hipStream_t stream) {
  const float* x  = (const float*)d_in[0];
  const int* lengths = (const int*)d_in[1];
  const float* qW = (const float*)d_in[2];
  const float* qb = (const float*)d_in[3];
  const float* kW = (const float*)d_in[4];
  const float* kb = (const float*)d_in[5];
  const float* vW = (const float*)d_in[6];
  const float* vb = (const float*)d_in[7];
  const float* oW = (const float*)d_in[8];
  const float* ob = (const float*)d_in[9];
  const float* w1 = (const float*)d_in[10];
  const float* b1 = (const float*)d_in[11];
  const float* w2 = (const float*)d_in[12];
  const float* b2 = (const float*)d_in[13];
  float* out = (float*)d_out;

  const int Bx = 4, S = 2048, D = 1024, FF = 4096;
  const int M = Bx * S;  // 8192

  unsigned short* p = (unsigned short*)d_ws;
  unsigned short* xb  = p; p += (size_t)M * D;
  unsigned short* qWt = p; p += (size_t)D * D;   // contiguous [3072,1024]
  unsigned short* kWt = p; p += (size_t)D * D;
  unsigned short* vWt = p; p += (size_t)D * D;
  unsigned short* oWt = p; p += (size_t)D * D;
  unsigned short* w1t = p; p += (size_t)D * FF;   // [FF, D]
  unsigned short* w2t = p; p += (size_t)FF * D;   // [D, FF]
  unsigned short* Qb  = p; p += (size_t)M * D;
  unsigned short* Kb  = p; p += (size_t)M * D;
  unsigned short* Vtb = p; p += (size_t)M * D;    // [B,H,64,S]
  unsigned short* Cb  = p; p += (size_t)M * D;
  unsigned short* Ab  = p; p += (size_t)M * D;
  unsigned short* Hb  = p; p += (size_t)M * FF;

  {
    int n4 = (int)((size_t)M * D / 4);
    cast_f32_bf16<<<dim3((n4 + 255) / 256), dim3(256), 0, stream>>>(x, xb, n4);
  }
  prep_weights<<<dim3(6144), dim3(256), 0, stream>>>(
      qW, kW, vW, oW, w1, w2, qWt, kWt, vWt, oWt, w1t, w2t);

  // qkv: 128^2 reg-dbuf core, 24 x 64 = 1536 blocks
  gemm128_qkv<<<dim3(1536), dim3(256), 0, stream>>>(
      xb, qWt, qb, kb, vb, Qb, Kb, Vtb, D);

  attn_fused<<<dim3(Bx * 16 * (S / 128)), dim3(256), 0, stream>>>(
      Qb, Kb, Vtb, lengths, Cb);

  // proj: 128^2 reg-dbuf core, 8 x 64 = 512 blocks
  gemm128_bt<1><<<dim3(512), dim3(256), 0, stream>>>(Cb, oWt, ob, Ab, D, D);
  // ffn1: 256^2 8-phase core, 32 x 16 = 512 blocks
  gemm256_bt<2><<<dim3(512), dim3(512), 0, stream>>>(Ab, w1t, b1, Hb, FF, D);
  // ffn2: 128^2 reg-dbuf core, 8 x 64 = 512 blocks (K=4096: 128 K-steps)
  gemm128_bt<0><<<dim3(512), dim3(256), 0, stream>>>(Hb, w2t, b2, out, D, FF);
}

// Round 8
// 440.019 us; speedup vs baseline: 1.2021x; 1.0231x over previous
//
#include <hip/hip_runtime.h>

// ---------------------------------------------------------------------------
// TransformerEncoder: B=4, S=2048, D=1024, H=16, HD=64, FF=4096
// Round 13: (1) 256^2 core rebuilt as BK=32 / 3-buf / 4-phase with whole-tile
// counted vmcnt — removes the R9 8-phase's derived 600-750 cy/K-tile stall
// (a0,a2 staged 1 phase before their wait; measured MfmaUtil 29% matched
// that prediction). New ledger (same proof skeleton as the verified 128^2
// depth-3): tile t computes buf t%3; stages tile t+2 into buf (t+2)%3 =
// (t-1)%3 (last read closed at t-1's final barrier) spread 1 round/phase
// (A0,A1,B0,B1); ONE vmcnt(4) per tile at P4-end => tile t+1 (issued during
// t-1, 4-8 phases of flight > HBM latency) fully landed. Tail: t=NK-2
// vmcnt(0); t=NK-1 none. NK>=3. LDS 96 KB.
// (2) 2-D chunked XCD mapping on all GEMMs: each XCD owns an (mt x nt)
// chunk so concurrent blocks share A-rows AND B-cols (R12: ffn2 FETCH=268MB
// for ~75MB unique = 4x fill amp from n-band streaming of A).
//   ffn1: 4x2 chunks of 8x8   (A 4MB + B 4MB per XCD)
//   ffn2/proj: 8x1 chunks of 8x8 (ffn2 16MB, proj 4MB = L2-resident)
//   qkv: 4x2 chunks of 16x12  (A 4MB + B 3MB)
// Epilogues (R12-verified coalesced), 128^2 reg-dbuf core (R11-verified),
// attention, cast, prep unchanged.
// ---------------------------------------------------------------------------

typedef short bf16x8 __attribute__((ext_vector_type(8)));
typedef float f32x4 __attribute__((ext_vector_type(4)));

__device__ __forceinline__ unsigned short f2bf(float f) {
  unsigned int u = __builtin_bit_cast(unsigned int, f);
  u += 0x7fffu + ((u >> 16) & 1u);   // round-to-nearest-even
  return (unsigned short)(u >> 16);
}

__device__ __forceinline__ void gload16(const unsigned short* g, unsigned short* l) {
  __builtin_amdgcn_global_load_lds(
      (const __attribute__((address_space(1))) unsigned int*)(g),
      (__attribute__((address_space(3))) unsigned int*)(l),
      16, 0, 0);
}

// --------------------------- cast fp32 -> bf16 -----------------------------
__global__ __launch_bounds__(256) void cast_f32_bf16(
    const float* __restrict__ src, unsigned short* __restrict__ dst, int n4) {
  int i = blockIdx.x * 256 + threadIdx.x;
  if (i < n4) {
    float4 f = ((const float4*)src)[i];
    ushort4 o;
    o.x = f2bf(f.x); o.y = f2bf(f.y); o.z = f2bf(f.z); o.w = f2bf(f.w);
    ((ushort4*)dst)[i] = o;
  }
}

// ---------------- merged weight prep: 6 transposes in one kernel -----------
__global__ __launch_bounds__(256) void prep_weights(
    const float* __restrict__ qW, const float* __restrict__ kW,
    const float* __restrict__ vW, const float* __restrict__ oW,
    const float* __restrict__ w1, const float* __restrict__ w2,
    unsigned short* __restrict__ qWt, unsigned short* __restrict__ kWt,
    unsigned short* __restrict__ vWt, unsigned short* __restrict__ oWt,
    unsigned short* __restrict__ w1t, unsigned short* __restrict__ w2t) {
  const int t = blockIdx.x;
  const float* W; unsigned short* Wt; int N, K, nt, kt;
  if (t < 2048) {
    const int w = t >> 9, r = t & 511;
    nt = r & 15; kt = r >> 4; N = 1024; K = 1024;
    W  = w == 0 ? qW : w == 1 ? kW : w == 2 ? vW : oW;
    Wt = w == 0 ? qWt : w == 1 ? kWt : w == 2 ? vWt : oWt;
  } else if (t < 4096) {
    const int r = t - 2048;
    nt = r & 63; kt = r >> 6; N = 4096; K = 1024; W = w1; Wt = w1t;
  } else {
    const int r = t - 4096;
    nt = r & 15; kt = r >> 4; N = 1024; K = 4096; W = w2; Wt = w2t;
  }
  const int wave = threadIdx.x >> 6, lane = threadIdx.x & 63;
  const int n = nt * 64 + lane;
  const int k0 = kt * 32 + wave * 8;
  union { int4 v; unsigned short u[8]; } s;
#pragma unroll
  for (int j = 0; j < 8; ++j) s.u[j] = f2bf(W[(size_t)(k0 + j) * N + n]);
  *(int4*)(Wt + (size_t)n * K + k0) = s.v;
}

// -------- 256x256 BK=32 3-buf 4-phase core (B^T) — see file header ---------
// 8 waves 2Mx4N, wave tile 128x64 (8x4 frags). Round = 128 rows x 32 cols
// (8 KB, 1 gload16/thread). Swizzle: LDS[r][chunk]=global[r][chunk^((r>>1)&3)].
__device__ __forceinline__ void gemm256_core(
    const unsigned short* __restrict__ A, const unsigned short* __restrict__ Bt,
    unsigned short* __restrict__ As, unsigned short* __restrict__ Bs,
    const int m0, const int n0, const int K, f32x4 (&acc)[8][4]) {
  const int tid = (int)threadIdx.x;
  const int w = tid >> 6, l = tid & 63;
  const int quad = l >> 4, l16 = l & 15;
  const int wm = (w >> 2) * 128, wn = (w & 3) * 64;

  // staging: round rnd covers rows rnd*128..+127; thread -> row w*16+(l>>2),
  // chunk l&3; source chunk pre-XOR'd with g(row)=(l>>3)&3; LDS linear.
  const int srow = w * 16 + (l >> 2);
  const int schunk = ((l & 3) ^ ((l >> 3) & 3)) * 8;
  const unsigned short* gA = A + (size_t)(m0 + srow) * K + schunk;
  const unsigned short* gB = Bt + (size_t)(n0 + srow) * K + schunk;
  const int dsw = w * 512;                     // wave base within a round

  const int cread = (quad ^ ((l16 >> 1) & 3)) * 8;

  auto STA = [&](int buf, int rnd, int t) {
    gload16(gA + (size_t)(rnd * 128) * K + t * 32,
            As + buf * 8192 + rnd * 4096 + dsw);
  };
  auto STB = [&](int buf, int rnd, int t) {
    gload16(gB + (size_t)(rnd * 128) * K + t * 32,
            Bs + buf * 8192 + rnd * 4096 + dsw);
  };
  auto LDA4 = [&](int buf, int mh, bf16x8 (&af)[4]) {
    const unsigned short* p = As + buf * 8192 + (wm + mh * 64 + l16) * 32 + cread;
#pragma unroll
    for (int mi = 0; mi < 4; ++mi) af[mi] = *(const bf16x8*)(p + mi * 16 * 32);
  };
  auto LDB2 = [&](int buf, int nh, bf16x8 (&bf)[2]) {
    const unsigned short* p = Bs + buf * 8192 + (wn + nh * 32 + l16) * 32 + cread;
#pragma unroll
    for (int ni = 0; ni < 2; ++ni) bf[ni] = *(const bf16x8*)(p + ni * 16 * 32);
  };
  auto MM8 = [&](int mh, int nh, bf16x8 (&af)[4], bf16x8 (&bf)[2]) {
    __builtin_amdgcn_s_setprio(1);
#pragma unroll
    for (int mi = 0; mi < 4; ++mi)
#pragma unroll
      for (int ni = 0; ni < 2; ++ni)
        acc[mh * 4 + mi][nh * 2 + ni] = __builtin_amdgcn_mfma_f32_16x16x32_bf16(
            af[mi], bf[ni], acc[mh * 4 + mi][nh * 2 + ni], 0, 0, 0);
    __builtin_amdgcn_s_setprio(0);
  };

  bf16x8 af[4], bf01[2], bf23[2];

  const int NK = K >> 5;   // >= 3
  // prologue: tiles 0 and 1 fully staged (8 loads/thread)
  STA(0, 0, 0); STA(0, 1, 0); STB(0, 0, 0); STB(0, 1, 0);
  STA(1, 0, 1); STA(1, 1, 1); STB(1, 0, 1); STB(1, 1, 1);
  asm volatile("s_waitcnt vmcnt(4)" ::: "memory");
  __builtin_amdgcn_s_barrier();

  int c = 0, cs = 2;
#pragma unroll 1
  for (int t = 0; t < NK; ++t) {
    const bool st = (t + 2 < NK);
    // ---- P1: MM (mh0, nh0)
    LDA4(c, 0, af); LDB2(c, 0, bf01);
    if (st) STA(cs, 0, t + 2);
    __builtin_amdgcn_s_barrier();
    asm volatile("s_waitcnt lgkmcnt(0)" ::: "memory");
    __builtin_amdgcn_sched_barrier(0);
    MM8(0, 0, af, bf01);
    __builtin_amdgcn_s_barrier();
    // ---- P2: MM (mh0, nh1)
    LDB2(c, 1, bf23);
    if (st) STA(cs, 1, t + 2);
    __builtin_amdgcn_s_barrier();
    asm volatile("s_waitcnt lgkmcnt(0)" ::: "memory");
    __builtin_amdgcn_sched_barrier(0);
    MM8(0, 1, af, bf23);
    __builtin_amdgcn_s_barrier();
    // ---- P3: MM (mh1, nh1)
    LDA4(c, 1, af);
    if (st) STB(cs, 0, t + 2);
    __builtin_amdgcn_s_barrier();
    asm volatile("s_waitcnt lgkmcnt(0)" ::: "memory");
    __builtin_amdgcn_sched_barrier(0);
    MM8(1, 1, af, bf23);
    __builtin_amdgcn_s_barrier();
    // ---- P4: MM (mh1, nh0) — no ds_reads (af from P3, bf01 from P1)
    if (st) STB(cs, 1, t + 2);
    __builtin_amdgcn_s_barrier();
    MM8(1, 0, af, bf01);
    if (st)              asm volatile("s_waitcnt vmcnt(4)" ::: "memory");
    else if (t + 1 < NK) asm volatile("s_waitcnt vmcnt(0)" ::: "memory");
    __builtin_amdgcn_s_barrier();
    c = c == 2 ? 0 : c + 1;
    cs = cs == 2 ? 0 : cs + 1;
  }
}

// --------------------- 256^2 GEMM (B^T) — ffn1 only ------------------------
// Grid 512 = 32mt x 16nt. Chunked XCD map: 4x2 chunks of 8x8 tiles.
template <int EPI>
__global__ __launch_bounds__(512, 1) void gemm256_bt(
    const unsigned short* __restrict__ A, const unsigned short* __restrict__ Bt,
    const float* __restrict__ bias, void* __restrict__ C, int N, int K) {
  __shared__ unsigned short As[3 * 8192];
  __shared__ unsigned short Bs[3 * 8192];
  const int xcd = (int)blockIdx.x & 7, local = (int)blockIdx.x >> 3;  // 0..63
  const int mt = (xcd >> 1) * 8 + (local >> 3);
  const int nt = (xcd & 1) * 8 + (local & 7);
  const int m0 = mt * 256, n0 = nt * 256;

  f32x4 acc[8][4] = {};
  gemm256_core(A, Bt, As, Bs, m0, n0, K, acc);

  const int tid = (int)threadIdx.x;
  const int w = tid >> 6, l = tid & 63;
  const int quad = l >> 4, l16 = l & 15;
  const int wm = (w >> 2) * 128, wn = (w & 3) * 64;

  if (EPI == 0) {
#pragma unroll
    for (int ni = 0; ni < 4; ++ni) {
      const int col = n0 + wn + ni * 16 + l16;
      const float bv = bias[col];
#pragma unroll
      for (int mi = 0; mi < 8; ++mi) {
        const int row = m0 + wm + mi * 16 + quad * 4;
#pragma unroll
        for (int r = 0; r < 4; ++r)
          ((float*)C)[(size_t)(row + r) * N + col] = acc[mi][ni][r] + bv;
      }
    }
    return;
  }

  // coalesced bf16 path (R12-verified)
  __syncthreads();
  unsigned short* sc = (w < 4) ? (As + w * 4608) : (Bs + (w - 4) * 4608);
  const int rr8 = l >> 3, c8 = (l & 7) * 8;
#pragma unroll
  for (int half = 0; half < 2; ++half) {
#pragma unroll
    for (int ni = 0; ni < 4; ++ni) {
      const int col = n0 + wn + ni * 16 + l16;
      const float bv = bias[col];
#pragma unroll
      for (int mi2 = 0; mi2 < 4; ++mi2) {
#pragma unroll
        for (int r = 0; r < 4; ++r) {
          float v = acc[half * 4 + mi2][ni][r] + bv;
          if (EPI == 2) v = v > 0.f ? v : 0.f;
          sc[(mi2 * 16 + quad * 4 + r) * 72 + ni * 16 + l16] = f2bf(v);
        }
      }
    }
    __syncthreads();
#pragma unroll
    for (int i = 0; i < 8; ++i) {
      bf16x8 vv = *(const bf16x8*)(sc + (i * 8 + rr8) * 72 + c8);
      const int row = m0 + wm + half * 64 + i * 8 + rr8;
      *(bf16x8*)((unsigned short*)C + (size_t)row * N + n0 + wn + c8) = vv;
    }
    __syncthreads();
  }
}

// -------- 128x128 depth-3 reg-double-buffered GEMM core (R11-verified) -----
__device__ __forceinline__ void gemm128_core(
    const unsigned short* __restrict__ A, const unsigned short* __restrict__ Bt,
    unsigned short* __restrict__ As, unsigned short* __restrict__ Bs,
    const int m0, const int n0, const int K, f32x4 (&acc)[4][4]) {
  const int tid = (int)threadIdx.x;
  const int w = tid >> 6, l = tid & 63;
  const int quad = l >> 4, l16 = l & 15;
  const int wm = (w >> 1) * 64, wn = (w & 1) * 64;

  const int lr = l >> 2, lc = l & 3;
  const int swz = (lc ^ ((l >> 3) & 3)) * 8;
  const unsigned short* gA[2]; const unsigned short* gB[2];
  unsigned short* dA[2]; unsigned short* dB[2];
#pragma unroll
  for (int j = 0; j < 2; ++j) {
    const int rr = (w * 2 + j) * 16 + lr;
    gA[j] = A + (size_t)(m0 + rr) * K + swz;
    gB[j] = Bt + (size_t)(n0 + rr) * K + swz;
    dA[j] = As + (w * 2 + j) * 512;
    dB[j] = Bs + (w * 2 + j) * 512;
  }

  const int cread = (quad ^ ((l16 >> 1) & 3)) * 8;
  const int rA = (wm + l16) * 32;
  const int rB = (wn + l16) * 32;

  auto STAGE = [&](int db, int t) {
#pragma unroll
    for (int j = 0; j < 2; ++j) {
      gload16(gA[j] + t * 32, dA[j] + db * 4096);
      gload16(gB[j] + t * 32, dB[j] + db * 4096);
    }
  };
  auto DSR = [&](int db, bf16x8 (&af)[4], bf16x8 (&bf)[4]) {
    const unsigned short* pa = As + db * 4096 + rA + cread;
    const unsigned short* pb = Bs + db * 4096 + rB + cread;
#pragma unroll
    for (int ni = 0; ni < 4; ++ni) bf[ni] = *(const bf16x8*)(pb + ni * 16 * 32);
#pragma unroll
    for (int mi = 0; mi < 4; ++mi) af[mi] = *(const bf16x8*)(pa + mi * 16 * 32);
  };
  auto MM = [&](bf16x8 (&af)[4], bf16x8 (&bf)[4]) {
    __builtin_amdgcn_s_setprio(1);
#pragma unroll
    for (int mi = 0; mi < 4; ++mi)
#pragma unroll
      for (int ni = 0; ni < 4; ++ni)
        acc[mi][ni] = __builtin_amdgcn_mfma_f32_16x16x32_bf16(
            af[mi], bf[ni], acc[mi][ni], 0, 0, 0);
    __builtin_amdgcn_s_setprio(0);
  };

  bf16x8 afA[4], bfA[4], afB[4], bfB[4];

  const int NK = K >> 5;   // even, >= 4
  STAGE(0, 0); STAGE(1, 1); STAGE(2, 2);
  asm volatile("s_waitcnt vmcnt(8)" ::: "memory");
  __builtin_amdgcn_s_barrier();
  DSR(0, afA, bfA);

#define STEP128(T, afC, bfC, afN, bfN)                                \
  {                                                                   \
    const int t_ = (T);                                               \
    if (t_ + 2 < NK) asm volatile("s_waitcnt vmcnt(4)" ::: "memory"); \
    else             asm volatile("s_waitcnt vmcnt(0)" ::: "memory"); \
    __builtin_amdgcn_s_barrier();                                     \
    DSR((t_ + 1) & 3, afN, bfN);                                      \
    if (t_ + 3 < NK) STAGE((t_ + 3) & 3, t_ + 3);                     \
    MM(afC, bfC);                                                     \
  }

#pragma unroll 1
  for (int t = 0; t < NK - 2; t += 2) {
    STEP128(t, afA, bfA, afB, bfB);
    STEP128(t + 1, afB, bfB, afA, bfA);
  }
  STEP128(NK - 2, afA, bfA, afB, bfB);
  MM(afB, bfB);
#undef STEP128
}

// --------------------- 128^2 GEMM (B^T) — proj, ffn2 -----------------------
// Grid 512 = 64mt x 8nt. Chunked XCD map: 8x1 chunks of 8x8 tiles.
template <int EPI>
__global__ __launch_bounds__(256, 2) void gemm128_bt(
    const unsigned short* __restrict__ A, const unsigned short* __restrict__ Bt,
    const float* __restrict__ bias, void* __restrict__ C, int N, int K) {
  __shared__ unsigned short As[4 * 4096];
  __shared__ unsigned short Bs[4 * 4096];
  const int xcd = (int)blockIdx.x & 7, local = (int)blockIdx.x >> 3;  // 0..63
  const int mt = xcd * 8 + (local >> 3);
  const int nt = local & 7;
  const int m0 = mt * 128, n0 = nt * 128;

  f32x4 acc[4][4] = {};
  gemm128_core(A, Bt, As, Bs, m0, n0, K, acc);

  const int tid = (int)threadIdx.x;
  const int w = tid >> 6, l = tid & 63;
  const int quad = l >> 4, l16 = l & 15;
  const int wm = (w >> 1) * 64, wn = (w & 1) * 64;

  if (EPI == 0) {
#pragma unroll
    for (int ni = 0; ni < 4; ++ni) {
      const int col = n0 + wn + ni * 16 + l16;
      const float bv = bias[col];
#pragma unroll
      for (int mi = 0; mi < 4; ++mi) {
        const int row = m0 + wm + mi * 16 + quad * 4;
#pragma unroll
        for (int r = 0; r < 4; ++r)
          ((float*)C)[(size_t)(row + r) * N + col] = acc[mi][ni][r] + bv;
      }
    }
    return;
  }

  __syncthreads();
  unsigned short* sc = (w < 2) ? (As + w * 4608) : (Bs + (w - 2) * 4608);
  const int rr8 = l >> 3, c8 = (l & 7) * 8;
#pragma unroll
  for (int ni = 0; ni < 4; ++ni) {
    const int col = n0 + wn + ni * 16 + l16;
    const float bv = bias[col];
#pragma unroll
    for (int mi = 0; mi < 4; ++mi) {
#pragma unroll
      for (int r = 0; r < 4; ++r) {
        float v = acc[mi][ni][r] + bv;
        if (EPI == 2) v = v > 0.f ? v : 0.f;
        sc[(mi * 16 + quad * 4 + r) * 72 + ni * 16 + l16] = f2bf(v);
      }
    }
  }
  __syncthreads();
#pragma unroll
  for (int i = 0; i < 8; ++i) {
    bf16x8 vv = *(const bf16x8*)(sc + (i * 8 + rr8) * 72 + c8);
    const int row = m0 + wm + i * 8 + rr8;
    *(bf16x8*)((unsigned short*)C + (size_t)row * N + n0 + wn + c8) = vv;
  }
}

// --------------------------- fused QKV GEMM (128^2) ------------------------
// Grid 1536 = 64mt x 24nt. Chunked XCD map: 4x2 chunks of 16x12 tiles.
#define QSCALE 0.180336884f   // 0.125 * log2(e)

__global__ __launch_bounds__(256, 2) void gemm128_qkv(
    const unsigned short* __restrict__ A, const unsigned short* __restrict__ Bt,
    const float* __restrict__ qb, const float* __restrict__ kb,
    const float* __restrict__ vb, unsigned short* __restrict__ Qo,
    unsigned short* __restrict__ Ko, unsigned short* __restrict__ Vto, int K) {
  __shared__ unsigned short As[4 * 4096];
  __shared__ unsigned short Bs[4 * 4096];
  const int xcd = (int)blockIdx.x & 7, local = (int)blockIdx.x >> 3;  // 0..191
  const int mt = (xcd >> 1) * 16 + (local & 15);
  const int nt = (xcd & 1) * 12 + (local >> 4);
  const int m0 = mt * 128, n0 = nt * 128;

  f32x4 acc[4][4] = {};
  gemm128_core(A, Bt, As, Bs, m0, n0, K, acc);

  const int tid = (int)threadIdx.x;
  const int w = tid >> 6, l = tid & 63;
  const int quad = l >> 4, l16 = l & 15;
  const int wm = (w >> 1) * 64, wn = (w & 1) * 64;

  const int seg = n0 >> 10;                    // 0=Q, 1=K, 2=V (block-uniform)
  const float* bias = seg == 0 ? qb : (seg == 1 ? kb : vb);
  const int colb = (n0 + wn) & 1023;           // wave-uniform col base

  __syncthreads();   // close K-loop LDS use
  unsigned short* sc = (w < 2) ? (As + w * 4608) : (Bs + (w - 2) * 4608);
  const int rr8 = l >> 3, c8 = (l & 7) * 8;

  if (seg == 2) {
    // V: scratch transposed [dh][s]; readout runs along s (contiguous in Vto)
    const int b = m0 >> 11;                    // tile never crosses b (128|2048)
    const int hh = colb >> 6;
    const int s0 = (m0 & 2047) + wm;
#pragma unroll
    for (int ni = 0; ni < 4; ++ni) {
      const float bv = bias[colb + ni * 16 + l16];
#pragma unroll
      for (int mi = 0; mi < 4; ++mi) {
        union { ushort4 v; unsigned short u[4]; } pk;
#pragma unroll
        for (int r = 0; r < 4; ++r) pk.u[r] = f2bf(acc[mi][ni][r] + bv);
        *(ushort4*)(sc + (ni * 16 + l16) * 72 + mi * 16 + quad * 4) = pk.v;
      }
    }
    __syncthreads();
    unsigned short* vbase = Vto + ((size_t)(b * 16 + hh) * 64) * 2048;
#pragma unroll
    for (int i = 0; i < 8; ++i) {
      bf16x8 vv = *(const bf16x8*)(sc + (i * 8 + rr8) * 72 + c8);
      const int dh = i * 8 + rr8;
      *(bf16x8*)(vbase + (size_t)dh * 2048 + s0 + c8) = vv;
    }
  } else {
    // Q/K: row-major scratch, coalesced 128-B row stores
    unsigned short* Out = seg == 0 ? Qo : Ko;
#pragma unroll
    for (int ni = 0; ni < 4; ++ni) {
      const float bv = bias[colb + ni * 16 + l16];
#pragma unroll
      for (int mi = 0; mi < 4; ++mi) {
#pragma unroll
        for (int r = 0; r < 4; ++r) {
          float v = acc[mi][ni][r] + bv;
          if (seg == 0) v *= QSCALE;
          sc[(mi * 16 + quad * 4 + r) * 72 + ni * 16 + l16] = f2bf(v);
        }
      }
    }
    __syncthreads();
#pragma unroll
    for (int i = 0; i < 8; ++i) {
      bf16x8 vv = *(const bf16x8*)(sc + (i * 8 + rr8) * 72 + c8);
      const int row = m0 + wm + i * 8 + rr8;
      *(bf16x8*)(Out + (size_t)row * 1024 + colb + c8) = vv;
    }
  }
}

// --------------------------- flash attention -------------------------------
__global__ __launch_bounds__(256, 4) void attn_fused(
    const unsigned short* __restrict__ Q, const unsigned short* __restrict__ K,
    const unsigned short* __restrict__ Vt, const int* __restrict__ lengths,
    unsigned short* __restrict__ ctx) {
  constexpr int S = 2048, D = 1024;
  __shared__ unsigned short Ks[64 * 72];
  __shared__ unsigned short Vs[64 * 72];
  __shared__ unsigned short Ps[4 * 32 * 72];

  const int tid = threadIdx.x;
  const int wave = tid >> 6, lane = tid & 63;
  const int quad = lane >> 4, l16 = lane & 15;
  const int bid = blockIdx.x;
  const int qt = bid & 15;
  const int h = (bid >> 4) & 15;
  const int b = bid >> 8;
  const int q0 = qt * 128;
  const int len = lengths[b];
  const int ktEnd = (len + 63) >> 6;
  const float NEGINF = -__builtin_inff();

  const size_t xbase = (size_t)b * S * D + (size_t)h * 64;
  const size_t vtb = (size_t)(b * 16 + h) * 64;

  bf16x8 qf0[2], qf1[2];
#pragma unroll
  for (int mb = 0; mb < 2; ++mb) {
    const unsigned short* qrow =
        Q + xbase + (size_t)(q0 + wave * 32 + mb * 16 + l16) * D;
    qf0[mb] = *(const bf16x8*)(qrow + quad * 8);
    qf1[mb] = *(const bf16x8*)(qrow + 32 + quad * 8);
  }

  const int sr1 = tid >> 3, sc1 = (tid & 7) * 8;
  const int sr2 = (256 + tid) >> 3, sc2 = (tid & 7) * 8;
  const unsigned short* kg1 = K + xbase + (size_t)sr1 * D + sc1;
  const unsigned short* kg2 = K + xbase + (size_t)sr2 * D + sc2;
  const unsigned short* vg1 = Vt + (vtb + sr1) * S + sc1;
  const unsigned short* vg2 = Vt + (vtb + sr2) * S + sc2;

  f32x4 oacc[2][4] = {};
  float rs[2][4] = {};

  unsigned short* pw = Ps + wave * (32 * 72);

  int4 kr1, kr2, vr1, vr2;
  {
    kr1 = *(const int4*)(kg1);
    kr2 = *(const int4*)(kg2);
    vr1 = *(const int4*)(vg1);
    vr2 = *(const int4*)(vg2);
  }

  for (int kt = 0; kt < ktEnd; ++kt) {
    const int k0 = kt * 64;
    __syncthreads();
    *(int4*)(Ks + sr1 * 72 + sc1) = kr1;
    *(int4*)(Ks + sr2 * 72 + sc2) = kr2;
    *(int4*)(Vs + sr1 * 72 + sc1) = vr1;
    *(int4*)(Vs + sr2 * 72 + sc2) = vr2;
    __syncthreads();

    if (kt + 1 < ktEnd) {            // async prefetch of next tile
      const int kn = (kt + 1) * 64;
      kr1 = *(const int4*)(kg1 + (size_t)kn * D);
      kr2 = *(const int4*)(kg2 + (size_t)kn * D);
      vr1 = *(const int4*)(vg1 + kn);
      vr2 = *(const int4*)(vg2 + kn);
    }

    f32x4 sf[2][4];
#pragma unroll
    for (int cb = 0; cb < 4; ++cb) {
      const bf16x8 kf0 = *(const bf16x8*)(Ks + (cb * 16 + l16) * 72 + quad * 8);
      const bf16x8 kf1 = *(const bf16x8*)(Ks + (cb * 16 + l16) * 72 + 32 + quad * 8);
#pragma unroll
      for (int mb = 0; mb < 2; ++mb) {
        f32x4 c = {0.f, 0.f, 0.f, 0.f};
        c = __builtin_amdgcn_mfma_f32_16x16x32_bf16(qf0[mb], kf0, c, 0, 0, 0);
        c = __builtin_amdgcn_mfma_f32_16x16x32_bf16(qf1[mb], kf1, c, 0, 0, 0);
        sf[mb][cb] = c;
      }
    }

    if (k0 + 64 > len) {
#pragma unroll
      for (int cb = 0; cb < 4; ++cb) {
        const bool msk = (k0 + cb * 16 + l16) >= len;
#pragma unroll
        for (int mb = 0; mb < 2; ++mb)
#pragma unroll
          for (int r = 0; r < 4; ++r) sf[mb][cb][r] = msk ? NEGINF : sf[mb][cb][r];
      }
    }

#pragma unroll
    for (int mb = 0; mb < 2; ++mb)
#pragma unroll
      for (int cb = 0; cb < 4; ++cb)
#pragma unroll
        for (int r = 0; r < 4; ++r) {
          const float p = __builtin_amdgcn_exp2f(sf[mb][cb][r]);
          sf[mb][cb][r] = p;
          rs[mb][r] += p;
        }

#pragma unroll
    for (int mb = 0; mb < 2; ++mb)
#pragma unroll
      for (int cb = 0; cb < 4; ++cb)
#pragma unroll
        for (int r = 0; r < 4; ++r)
          pw[(mb * 16 + quad * 4 + r) * 72 + cb * 16 + l16] = f2bf(sf[mb][cb][r]);

    bf16x8 pa0[2], pa1[2];
#pragma unroll
    for (int mb = 0; mb < 2; ++mb) {
      pa0[mb] = *(const bf16x8*)(pw + (mb * 16 + l16) * 72 + quad * 8);
      pa1[mb] = *(const bf16x8*)(pw + (mb * 16 + l16) * 72 + 32 + quad * 8);
    }
#pragma unroll
    for (int cb = 0; cb < 4; ++cb) {
      const bf16x8 vb0 = *(const bf16x8*)(Vs + (cb * 16 + l16) * 72 + quad * 8);
      const bf16x8 vb1 = *(const bf16x8*)(Vs + (cb * 16 + l16) * 72 + 32 + quad * 8);
#pragma unroll
      for (int mb = 0; mb < 2; ++mb) {
        oacc[mb][cb] = __builtin_amdgcn_mfma_f32_16x16x32_bf16(pa0[mb], vb0, oacc[mb][cb], 0, 0, 0);
        oacc[mb][cb] = __builtin_amdgcn_mfma_f32_16x16x32_bf16(pa1[mb], vb1, oacc[mb][cb], 0, 0, 0);
      }
    }
  }

#pragma unroll
  for (int off = 8; off > 0; off >>= 1)
#pragma unroll
    for (int mb = 0; mb < 2; ++mb)
#pragma unroll
      for (int r = 0; r < 4; ++r) rs[mb][r] += __shfl_xor(rs[mb][r], off, 16);

#pragma unroll
  for (int mb = 0; mb < 2; ++mb) {
    float inv[4];
#pragma unroll
    for (int r = 0; r < 4; ++r) inv[r] = 1.0f / rs[mb][r];
#pragma unroll
    for (int cb = 0; cb < 4; ++cb)
#pragma unroll
      for (int r = 0; r < 4; ++r) {
        const int row = q0 + wave * 32 + mb * 16 + quad * 4 + r;
        ctx[xbase + (size_t)row * D + cb * 16 + l16] = f2bf(oacc[mb][cb][r] * inv[r]);
      }
  }
}

// ------------------------------ launcher -----------------------------------
extern "C" void kernel_launch(void* const* d_in, const int* in_sizes, int n_in,
                              void* d_out, int out_size, void* d_ws,
                              size_t ws_size, hipStream_t stream) {
  const float* x  = (const float*)d_in[0];
  const int* lengths = (const int*)d_in[1];
  const float* qW = (const float*)d_in[2];
  const float* qb = (const float*)d_in[3];
  const float* kW = (const float*)d_in[4];
  const float* kb = (const float*)d_in[5];
  const float* vW = (const float*)d_in[6];
  const float* vb = (const float*)d_in[7];
  const float* oW = (const float*)d_in[8];
  const float* ob = (const float*)d_in[9];
  const float* w1 = (const float*)d_in[10];
  const float* b1 = (const float*)d_in[11];
  const float* w2 = (const float*)d_in[12];
  const float* b2 = (const float*)d_in[13];
  float* out = (float*)d_out;

  const int Bx = 4, S = 2048, D = 1024, FF = 4096;
  const int M = Bx * S;  // 8192

  unsigned short* p = (unsigned short*)d_ws;
  unsigned short* xb  = p; p += (size_t)M * D;
  unsigned short* qWt = p; p += (size_t)D * D;   // contiguous [3072,1024]
  unsigned short* kWt = p; p += (size_t)D * D;
  unsigned short* vWt = p; p += (size_t)D * D;
  unsigned short* oWt = p; p += (size_t)D * D;
  unsigned short* w1t = p; p += (size_t)D * FF;   // [FF, D]
  unsigned short* w2t = p; p += (size_t)FF * D;   // [D, FF]
  unsigned short* Qb  = p; p += (size_t)M * D;
  unsigned short* Kb  = p; p += (size_t)M * D;
  unsigned short* Vtb = p; p += (size_t)M * D;    // [B,H,64,S]
  unsigned short* Cb  = p; p += (size_t)M * D;
  unsigned short* Ab  = p; p += (size_t)M * D;
  unsigned short* Hb  = p; p += (size_t)M * FF;

  {
    int n4 = (int)((size_t)M * D / 4);
    cast_f32_bf16<<<dim3((n4 + 255) / 256), dim3(256), 0, stream>>>(x, xb, n4);
  }
  prep_weights<<<dim3(6144), dim3(256), 0, stream>>>(
      qW, kW, vW, oW, w1, w2, qWt, kWt, vWt, oWt, w1t, w2t);

  // qkv: 128^2 reg-dbuf core, 24 x 64 = 1536 blocks
  gemm128_qkv<<<dim3(1536), dim3(256), 0, stream>>>(
      xb, qWt, qb, kb, vb, Qb, Kb, Vtb, D);

  attn_fused<<<dim3(Bx * 16 * (S / 128)), dim3(256), 0, stream>>>(
      Qb, Kb, Vtb, lengths, Cb);

  // proj: 128^2 reg-dbuf core, 8 x 64 = 512 blocks
  gemm128_bt<1><<<dim3(512), dim3(256), 0, stream>>>(Cb, oWt, ob, Ab, D, D);
  // ffn1: 256^2 BK=32 3-buf core, 32 x 16 = 512 blocks
  gemm256_bt<2><<<dim3(512), dim3(512), 0, stream>>>(Ab, w1t, b1, Hb, FF, D);
  // ffn2: 128^2 reg-dbuf core, 8 x 64 = 512 blocks (K=4096: 128 K-steps)
  gemm128_bt<0><<<dim3(512), dim3(256), 0, stream>>>(Hb, w2t, b2, out, D, FF);
}

// Round 9
// 433.829 us; speedup vs baseline: 1.2193x; 1.0143x over previous
//
#include <hip/hip_runtime.h>

// ---------------------------------------------------------------------------
// TransformerEncoder: B=4, S=2048, D=1024, H=16, HD=64, FF=4096
// Round 14: recombine measured wins + attn setprio.
//   - ffn1: R9-verified 8-phase BK=64 core RESTORED (R13's BK=32 4-phase was
//     a measured -10 regression), keeping R13's chunked XCD map (FETCH
//     74->49MB) and R12's coalesced epilogue.
//   - attention: T5 s_setprio(1/0) around QK^T and PV MFMA clusters (m191:
//     +4-7% on attn-like independent-block kernels; first direct attn change).
//   - qkv/proj/ffn2 (reg-dbuf 128^2 + chunked XCD + coalesced epi), cast,
//     prep unchanged.
// ---------------------------------------------------------------------------

typedef short bf16x8 __attribute__((ext_vector_type(8)));
typedef float f32x4 __attribute__((ext_vector_type(4)));

__device__ __forceinline__ unsigned short f2bf(float f) {
  unsigned int u = __builtin_bit_cast(unsigned int, f);
  u += 0x7fffu + ((u >> 16) & 1u);   // round-to-nearest-even
  return (unsigned short)(u >> 16);
}

__device__ __forceinline__ void gload16(const unsigned short* g, unsigned short* l) {
  __builtin_amdgcn_global_load_lds(
      (const __attribute__((address_space(1))) unsigned int*)(g),
      (__attribute__((address_space(3))) unsigned int*)(l),
      16, 0, 0);
}

// --------------------------- cast fp32 -> bf16 -----------------------------
__global__ __launch_bounds__(256) void cast_f32_bf16(
    const float* __restrict__ src, unsigned short* __restrict__ dst, int n4) {
  int i = blockIdx.x * 256 + threadIdx.x;
  if (i < n4) {
    float4 f = ((const float4*)src)[i];
    ushort4 o;
    o.x = f2bf(f.x); o.y = f2bf(f.y); o.z = f2bf(f.z); o.w = f2bf(f.w);
    ((ushort4*)dst)[i] = o;
  }
}

// ---------------- merged weight prep: 6 transposes in one kernel -----------
__global__ __launch_bounds__(256) void prep_weights(
    const float* __restrict__ qW, const float* __restrict__ kW,
    const float* __restrict__ vW, const float* __restrict__ oW,
    const float* __restrict__ w1, const float* __restrict__ w2,
    unsigned short* __restrict__ qWt, unsigned short* __restrict__ kWt,
    unsigned short* __restrict__ vWt, unsigned short* __restrict__ oWt,
    unsigned short* __restrict__ w1t, unsigned short* __restrict__ w2t) {
  const int t = blockIdx.x;
  const float* W; unsigned short* Wt; int N, K, nt, kt;
  if (t < 2048) {
    const int w = t >> 9, r = t & 511;
    nt = r & 15; kt = r >> 4; N = 1024; K = 1024;
    W  = w == 0 ? qW : w == 1 ? kW : w == 2 ? vW : oW;
    Wt = w == 0 ? qWt : w == 1 ? kWt : w == 2 ? vWt : oWt;
  } else if (t < 4096) {
    const int r = t - 2048;
    nt = r & 63; kt = r >> 6; N = 4096; K = 1024; W = w1; Wt = w1t;
  } else {
    const int r = t - 4096;
    nt = r & 15; kt = r >> 4; N = 1024; K = 4096; W = w2; Wt = w2t;
  }
  const int wave = threadIdx.x >> 6, lane = threadIdx.x & 63;
  const int n = nt * 64 + lane;
  const int k0 = kt * 32 + wave * 8;
  union { int4 v; unsigned short u[8]; } s;
#pragma unroll
  for (int j = 0; j < 8; ++j) s.u[j] = f2bf(W[(size_t)(k0 + j) * N + n]);
  *(int4*)(Wt + (size_t)n * K + k0) = s.v;
}

// ---------------- 256x256 8-phase counted-vmcnt core (B^T) -----------------
// 8 waves 2Mx4N, wave tile 128x64 (8x4 frags), BK=64 (2 kk). R9-verified.
__device__ __forceinline__ void gemm256_8ph(
    const unsigned short* __restrict__ A, const unsigned short* __restrict__ Bt,
    unsigned short* __restrict__ As, unsigned short* __restrict__ Bs,
    const int m0, const int n0, const int K, f32x4 (&acc)[8][4]) {
  const int tid = (int)threadIdx.x;
  const int w = tid >> 6, l = tid & 63;
  const int quad = l >> 4, l16 = l & 15;
  const int wm = (w >> 2) * 128, wn = (w & 3) * 64;

  const int srow = w * 8 + (l >> 3);
  const int schunk = ((l & 7) ^ (l >> 3)) * 8;
  const unsigned short* gA = A + (size_t)(m0 + srow) * K + schunk;
  const unsigned short* gB = Bt + (size_t)(n0 + srow) * K + schunk;
  const int ldsW = w * 512;

  const int xr = l16 & 7;
  const int c0 = ((0 + quad) ^ xr) * 8;
  const int c1 = ((4 + quad) ^ xr) * 8;

  bf16x8 af[4][2], bf0[2][2], bf1[2][2];

  auto STA = [&](int buf, int a, int t) {
    gload16(gA + (size_t)(a * 64) * K + t * 64,
            As + buf * 16384 + a * 4096 + ldsW);
  };
  auto STB = [&](int buf, int a, int t) {
    gload16(gB + (size_t)(a * 64) * K + t * 64,
            Bs + buf * 16384 + a * 4096 + ldsW);
  };
  auto LDA = [&](int buf, int mh) {
    const unsigned short* p = As + buf * 16384 + (wm + mh * 64 + l16) * 64;
#pragma unroll
    for (int mi = 0; mi < 4; ++mi) {
      af[mi][0] = *(const bf16x8*)(p + mi * 16 * 64 + c0);
      af[mi][1] = *(const bf16x8*)(p + mi * 16 * 64 + c1);
    }
  };
  auto LDB = [&](int buf, int nh, bf16x8 (&bf)[2][2]) {
    const unsigned short* p = Bs + buf * 16384 + (wn + nh * 32 + l16) * 64;
#pragma unroll
    for (int ni = 0; ni < 2; ++ni) {
      bf[ni][0] = *(const bf16x8*)(p + ni * 16 * 64 + c0);
      bf[ni][1] = *(const bf16x8*)(p + ni * 16 * 64 + c1);
    }
  };
  auto MM = [&](int mh, int nh, bf16x8 (&bf)[2][2]) {
    __builtin_amdgcn_s_setprio(1);
#pragma unroll
    for (int mi = 0; mi < 4; ++mi)
#pragma unroll
      for (int ni = 0; ni < 2; ++ni) {
        f32x4& a = acc[mh * 4 + mi][nh * 2 + ni];
        a = __builtin_amdgcn_mfma_f32_16x16x32_bf16(af[mi][0], bf[ni][0], a, 0, 0, 0);
        a = __builtin_amdgcn_mfma_f32_16x16x32_bf16(af[mi][1], bf[ni][1], a, 0, 0, 0);
      }
    __builtin_amdgcn_s_setprio(0);
  };

  const int NK = K >> 6;   // >= 2
  STB(0, 0, 0); STB(0, 1, 0); STB(0, 2, 0); STB(0, 3, 0);
  STA(0, 0, 0); STA(0, 2, 0); STA(0, 1, 0); STA(0, 3, 0);
  asm volatile("s_waitcnt vmcnt(2)" ::: "memory");
  __builtin_amdgcn_s_barrier();

#pragma unroll 1
  for (int t = 0; t < NK; ++t) {
    const int c = t & 1, nb = c ^ 1;
    const bool st = (t + 1 < NK);
    // ---- P1 (mh0, nh0)
    LDA(c, 0); LDB(c, 0, bf0);
    if (st) { STB(nb, 0, t + 1); STB(nb, 1, t + 1); }
    __builtin_amdgcn_s_barrier();
    asm volatile("s_waitcnt lgkmcnt(0)" ::: "memory");
    __builtin_amdgcn_sched_barrier(0);
    MM(0, 0, bf0);
    __builtin_amdgcn_s_barrier();
    // ---- P2 (mh0, nh1)
    LDB(c, 1, bf1);
    if (st) { STB(nb, 2, t + 1); STB(nb, 3, t + 1); }
    __builtin_amdgcn_s_barrier();
    asm volatile("s_waitcnt lgkmcnt(0)" ::: "memory");
    __builtin_amdgcn_sched_barrier(0);
    MM(0, 1, bf1);
    if (st) asm volatile("s_waitcnt vmcnt(4)" ::: "memory");
    else    asm volatile("s_waitcnt vmcnt(0)" ::: "memory");
    __builtin_amdgcn_s_barrier();
    // ---- P3 (mh1, nh1)
    LDA(c, 1);
    if (st) { STA(nb, 0, t + 1); STA(nb, 2, t + 1); }
    __builtin_amdgcn_s_barrier();
    asm volatile("s_waitcnt lgkmcnt(0)" ::: "memory");
    __builtin_amdgcn_sched_barrier(0);
    MM(1, 1, bf1);
    __builtin_amdgcn_s_barrier();
    // ---- P4 (mh1, nh0)
    if (st) { STA(nb, 1, t + 1); STA(nb, 3, t + 1); }
    __builtin_amdgcn_s_barrier();
    MM(1, 0, bf0);
    if (st) asm volatile("s_waitcnt vmcnt(2)" ::: "memory");
    __builtin_amdgcn_s_barrier();
  }
}

// --------------------- 256^2 GEMM (B^T) — ffn1 only ------------------------
// Grid 512 = 32mt x 16nt. Chunked XCD map (R13): 4x2 chunks of 8x8 tiles.
template <int EPI>
__global__ __launch_bounds__(512, 1) void gemm256_bt(
    const unsigned short* __restrict__ A, const unsigned short* __restrict__ Bt,
    const float* __restrict__ bias, void* __restrict__ C, int N, int K) {
  __shared__ unsigned short As[2 * 16384];
  __shared__ unsigned short Bs[2 * 16384];
  const int xcd = (int)blockIdx.x & 7, local = (int)blockIdx.x >> 3;  // 0..63
  const int mt = (xcd >> 1) * 8 + (local >> 3);
  const int nt = (xcd & 1) * 8 + (local & 7);
  const int m0 = mt * 256, n0 = nt * 256;

  f32x4 acc[8][4] = {};
  gemm256_8ph(A, Bt, As, Bs, m0, n0, K, acc);

  const int tid = (int)threadIdx.x;
  const int w = tid >> 6, l = tid & 63;
  const int quad = l >> 4, l16 = l & 15;
  const int wm = (w >> 2) * 128, wn = (w & 3) * 64;

  if (EPI == 0) {
#pragma unroll
    for (int ni = 0; ni < 4; ++ni) {
      const int col = n0 + wn + ni * 16 + l16;
      const float bv = bias[col];
#pragma unroll
      for (int mi = 0; mi < 8; ++mi) {
        const int row = m0 + wm + mi * 16 + quad * 4;
#pragma unroll
        for (int r = 0; r < 4; ++r)
          ((float*)C)[(size_t)(row + r) * N + col] = acc[mi][ni][r] + bv;
      }
    }
    return;
  }

  // coalesced bf16 path (R12-verified)
  __syncthreads();
  unsigned short* sc = (w < 4) ? (As + w * 4608) : (Bs + (w - 4) * 4608);
  const int rr8 = l >> 3, c8 = (l & 7) * 8;
#pragma unroll
  for (int half = 0; half < 2; ++half) {
#pragma unroll
    for (int ni = 0; ni < 4; ++ni) {
      const int col = n0 + wn + ni * 16 + l16;
      const float bv = bias[col];
#pragma unroll
      for (int mi2 = 0; mi2 < 4; ++mi2) {
#pragma unroll
        for (int r = 0; r < 4; ++r) {
          float v = acc[half * 4 + mi2][ni][r] + bv;
          if (EPI == 2) v = v > 0.f ? v : 0.f;
          sc[(mi2 * 16 + quad * 4 + r) * 72 + ni * 16 + l16] = f2bf(v);
        }
      }
    }
    __syncthreads();
#pragma unroll
    for (int i = 0; i < 8; ++i) {
      bf16x8 vv = *(const bf16x8*)(sc + (i * 8 + rr8) * 72 + c8);
      const int row = m0 + wm + half * 64 + i * 8 + rr8;
      *(bf16x8*)((unsigned short*)C + (size_t)row * N + n0 + wn + c8) = vv;
    }
    __syncthreads();
  }
}

// -------- 128x128 depth-3 reg-double-buffered GEMM core (R11-verified) -----
__device__ __forceinline__ void gemm128_core(
    const unsigned short* __restrict__ A, const unsigned short* __restrict__ Bt,
    unsigned short* __restrict__ As, unsigned short* __restrict__ Bs,
    const int m0, const int n0, const int K, f32x4 (&acc)[4][4]) {
  const int tid = (int)threadIdx.x;
  const int w = tid >> 6, l = tid & 63;
  const int quad = l >> 4, l16 = l & 15;
  const int wm = (w >> 1) * 64, wn = (w & 1) * 64;

  const int lr = l >> 2, lc = l & 3;
  const int swz = (lc ^ ((l >> 3) & 3)) * 8;
  const unsigned short* gA[2]; const unsigned short* gB[2];
  unsigned short* dA[2]; unsigned short* dB[2];
#pragma unroll
  for (int j = 0; j < 2; ++j) {
    const int rr = (w * 2 + j) * 16 + lr;
    gA[j] = A + (size_t)(m0 + rr) * K + swz;
    gB[j] = Bt + (size_t)(n0 + rr) * K + swz;
    dA[j] = As + (w * 2 + j) * 512;
    dB[j] = Bs + (w * 2 + j) * 512;
  }

  const int cread = (quad ^ ((l16 >> 1) & 3)) * 8;
  const int rA = (wm + l16) * 32;
  const int rB = (wn + l16) * 32;

  auto STAGE = [&](int db, int t) {
#pragma unroll
    for (int j = 0; j < 2; ++j) {
      gload16(gA[j] + t * 32, dA[j] + db * 4096);
      gload16(gB[j] + t * 32, dB[j] + db * 4096);
    }
  };
  auto DSR = [&](int db, bf16x8 (&af)[4], bf16x8 (&bf)[4]) {
    const unsigned short* pa = As + db * 4096 + rA + cread;
    const unsigned short* pb = Bs + db * 4096 + rB + cread;
#pragma unroll
    for (int ni = 0; ni < 4; ++ni) bf[ni] = *(const bf16x8*)(pb + ni * 16 * 32);
#pragma unroll
    for (int mi = 0; mi < 4; ++mi) af[mi] = *(const bf16x8*)(pa + mi * 16 * 32);
  };
  auto MM = [&](bf16x8 (&af)[4], bf16x8 (&bf)[4]) {
    __builtin_amdgcn_s_setprio(1);
#pragma unroll
    for (int mi = 0; mi < 4; ++mi)
#pragma unroll
      for (int ni = 0; ni < 4; ++ni)
        acc[mi][ni] = __builtin_amdgcn_mfma_f32_16x16x32_bf16(
            af[mi], bf[ni], acc[mi][ni], 0, 0, 0);
    __builtin_amdgcn_s_setprio(0);
  };

  bf16x8 afA[4], bfA[4], afB[4], bfB[4];

  const int NK = K >> 5;   // even, >= 4
  STAGE(0, 0); STAGE(1, 1); STAGE(2, 2);
  asm volatile("s_waitcnt vmcnt(8)" ::: "memory");
  __builtin_amdgcn_s_barrier();
  DSR(0, afA, bfA);

#define STEP128(T, afC, bfC, afN, bfN)                                \
  {                                                                   \
    const int t_ = (T);                                               \
    if (t_ + 2 < NK) asm volatile("s_waitcnt vmcnt(4)" ::: "memory"); \
    else             asm volatile("s_waitcnt vmcnt(0)" ::: "memory"); \
    __builtin_amdgcn_s_barrier();                                     \
    DSR((t_ + 1) & 3, afN, bfN);                                      \
    if (t_ + 3 < NK) STAGE((t_ + 3) & 3, t_ + 3);                     \
    MM(afC, bfC);                                                     \
  }

#pragma unroll 1
  for (int t = 0; t < NK - 2; t += 2) {
    STEP128(t, afA, bfA, afB, bfB);
    STEP128(t + 1, afB, bfB, afA, bfA);
  }
  STEP128(NK - 2, afA, bfA, afB, bfB);
  MM(afB, bfB);
#undef STEP128
}

// --------------------- 128^2 GEMM (B^T) — proj, ffn2 -----------------------
// Grid 512 = 64mt x 8nt. Chunked XCD map: 8x1 chunks of 8x8 tiles.
template <int EPI>
__global__ __launch_bounds__(256, 2) void gemm128_bt(
    const unsigned short* __restrict__ A, const unsigned short* __restrict__ Bt,
    const float* __restrict__ bias, void* __restrict__ C, int N, int K) {
  __shared__ unsigned short As[4 * 4096];
  __shared__ unsigned short Bs[4 * 4096];
  const int xcd = (int)blockIdx.x & 7, local = (int)blockIdx.x >> 3;  // 0..63
  const int mt = xcd * 8 + (local >> 3);
  const int nt = local & 7;
  const int m0 = mt * 128, n0 = nt * 128;

  f32x4 acc[4][4] = {};
  gemm128_core(A, Bt, As, Bs, m0, n0, K, acc);

  const int tid = (int)threadIdx.x;
  const int w = tid >> 6, l = tid & 63;
  const int quad = l >> 4, l16 = l & 15;
  const int wm = (w >> 1) * 64, wn = (w & 1) * 64;

  if (EPI == 0) {
#pragma unroll
    for (int ni = 0; ni < 4; ++ni) {
      const int col = n0 + wn + ni * 16 + l16;
      const float bv = bias[col];
#pragma unroll
      for (int mi = 0; mi < 4; ++mi) {
        const int row = m0 + wm + mi * 16 + quad * 4;
#pragma unroll
        for (int r = 0; r < 4; ++r)
          ((float*)C)[(size_t)(row + r) * N + col] = acc[mi][ni][r] + bv;
      }
    }
    return;
  }

  __syncthreads();
  unsigned short* sc = (w < 2) ? (As + w * 4608) : (Bs + (w - 2) * 4608);
  const int rr8 = l >> 3, c8 = (l & 7) * 8;
#pragma unroll
  for (int ni = 0; ni < 4; ++ni) {
    const int col = n0 + wn + ni * 16 + l16;
    const float bv = bias[col];
#pragma unroll
    for (int mi = 0; mi < 4; ++mi) {
#pragma unroll
      for (int r = 0; r < 4; ++r) {
        float v = acc[mi][ni][r] + bv;
        if (EPI == 2) v = v > 0.f ? v : 0.f;
        sc[(mi * 16 + quad * 4 + r) * 72 + ni * 16 + l16] = f2bf(v);
      }
    }
  }
  __syncthreads();
#pragma unroll
  for (int i = 0; i < 8; ++i) {
    bf16x8 vv = *(const bf16x8*)(sc + (i * 8 + rr8) * 72 + c8);
    const int row = m0 + wm + i * 8 + rr8;
    *(bf16x8*)((unsigned short*)C + (size_t)row * N + n0 + wn + c8) = vv;
  }
}

// --------------------------- fused QKV GEMM (128^2) ------------------------
// Grid 1536 = 64mt x 24nt. Chunked XCD map: 4x2 chunks of 16x12 tiles.
#define QSCALE 0.180336884f   // 0.125 * log2(e)

__global__ __launch_bounds__(256, 2) void gemm128_qkv(
    const unsigned short* __restrict__ A, const unsigned short* __restrict__ Bt,
    const float* __restrict__ qb, const float* __restrict__ kb,
    const float* __restrict__ vb, unsigned short* __restrict__ Qo,
    unsigned short* __restrict__ Ko, unsigned short* __restrict__ Vto, int K) {
  __shared__ unsigned short As[4 * 4096];
  __shared__ unsigned short Bs[4 * 4096];
  const int xcd = (int)blockIdx.x & 7, local = (int)blockIdx.x >> 3;  // 0..191
  const int mt = (xcd >> 1) * 16 + (local & 15);
  const int nt = (xcd & 1) * 12 + (local >> 4);
  const int m0 = mt * 128, n0 = nt * 128;

  f32x4 acc[4][4] = {};
  gemm128_core(A, Bt, As, Bs, m0, n0, K, acc);

  const int tid = (int)threadIdx.x;
  const int w = tid >> 6, l = tid & 63;
  const int quad = l >> 4, l16 = l & 15;
  const int wm = (w >> 1) * 64, wn = (w & 1) * 64;

  const int seg = n0 >> 10;                    // 0=Q, 1=K, 2=V (block-uniform)
  const float* bias = seg == 0 ? qb : (seg == 1 ? kb : vb);
  const int colb = (n0 + wn) & 1023;           // wave-uniform col base

  __syncthreads();   // close K-loop LDS use
  unsigned short* sc = (w < 2) ? (As + w * 4608) : (Bs + (w - 2) * 4608);
  const int rr8 = l >> 3, c8 = (l & 7) * 8;

  if (seg == 2) {
    // V: scratch transposed [dh][s]; readout runs along s (contiguous in Vto)
    const int b = m0 >> 11;                    // tile never crosses b (128|2048)
    const int hh = colb >> 6;
    const int s0 = (m0 & 2047) + wm;
#pragma unroll
    for (int ni = 0; ni < 4; ++ni) {
      const float bv = bias[colb + ni * 16 + l16];
#pragma unroll
      for (int mi = 0; mi < 4; ++mi) {
        union { ushort4 v; unsigned short u[4]; } pk;
#pragma unroll
        for (int r = 0; r < 4; ++r) pk.u[r] = f2bf(acc[mi][ni][r] + bv);
        *(ushort4*)(sc + (ni * 16 + l16) * 72 + mi * 16 + quad * 4) = pk.v;
      }
    }
    __syncthreads();
    unsigned short* vbase = Vto + ((size_t)(b * 16 + hh) * 64) * 2048;
#pragma unroll
    for (int i = 0; i < 8; ++i) {
      bf16x8 vv = *(const bf16x8*)(sc + (i * 8 + rr8) * 72 + c8);
      const int dh = i * 8 + rr8;
      *(bf16x8*)(vbase + (size_t)dh * 2048 + s0 + c8) = vv;
    }
  } else {
    // Q/K: row-major scratch, coalesced 128-B row stores
    unsigned short* Out = seg == 0 ? Qo : Ko;
#pragma unroll
    for (int ni = 0; ni < 4; ++ni) {
      const float bv = bias[colb + ni * 16 + l16];
#pragma unroll
      for (int mi = 0; mi < 4; ++mi) {
#pragma unroll
        for (int r = 0; r < 4; ++r) {
          float v = acc[mi][ni][r] + bv;
          if (seg == 0) v *= QSCALE;
          sc[(mi * 16 + quad * 4 + r) * 72 + ni * 16 + l16] = f2bf(v);
        }
      }
    }
    __syncthreads();
#pragma unroll
    for (int i = 0; i < 8; ++i) {
      bf16x8 vv = *(const bf16x8*)(sc + (i * 8 + rr8) * 72 + c8);
      const int row = m0 + wm + i * 8 + rr8;
      *(bf16x8*)(Out + (size_t)row * 1024 + colb + c8) = vv;
    }
  }
}

// --------------------------- flash attention -------------------------------
__global__ __launch_bounds__(256, 4) void attn_fused(
    const unsigned short* __restrict__ Q, const unsigned short* __restrict__ K,
    const unsigned short* __restrict__ Vt, const int* __restrict__ lengths,
    unsigned short* __restrict__ ctx) {
  constexpr int S = 2048, D = 1024;
  __shared__ unsigned short Ks[64 * 72];
  __shared__ unsigned short Vs[64 * 72];
  __shared__ unsigned short Ps[4 * 32 * 72];

  const int tid = threadIdx.x;
  const int wave = tid >> 6, lane = tid & 63;
  const int quad = lane >> 4, l16 = lane & 15;
  const int bid = blockIdx.x;
  const int qt = bid & 15;
  const int h = (bid >> 4) & 15;
  const int b = bid >> 8;
  const int q0 = qt * 128;
  const int len = lengths[b];
  const int ktEnd = (len + 63) >> 6;
  const float NEGINF = -__builtin_inff();

  const size_t xbase = (size_t)b * S * D + (size_t)h * 64;
  const size_t vtb = (size_t)(b * 16 + h) * 64;

  bf16x8 qf0[2], qf1[2];
#pragma unroll
  for (int mb = 0; mb < 2; ++mb) {
    const unsigned short* qrow =
        Q + xbase + (size_t)(q0 + wave * 32 + mb * 16 + l16) * D;
    qf0[mb] = *(const bf16x8*)(qrow + quad * 8);
    qf1[mb] = *(const bf16x8*)(qrow + 32 + quad * 8);
  }

  const int sr1 = tid >> 3, sc1 = (tid & 7) * 8;
  const int sr2 = (256 + tid) >> 3, sc2 = (tid & 7) * 8;
  const unsigned short* kg1 = K + xbase + (size_t)sr1 * D + sc1;
  const unsigned short* kg2 = K + xbase + (size_t)sr2 * D + sc2;
  const unsigned short* vg1 = Vt + (vtb + sr1) * S + sc1;
  const unsigned short* vg2 = Vt + (vtb + sr2) * S + sc2;

  f32x4 oacc[2][4] = {};
  float rs[2][4] = {};

  unsigned short* pw = Ps + wave * (32 * 72);

  int4 kr1, kr2, vr1, vr2;
  {
    kr1 = *(const int4*)(kg1);
    kr2 = *(const int4*)(kg2);
    vr1 = *(const int4*)(vg1);
    vr2 = *(const int4*)(vg2);
  }

  for (int kt = 0; kt < ktEnd; ++kt) {
    const int k0 = kt * 64;
    __syncthreads();
    *(int4*)(Ks + sr1 * 72 + sc1) = kr1;
    *(int4*)(Ks + sr2 * 72 + sc2) = kr2;
    *(int4*)(Vs + sr1 * 72 + sc1) = vr1;
    *(int4*)(Vs + sr2 * 72 + sc2) = vr2;
    __syncthreads();

    if (kt + 1 < ktEnd) {            // async prefetch of next tile
      const int kn = (kt + 1) * 64;
      kr1 = *(const int4*)(kg1 + (size_t)kn * D);
      kr2 = *(const int4*)(kg2 + (size_t)kn * D);
      vr1 = *(const int4*)(vg1 + kn);
      vr2 = *(const int4*)(vg2 + kn);
    }

    f32x4 sf[2][4];
    __builtin_amdgcn_s_setprio(1);
#pragma unroll
    for (int cb = 0; cb < 4; ++cb) {
      const bf16x8 kf0 = *(const bf16x8*)(Ks + (cb * 16 + l16) * 72 + quad * 8);
      const bf16x8 kf1 = *(const bf16x8*)(Ks + (cb * 16 + l16) * 72 + 32 + quad * 8);
#pragma unroll
      for (int mb = 0; mb < 2; ++mb) {
        f32x4 c = {0.f, 0.f, 0.f, 0.f};
        c = __builtin_amdgcn_mfma_f32_16x16x32_bf16(qf0[mb], kf0, c, 0, 0, 0);
        c = __builtin_amdgcn_mfma_f32_16x16x32_bf16(qf1[mb], kf1, c, 0, 0, 0);
        sf[mb][cb] = c;
      }
    }
    __builtin_amdgcn_s_setprio(0);

    if (k0 + 64 > len) {
#pragma unroll
      for (int cb = 0; cb < 4; ++cb) {
        const bool msk = (k0 + cb * 16 + l16) >= len;
#pragma unroll
        for (int mb = 0; mb < 2; ++mb)
#pragma unroll
          for (int r = 0; r < 4; ++r) sf[mb][cb][r] = msk ? NEGINF : sf[mb][cb][r];
      }
    }

#pragma unroll
    for (int mb = 0; mb < 2; ++mb)
#pragma unroll
      for (int cb = 0; cb < 4; ++cb)
#pragma unroll
        for (int r = 0; r < 4; ++r) {
          const float p = __builtin_amdgcn_exp2f(sf[mb][cb][r]);
          sf[mb][cb][r] = p;
          rs[mb][r] += p;
        }

#pragma unroll
    for (int mb = 0; mb < 2; ++mb)
#pragma unroll
      for (int cb = 0; cb < 4; ++cb)
#pragma unroll
        for (int r = 0; r < 4; ++r)
          pw[(mb * 16 + quad * 4 + r) * 72 + cb * 16 + l16] = f2bf(sf[mb][cb][r]);

    bf16x8 pa0[2], pa1[2];
#pragma unroll
    for (int mb = 0; mb < 2; ++mb) {
      pa0[mb] = *(const bf16x8*)(pw + (mb * 16 + l16) * 72 + quad * 8);
      pa1[mb] = *(const bf16x8*)(pw + (mb * 16 + l16) * 72 + 32 + quad * 8);
    }
    __builtin_amdgcn_s_setprio(1);
#pragma unroll
    for (int cb = 0; cb < 4; ++cb) {
      const bf16x8 vb0 = *(const bf16x8*)(Vs + (cb * 16 + l16) * 72 + quad * 8);
      const bf16x8 vb1 = *(const bf16x8*)(Vs + (cb * 16 + l16) * 72 + 32 + quad * 8);
#pragma unroll
      for (int mb = 0; mb < 2; ++mb) {
        oacc[mb][cb] = __builtin_amdgcn_mfma_f32_16x16x32_bf16(pa0[mb], vb0, oacc[mb][cb], 0, 0, 0);
        oacc[mb][cb] = __builtin_amdgcn_mfma_f32_16x16x32_bf16(pa1[mb], vb1, oacc[mb][cb], 0, 0, 0);
      }
    }
    __builtin_amdgcn_s_setprio(0);
  }

#pragma unroll
  for (int off = 8; off > 0; off >>= 1)
#pragma unroll
    for (int mb = 0; mb < 2; ++mb)
#pragma unroll
      for (int r = 0; r < 4; ++r) rs[mb][r] += __shfl_xor(rs[mb][r], off, 16);

#pragma unroll
  for (int mb = 0; mb < 2; ++mb) {
    float inv[4];
#pragma unroll
    for (int r = 0; r < 4; ++r) inv[r] = 1.0f / rs[mb][r];
#pragma unroll
    for (int cb = 0; cb < 4; ++cb)
#pragma unroll
      for (int r = 0; r < 4; ++r) {
        const int row = q0 + wave * 32 + mb * 16 + quad * 4 + r;
        ctx[xbase + (size_t)row * D + cb * 16 + l16] = f2bf(oacc[mb][cb][r] * inv[r]);
      }
  }
}

// ------------------------------ launcher -----------------------------------
extern "C" void kernel_launch(void* const* d_in, const int* in_sizes, int n_in,
                              void* d_out, int out_size, void* d_ws,
                              size_t ws_size, hipStream_t stream) {
  const float* x  = (const float*)d_in[0];
  const int* lengths = (const int*)d_in[1];
  const float* qW = (const float*)d_in[2];
  const float* qb = (const float*)d_in[3];
  const float* kW = (const float*)d_in[4];
  const float* kb = (const float*)d_in[5];
  const float* vW = (const float*)d_in[6];
  const float* vb = (const float*)d_in[7];
  const float* oW = (const float*)d_in[8];
  const float* ob = (const float*)d_in[9];
  const float* w1 = (const float*)d_in[10];
  const float* b1 = (const float*)d_in[11];
  const float* w2 = (const float*)d_in[12];
  const float* b2 = (const float*)d_in[13];
  float* out = (float*)d_out;

  const int Bx = 4, S = 2048, D = 1024, FF = 4096;
  const int M = Bx * S;  // 8192

  unsigned short* p = (unsigned short*)d_ws;
  unsigned short* xb  = p; p += (size_t)M * D;
  unsigned short* qWt = p; p += (size_t)D * D;   // contiguous [3072,1024]
  unsigned short* kWt = p; p += (size_t)D * D;
  unsigned short* vWt = p; p += (size_t)D * D;
  unsigned short* oWt = p; p += (size_t)D * D;
  unsigned short* w1t = p; p += (size_t)D * FF;   // [FF, D]
  unsigned short* w2t = p; p += (size_t)FF * D;   // [D, FF]
  unsigned short* Qb  = p; p += (size_t)M * D;
  unsigned short* Kb  = p; p += (size_t)M * D;
  unsigned short* Vtb = p; p += (size_t)M * D;    // [B,H,64,S]
  unsigned short* Cb  = p; p += (size_t)M * D;
  unsigned short* Ab  = p; p += (size_t)M * D;
  unsigned short* Hb  = p; p += (size_t)M * FF;

  {
    int n4 = (int)((size_t)M * D / 4);
    cast_f32_bf16<<<dim3((n4 + 255) / 256), dim3(256), 0, stream>>>(x, xb, n4);
  }
  prep_weights<<<dim3(6144), dim3(256), 0, stream>>>(
      qW, kW, vW, oW, w1, w2, qWt, kWt, vWt, oWt, w1t, w2t);

  // qkv: 128^2 reg-dbuf core, 24 x 64 = 1536 blocks
  gemm128_qkv<<<dim3(1536), dim3(256), 0, stream>>>(
      xb, qWt, qb, kb, vb, Qb, Kb, Vtb, D);

  attn_fused<<<dim3(Bx * 16 * (S / 128)), dim3(256), 0, stream>>>(
      Qb, Kb, Vtb, lengths, Cb);

  // proj: 128^2 reg-dbuf core, 8 x 64 = 512 blocks
  gemm128_bt<1><<<dim3(512), dim3(256), 0, stream>>>(Cb, oWt, ob, Ab, D, D);
  // ffn1: 256^2 8-phase core, 32 x 16 = 512 blocks
  gemm256_bt<2><<<dim3(512), dim3(512), 0, stream>>>(Ab, w1t, b1, Hb, FF, D);
  // ffn2: 128^2 reg-dbuf core, 8 x 64 = 512 blocks (K=4096: 128 K-steps)
  gemm128_bt<0><<<dim3(512), dim3(256), 0, stream>>>(Hb, w2t, b2, out, D, FF);
}